// Round 1
// baseline (705.728 us; speedup 1.0000x reference)
//
#include <hip/hip_runtime.h>

#define NN 131072
#define NE 2097152
#define NT (NE + NN)      // edges + self loops
#define NG 2048
#define EPSV 1e-5f

// ---------------- degree / CSR build ----------------
__global__ void k_init_deg(int* __restrict__ deg) {
    int i = blockIdx.x * 256 + threadIdx.x;
    deg[i] = 1;  // self loop
}
__global__ void k_count(const int* __restrict__ dst, int* __restrict__ deg) {
    int e = blockIdx.x * 256 + threadIdx.x;
    atomicAdd(&deg[dst[e]], 1);
}
__global__ void k_dinv(const int* __restrict__ deg, float* __restrict__ dinv) {
    int i = blockIdx.x * 256 + threadIdx.x;
    dinv[i] = rsqrtf((float)deg[i]);
}
// exclusive scan, 1024 elems per block (Hillis-Steele in LDS)
__global__ void k_scan1(const int* __restrict__ in, int* __restrict__ out,
                        int* __restrict__ bsums, int n) {
    __shared__ int tmp[1024];
    int t = threadIdx.x;
    int gid = blockIdx.x * 1024 + t;
    int v = (gid < n) ? in[gid] : 0;
    tmp[t] = v;
    __syncthreads();
    for (int off = 1; off < 1024; off <<= 1) {
        int add = (t >= off) ? tmp[t - off] : 0;
        __syncthreads();
        tmp[t] += add;
        __syncthreads();
    }
    if (gid < n) out[gid] = tmp[t] - v;       // exclusive
    if (t == 1023) bsums[blockIdx.x] = tmp[t];
}
__global__ void k_scan_add(int* __restrict__ out, const int* __restrict__ bs,
                           int* __restrict__ cur, int n) {
    int gid = blockIdx.x * 1024 + threadIdx.x;
    if (gid < n) {
        int v = out[gid] + bs[blockIdx.x];
        out[gid] = v;
        if (cur) cur[gid] = v;
    }
}
__global__ void k_set_int(int* p, int v) { *p = v; }

__global__ void k_fill_self(int* __restrict__ cur, int* __restrict__ srcs) {
    int i = blockIdx.x * 256 + threadIdx.x;
    int pos = atomicAdd(&cur[i], 1);
    srcs[pos] = i;
}
__global__ void k_fill_edges(const int* __restrict__ src, const int* __restrict__ dst,
                             int* __restrict__ cur, int* __restrict__ srcs) {
    int e = blockIdx.x * 256 + threadIdx.x;
    int d = dst[e];
    int pos = atomicAdd(&cur[d], 1);
    srcs[pos] = src[e];
}
__global__ void k_gcount(const int* __restrict__ batch, int* __restrict__ gcnt) {
    int i = blockIdx.x * 256 + threadIdx.x;
    atomicAdd(&gcnt[batch[i]], 1);
}

// ---------------- dense GEMM: out[64rows x COUT] = A[64 x K] @ W[K x COUT] ----------------
template <int K, int COUT, int CN>
__global__ __launch_bounds__(256) void k_gemm(const float* __restrict__ A,
                                              const float* __restrict__ W,
                                              float* __restrict__ out) {
    __shared__ float as[64 * K];
    __shared__ float ws[K * COUT];
    int tid = threadIdx.x;
    long r0 = (long)blockIdx.x * 64;
    const float4* Ag = (const float4*)(A + r0 * K);
    float4* As4 = (float4*)as;
#pragma unroll
    for (int i = 0; i < (64 * K / 4) / 256; ++i) As4[tid + i * 256] = Ag[tid + i * 256];
    const float4* Wg = (const float4*)W;
    float4* Ws4 = (float4*)ws;
#pragma unroll
    for (int i = 0; i < (K * COUT / 4) / 256; ++i) Ws4[tid + i * 256] = Wg[tid + i * 256];
    __syncthreads();
    int ty = tid >> 4, tx = tid & 15;   // 16x16 thread grid; micro-tile 4 rows x CN cols
    float acc[4][CN] = {};
    for (int k = 0; k < K; ++k) {
        float a0 = as[(ty * 4 + 0) * K + k];
        float a1 = as[(ty * 4 + 1) * K + k];
        float a2 = as[(ty * 4 + 2) * K + k];
        float a3 = as[(ty * 4 + 3) * K + k];
#pragma unroll
        for (int j = 0; j < CN; ++j) {
            float w = ws[k * COUT + tx * CN + j];
            acc[0][j] = fmaf(a0, w, acc[0][j]);
            acc[1][j] = fmaf(a1, w, acc[1][j]);
            acc[2][j] = fmaf(a2, w, acc[2][j]);
            acc[3][j] = fmaf(a3, w, acc[3][j]);
        }
    }
#pragma unroll
    for (int i = 0; i < 4; ++i) {
        float* orow = out + (r0 + ty * 4 + i) * COUT + tx * CN;
#pragma unroll
        for (int j = 0; j < CN; ++j) orow[j] = acc[i][j];
    }
}

// ---------------- 64-channel CSR aggregation: out[n] = dinv[n] * sum_e dinv[src]*feat[src] ----------------
__global__ __launch_bounds__(256) void k_agg64(const float* __restrict__ feat,
                                               const int* __restrict__ offs,
                                               const int* __restrict__ srcs,
                                               const float* __restrict__ dinv,
                                               float* __restrict__ out) {
    int wid = (blockIdx.x * 256 + threadIdx.x) >> 6;   // one wave per dst node
    int lane = threadIdx.x & 63;                       // lane = channel
    int beg = offs[wid], end = offs[wid + 1];
    float dn = dinv[wid];
    float acc = 0.f;
    int e = beg;
    for (; e + 4 <= end; e += 4) {
        int s0 = srcs[e], s1 = srcs[e + 1], s2 = srcs[e + 2], s3 = srcs[e + 3];
        float w0 = dinv[s0], w1 = dinv[s1], w2 = dinv[s2], w3 = dinv[s3];
        float f0 = feat[(long)s0 * 64 + lane];
        float f1 = feat[(long)s1 * 64 + lane];
        float f2 = feat[(long)s2 * 64 + lane];
        float f3 = feat[(long)s3 * 64 + lane];
        acc += f0 * w0 + f1 * w1 + f2 * w2 + f3 * w3;
    }
    for (; e < end; ++e) {
        int s = srcs[e];
        acc += feat[(long)s * 64 + lane] * dinv[s];
    }
    out[(long)wid * 64 + lane] = acc * dn;
}

// ---------------- BatchNorm ----------------
template <int C>
__global__ __launch_bounds__(256) void k_bn_stats(const float* __restrict__ h,
                                                  float* __restrict__ sums,
                                                  float* __restrict__ sqs) {
    __shared__ float lsum[256], lsq[256];
    const int RG = 256 / C;
    int tid = threadIdx.x;
    int c = tid % C;
    int rg = tid / C;
    int row0 = blockIdx.x * 256;
    float s = 0.f, q = 0.f;
    for (int i = rg; i < 256; i += RG) {
        float v = h[(long)(row0 + i) * C + c];
        s += v;
        q += v * v;
    }
    lsum[tid] = s; lsq[tid] = q;
    __syncthreads();
    if (tid < C) {
        float ts = 0.f, tq = 0.f;
#pragma unroll
        for (int g = 0; g < RG; ++g) { ts += lsum[g * C + c]; tq += lsq[g * C + c]; }
        atomicAdd(&sums[c], ts);
        atomicAdd(&sqs[c], tq);
    }
}
template <int C>
__global__ void k_bn_prep(const float* __restrict__ sums, const float* __restrict__ sqs,
                          const float* __restrict__ gamma, const float* __restrict__ beta,
                          float* __restrict__ scale, float* __restrict__ shift) {
    int c = threadIdx.x;
    if (c >= C) return;
    const float invN = 1.0f / (float)NN;
    float mean = sums[c] * invN;
    float var = sqs[c] * invN - mean * mean;
    float inv = rsqrtf(var + EPSV);
    float sc = gamma[c] * inv;
    scale[c] = sc;
    shift[c] = beta[c] - mean * sc;
}
template <int C>
__global__ __launch_bounds__(256) void k_bn_apply(float* __restrict__ h,
                                                  const float* __restrict__ scale,
                                                  const float* __restrict__ shift) {
    int idx = blockIdx.x * 256 + threadIdx.x;
    float4 v = ((float4*)h)[idx];
    int cb = (idx * 4) & (C - 1);
    float r[4] = {v.x, v.y, v.z, v.w};
#pragma unroll
    for (int j = 0; j < 4; ++j) {
        float y = fmaf(r[j], scale[cb + j], shift[cb + j]);
        r[j] = y > 0.f ? y : 0.01f * y;
    }
    ((float4*)h)[idx] = make_float4(r[0], r[1], r[2], r[3]);
}

// ---------------- pooling + output head ----------------
__global__ __launch_bounds__(256) void k_pool(const float* __restrict__ h,
                                              const int* __restrict__ goff,
                                              const int* __restrict__ gcnt,
                                              const float* __restrict__ Wo,
                                              const float* __restrict__ bo,
                                              float* __restrict__ out) {
    int g = (blockIdx.x * 256 + threadIdx.x) >> 6;   // one wave per graph
    int lane = threadIdx.x & 63;
    int beg = goff[g], cnt = gcnt[g];
    float a0 = 0.f, a1 = 0.f;
    for (int i = 0; i < cnt; ++i) {
        const float* row = h + (long)(beg + i) * 128;
        a0 += row[lane];
        a1 += row[lane + 64];
    }
    float v = a0 * Wo[lane] + a1 * Wo[lane + 64];
    v /= fmaxf((float)cnt, 1.f);
#pragma unroll
    for (int m = 32; m; m >>= 1) v += __shfl_xor(v, m);
    if (lane == 0) out[g] = v + bo[0];
}

extern "C" void kernel_launch(void* const* d_in, const int* in_sizes, int n_in,
                              void* d_out, int out_size, void* d_ws, size_t ws_size,
                              hipStream_t stream) {
    const float* x    = (const float*)d_in[0];
    const int* ei     = (const int*)d_in[1];
    const int* batch  = (const int*)d_in[2];
    const float* W1   = (const float*)d_in[3];
    const float* g1   = (const float*)d_in[5];
    const float* be1  = (const float*)d_in[6];
    const float* W2   = (const float*)d_in[7];
    const float* g2   = (const float*)d_in[9];
    const float* be2  = (const float*)d_in[10];
    const float* Wo   = (const float*)d_in[11];
    const float* bo   = (const float*)d_in[12];
    float* out = (float*)d_out;

    const int* esrc = ei;
    const int* edst = ei + NE;

    // ---- workspace layout ----
    float* r0   = (float*)d_ws;                    // [NN,64]  xw1, later aggh
    float* r12  = r0 + (size_t)NN * 64;            // [NN,128] h1 (first half), later h2
    float* dinv = r12 + (size_t)NN * 128;          // [NN]
    float* stats = dinv + NN;                      // 1024 floats
    float* sums1 = stats, *sqs1 = stats + 128;
    float* sums2 = stats + 256, *sqs2 = stats + 384;
    float* scale = stats + 512, *shift = stats + 768;
    int* degInt = (int*)(stats + 1024);            // [NN]
    int* offs   = degInt + NN;                     // [NN+1]
    int* cur    = offs + NN + 1;                   // [NN]
    int* srcs   = cur + NN;                        // [NT]
    int* bsums  = srcs + NT;                       // 128
    int* bsums_s = bsums + 128;                    // 128
    int* dummy  = bsums_s + 128;                   // 8
    int* gcnt   = dummy + 8;                       // [NG]
    int* goff   = gcnt + NG;                       // [NG]
    int* gb     = goff + NG;                       // 8
    int* gb_s   = gb + 8;                          // 8

    hipMemsetAsync(stats, 0, 1024 * sizeof(float), stream);
    hipMemsetAsync(gcnt, 0, NG * sizeof(int), stream);

    // degrees + dinv
    k_init_deg<<<NN / 256, 256, 0, stream>>>(degInt);
    k_count<<<NE / 256, 256, 0, stream>>>(edst, degInt);
    k_dinv<<<NN / 256, 256, 0, stream>>>(degInt, dinv);
    // CSR offsets (exclusive scan of deg)
    k_scan1<<<NN / 1024, 1024, 0, stream>>>(degInt, offs, bsums, NN);
    k_scan1<<<1, 1024, 0, stream>>>(bsums, bsums_s, dummy, NN / 1024);
    k_scan_add<<<NN / 1024, 1024, 0, stream>>>(offs, bsums_s, cur, NN);
    k_set_int<<<1, 1, 0, stream>>>(offs + NN, NT);
    // CSR fill (self loops + edges)
    k_fill_self<<<NN / 256, 256, 0, stream>>>(cur, srcs);
    k_fill_edges<<<NE / 256, 256, 0, stream>>>(esrc, edst, cur, srcs);

    // layer 1: xw1 = x @ W1 (transform-then-aggregate; b1 cancels in BN)
    k_gemm<128, 64, 4><<<NN / 64, 256, 0, stream>>>(x, W1, r0);
    k_agg64<<<NN / 4, 256, 0, stream>>>(r0, offs, srcs, dinv, r12);
    k_bn_stats<64><<<NN / 256, 256, 0, stream>>>(r12, sums1, sqs1);
    k_bn_prep<64><<<1, 64, 0, stream>>>(sums1, sqs1, g1, be1, scale, shift);
    k_bn_apply<64><<<NN * 64 / 4 / 256, 256, 0, stream>>>(r12, scale, shift);

    // layer 2: aggregate-then-transform (64ch agg), h2 = aggh @ W2
    k_agg64<<<NN / 4, 256, 0, stream>>>(r12, offs, srcs, dinv, r0);
    k_gemm<64, 128, 8><<<NN / 64, 256, 0, stream>>>(r0, W2, r12);
    k_bn_stats<128><<<NN / 256, 256, 0, stream>>>(r12, sums2, sqs2);
    k_bn_prep<128><<<1, 128, 0, stream>>>(sums2, sqs2, g2, be2, scale, shift);
    k_bn_apply<128><<<NN * 128 / 4 / 256, 256, 0, stream>>>(r12, scale, shift);

    // pooling (batch sorted -> contiguous ranges) + head
    k_gcount<<<NN / 256, 256, 0, stream>>>(batch, gcnt);
    k_scan1<<<NG / 1024, 1024, 0, stream>>>(gcnt, goff, gb, NG);
    k_scan1<<<1, 1024, 0, stream>>>(gb, gb_s, dummy, NG / 1024);
    k_scan_add<<<NG / 1024, 1024, 0, stream>>>(goff, gb_s, nullptr, NG);
    k_pool<<<NG / 4, 256, 0, stream>>>(r12, goff, gcnt, Wo, bo, out);
}

// Round 3
// 497.066 us; speedup vs baseline: 1.4198x; 1.4198x over previous
//
#include <hip/hip_runtime.h>

#define NN 131072
#define NE 2097152
#define NT (NE + NN)      // edges + self loops
#define NG 2048
#define NB 1024           // coarse buckets (dst >> 7)
#define CH 256            // chunks
#define ECH (NE / CH)     // 8192 edges per chunk
#define EPSV 1e-5f

// ---------------- generic scan helpers ----------------
__global__ void k_scan1(const int* __restrict__ in, int* __restrict__ out,
                        int* __restrict__ bsums, int n) {
    __shared__ int tmp[1024];
    int t = threadIdx.x;
    int gid = blockIdx.x * 1024 + t;
    int v = (gid < n) ? in[gid] : 0;
    tmp[t] = v;
    __syncthreads();
    for (int off = 1; off < 1024; off <<= 1) {
        int add = (t >= off) ? tmp[t - off] : 0;
        __syncthreads();
        tmp[t] += add;
        __syncthreads();
    }
    if (gid < n) out[gid] = tmp[t] - v;       // exclusive
    if (t == 1023) bsums[blockIdx.x] = tmp[t];
}
__global__ void k_scan_add(int* __restrict__ out, const int* __restrict__ bs, int n) {
    int gid = blockIdx.x * 1024 + threadIdx.x;
    if (gid < n) out[gid] += bs[blockIdx.x];
}
__global__ void k_set_int(int* p, int v) { *p = v; }

// ---------------- CSR build: stable two-level counting sort ----------------
// coarse per-chunk histogram over 1024 buckets; chunk-major output (clean writes)
__global__ __launch_bounds__(256) void k_chist(const int* __restrict__ dst, int* __restrict__ ghist) {
    __shared__ int h[NB];
    int c = blockIdx.x, tid = threadIdx.x;
    for (int i = tid; i < NB; i += 256) h[i] = 0;
    __syncthreads();
    const int* d = dst + (long)c * ECH;
    for (int i = tid; i < ECH; i += 256) atomicAdd(&h[d[i] >> 7], 1);
    __syncthreads();
    int* o = ghist + (long)c * NB;
    for (int i = tid; i < NB; i += 256) o[i] = h[i];
}
// transpose [CH][NB] -> [NB][CH], both sides coalesced
__global__ void k_transpose(const int* __restrict__ in, int* __restrict__ out) {
    __shared__ int tile[32][33];
    int x = blockIdx.x * 32 + threadIdx.x;      // col in 'in' (bucket)
    int y0 = blockIdx.y * 32 + threadIdx.y;     // row in 'in' (chunk)
    for (int i = 0; i < 32; i += 8)
        tile[threadIdx.y + i][threadIdx.x] = in[(y0 + i) * NB + x];
    __syncthreads();
    int ox = blockIdx.y * 32 + threadIdx.x;     // col in 'out' (chunk)
    int oy0 = blockIdx.x * 32 + threadIdx.y;    // row in 'out' (bucket)
    for (int i = 0; i < 32; i += 8)
        out[(oy0 + i) * CH + ox] = tile[threadIdx.x][threadIdx.y + i];
}
// stable scatter: block = chunk, block-private (bucket,chunk) regions
// pack src (17b) | (dst & 127) << 17  -> single 4B write per edge
__global__ __launch_bounds__(256) void k_cscatter(const int* __restrict__ src, const int* __restrict__ dst,
                                                  const int* __restrict__ scanned, int* __restrict__ packed) {
    __shared__ int cur[NB];
    int c = blockIdx.x, tid = threadIdx.x;
    for (int i = tid; i < NB; i += 256) cur[i] = scanned[i * CH + c];
    __syncthreads();
    const int* s = src + (long)c * ECH;
    const int* d = dst + (long)c * ECH;
    for (int i = tid; i < ECH; i += 256) {
        int dv = d[i], sv = s[i];
        int p = atomicAdd(&cur[dv >> 7], 1);
        packed[p] = sv | ((dv & 127) << 17);
    }
}
// fine pass: block = bucket (128 nodes). Emits deg->dinv, CSR offs, srcs (self loop first).
__global__ __launch_bounds__(256) void k_fine(const int* __restrict__ packed,
                                              const int* __restrict__ scanned,
                                              int* __restrict__ offs, float* __restrict__ dinv,
                                              int* __restrict__ srcs) {
    __shared__ int hist[128], sc[128], cursor[128];
    int b = blockIdx.x, tid = threadIdx.x;
    int ebeg = scanned[b * CH];
    int eend = (b == NB - 1) ? NE : scanned[(b + 1) * CH];
    if (tid < 128) hist[tid] = 0;
    __syncthreads();
    for (int e = ebeg + tid; e < eend; e += 256)
        atomicAdd(&hist[packed[e] >> 17], 1);
    __syncthreads();
    if (tid < 128) sc[tid] = hist[tid] + 1;     // +1 self loop
    __syncthreads();
    for (int off = 1; off < 128; off <<= 1) {
        int v = 0;
        if (tid < 128 && tid >= off) v = sc[tid - off];
        __syncthreads();
        if (tid < 128) sc[tid] += v;
        __syncthreads();
    }
    int base = ebeg + b * 128;
    if (tid < 128) {
        int cnt = hist[tid] + 1;
        int ex = sc[tid] - cnt;                 // exclusive scan
        int n = (b << 7) | tid;
        offs[n] = base + ex;
        dinv[n] = rsqrtf((float)cnt);
        srcs[base + ex] = n;                    // self loop first
        cursor[tid] = ex + 1;
    }
    __syncthreads();
    for (int e = ebeg + tid; e < eend; e += 256) {
        int p = packed[e];
        int pos = atomicAdd(&cursor[p >> 17], 1);
        srcs[base + pos] = p & 131071;
    }
}
__global__ void k_gcount(const int* __restrict__ batch, int* __restrict__ gcnt) {
    int i = blockIdx.x * 256 + threadIdx.x;
    atomicAdd(&gcnt[batch[i]], 1);
}

// ---------------- dense GEMM: out[64rows x COUT] = A[64 x K] @ W[K x COUT] ----------------
template <int K, int COUT, int CN>
__global__ __launch_bounds__(256) void k_gemm(const float* __restrict__ A,
                                              const float* __restrict__ W,
                                              float* __restrict__ out) {
    __shared__ float as[64 * K];
    __shared__ float ws[K * COUT];
    int tid = threadIdx.x;
    long r0 = (long)blockIdx.x * 64;
    const float4* Ag = (const float4*)(A + r0 * K);
    float4* As4 = (float4*)as;
#pragma unroll
    for (int i = 0; i < (64 * K / 4) / 256; ++i) As4[tid + i * 256] = Ag[tid + i * 256];
    const float4* Wg = (const float4*)W;
    float4* Ws4 = (float4*)ws;
#pragma unroll
    for (int i = 0; i < (K * COUT / 4) / 256; ++i) Ws4[tid + i * 256] = Wg[tid + i * 256];
    __syncthreads();
    int ty = tid >> 4, tx = tid & 15;   // 16x16 thread grid; micro-tile 4 rows x CN cols
    float acc[4][CN] = {};
    for (int k = 0; k < K; ++k) {
        float a0 = as[(ty * 4 + 0) * K + k];
        float a1 = as[(ty * 4 + 1) * K + k];
        float a2 = as[(ty * 4 + 2) * K + k];
        float a3 = as[(ty * 4 + 3) * K + k];
#pragma unroll
        for (int j = 0; j < CN; ++j) {
            float w = ws[k * COUT + tx * CN + j];
            acc[0][j] = fmaf(a0, w, acc[0][j]);
            acc[1][j] = fmaf(a1, w, acc[1][j]);
            acc[2][j] = fmaf(a2, w, acc[2][j]);
            acc[3][j] = fmaf(a3, w, acc[3][j]);
        }
    }
#pragma unroll
    for (int i = 0; i < 4; ++i) {
        float* orow = out + (r0 + ty * 4 + i) * COUT + tx * CN;
#pragma unroll
        for (int j = 0; j < CN; ++j) orow[j] = acc[i][j];
    }
}

// ---------------- 64-channel CSR aggregation ----------------
__global__ __launch_bounds__(256) void k_agg64(const float* __restrict__ feat,
                                               const int* __restrict__ offs,
                                               const int* __restrict__ srcs,
                                               const float* __restrict__ dinv,
                                               float* __restrict__ out) {
    int wid = (blockIdx.x * 256 + threadIdx.x) >> 6;   // one wave per dst node
    int lane = threadIdx.x & 63;                       // lane = channel
    int beg = offs[wid], end = offs[wid + 1];
    float dn = dinv[wid];
    float acc = 0.f;
    int e = beg;
    for (; e + 4 <= end; e += 4) {
        int s0 = srcs[e], s1 = srcs[e + 1], s2 = srcs[e + 2], s3 = srcs[e + 3];
        float w0 = dinv[s0], w1 = dinv[s1], w2 = dinv[s2], w3 = dinv[s3];
        float f0 = feat[(long)s0 * 64 + lane];
        float f1 = feat[(long)s1 * 64 + lane];
        float f2 = feat[(long)s2 * 64 + lane];
        float f3 = feat[(long)s3 * 64 + lane];
        acc += f0 * w0 + f1 * w1 + f2 * w2 + f3 * w3;
    }
    for (; e < end; ++e) {
        int s = srcs[e];
        acc += feat[(long)s * 64 + lane] * dinv[s];
    }
    out[(long)wid * 64 + lane] = acc * dn;
}

// ---------------- BatchNorm ----------------
template <int C>
__global__ __launch_bounds__(256) void k_bn_stats(const float* __restrict__ h,
                                                  float* __restrict__ sums,
                                                  float* __restrict__ sqs) {
    __shared__ float lsum[256], lsq[256];
    const int RG = 256 / C;
    int tid = threadIdx.x;
    int c = tid % C;
    int rg = tid / C;
    int row0 = blockIdx.x * 256;
    float s = 0.f, q = 0.f;
    for (int i = rg; i < 256; i += RG) {
        float v = h[(long)(row0 + i) * C + c];
        s += v;
        q += v * v;
    }
    lsum[tid] = s; lsq[tid] = q;
    __syncthreads();
    if (tid < C) {
        float ts = 0.f, tq = 0.f;
#pragma unroll
        for (int g = 0; g < RG; ++g) { ts += lsum[g * C + c]; tq += lsq[g * C + c]; }
        atomicAdd(&sums[c], ts);
        atomicAdd(&sqs[c], tq);
    }
}
template <int C>
__global__ void k_bn_prep(const float* __restrict__ sums, const float* __restrict__ sqs,
                          const float* __restrict__ gamma, const float* __restrict__ beta,
                          float* __restrict__ scale, float* __restrict__ shift) {
    int c = threadIdx.x;
    if (c >= C) return;
    const float invN = 1.0f / (float)NN;
    float mean = sums[c] * invN;
    float var = sqs[c] * invN - mean * mean;
    float inv = rsqrtf(var + EPSV);
    float sc = gamma[c] * inv;
    scale[c] = sc;
    shift[c] = beta[c] - mean * sc;
}
template <int C>
__global__ __launch_bounds__(256) void k_bn_apply(float* __restrict__ h,
                                                  const float* __restrict__ scale,
                                                  const float* __restrict__ shift) {
    int idx = blockIdx.x * 256 + threadIdx.x;
    float4 v = ((float4*)h)[idx];
    int cb = (idx * 4) & (C - 1);
    float r[4] = {v.x, v.y, v.z, v.w};
#pragma unroll
    for (int j = 0; j < 4; ++j) {
        float y = fmaf(r[j], scale[cb + j], shift[cb + j]);
        r[j] = y > 0.f ? y : 0.01f * y;
    }
    ((float4*)h)[idx] = make_float4(r[0], r[1], r[2], r[3]);
}

// ---------------- pooling + output head ----------------
__global__ __launch_bounds__(256) void k_pool(const float* __restrict__ h,
                                              const int* __restrict__ goff,
                                              const int* __restrict__ gcnt,
                                              const float* __restrict__ Wo,
                                              const float* __restrict__ bo,
                                              float* __restrict__ out) {
    int g = (blockIdx.x * 256 + threadIdx.x) >> 6;   // one wave per graph
    int lane = threadIdx.x & 63;
    int beg = goff[g], cnt = gcnt[g];
    float a0 = 0.f, a1 = 0.f;
    for (int i = 0; i < cnt; ++i) {
        const float* row = h + (long)(beg + i) * 128;
        a0 += row[lane];
        a1 += row[lane + 64];
    }
    float v = a0 * Wo[lane] + a1 * Wo[lane + 64];
    v /= fmaxf((float)cnt, 1.f);
#pragma unroll
    for (int m = 32; m; m >>= 1) v += __shfl_xor(v, m);
    if (lane == 0) out[g] = v + bo[0];
}

extern "C" void kernel_launch(void* const* d_in, const int* in_sizes, int n_in,
                              void* d_out, int out_size, void* d_ws, size_t ws_size,
                              hipStream_t stream) {
    const float* x    = (const float*)d_in[0];
    const int* ei     = (const int*)d_in[1];
    const int* batch  = (const int*)d_in[2];
    const float* W1   = (const float*)d_in[3];
    const float* g1   = (const float*)d_in[5];
    const float* be1  = (const float*)d_in[6];
    const float* W2   = (const float*)d_in[7];
    const float* g2   = (const float*)d_in[9];
    const float* be2  = (const float*)d_in[10];
    const float* Wo   = (const float*)d_in[11];
    const float* bo   = (const float*)d_in[12];
    float* out = (float*)d_out;

    const int* esrc = ei;
    const int* edst = ei + NE;

    // ---- workspace layout ----
    float* r0   = (float*)d_ws;                    // [NN,64]  xw1, later aggh
    float* r12  = r0 + (size_t)NN * 64;            // [NN,128] h1/h2
    float* dinv = r12 + (size_t)NN * 128;          // [NN]
    float* stats = dinv + NN;                      // 1024 floats
    float* sums1 = stats, *sqs1 = stats + 128;
    float* sums2 = stats + 256, *sqs2 = stats + 384;
    float* scale = stats + 512, *shift = stats + 768;
    int* offs   = (int*)(stats + 1024);            // [NN+1]
    int* srcs   = offs + NN + 1;                   // [NT]
    int* bsums  = srcs + NT;                       // 256
    int* bsums2 = bsums + 256;                     // 256
    int* dummy  = bsums2 + 256;                    // 8
    int* gcnt   = dummy + 8;                       // [NG]
    int* goff   = gcnt + NG;                       // [NG]
    int* gb     = goff + NG;                       // 8
    int* gb_s   = gb + 8;                          // 8
    // aliases (consumed before r0/r12 first written by gemm/agg)
    int* ghist   = (int*)r0;                       // [CH][NB]
    int* ghist_t = ghist + CH * NB;                // [NB][CH]
    int* scanned = ghist_t + NB * CH;              // [NB][CH]
    int* packed  = (int*)r12;                      // [NE]

    hipMemsetAsync(stats, 0, 1024 * sizeof(float), stream);
    hipMemsetAsync(gcnt, 0, NG * sizeof(int), stream);

    // ---- CSR build: stable two-level counting sort ----
    k_chist<<<CH, 256, 0, stream>>>(edst, ghist);
    k_transpose<<<dim3(NB / 32, CH / 32), dim3(32, 8), 0, stream>>>(ghist, ghist_t);
    k_scan1<<<NB * CH / 1024, 1024, 0, stream>>>(ghist_t, scanned, bsums, NB * CH);
    k_scan1<<<1, 1024, 0, stream>>>(bsums, bsums2, dummy, NB * CH / 1024);
    k_scan_add<<<NB * CH / 1024, 1024, 0, stream>>>(scanned, bsums2, NB * CH);
    k_cscatter<<<CH, 256, 0, stream>>>(esrc, edst, scanned, packed);
    k_fine<<<NB, 256, 0, stream>>>(packed, scanned, offs, dinv, srcs);
    k_set_int<<<1, 1, 0, stream>>>(offs + NN, NT);

    // layer 1: xw1 = x @ W1 (transform-then-aggregate; b1 cancels in BN)
    k_gemm<128, 64, 4><<<NN / 64, 256, 0, stream>>>(x, W1, r0);
    k_agg64<<<NN / 4, 256, 0, stream>>>(r0, offs, srcs, dinv, r12);
    k_bn_stats<64><<<NN / 256, 256, 0, stream>>>(r12, sums1, sqs1);
    k_bn_prep<64><<<1, 64, 0, stream>>>(sums1, sqs1, g1, be1, scale, shift);
    k_bn_apply<64><<<NN * 64 / 4 / 256, 256, 0, stream>>>(r12, scale, shift);

    // layer 2: aggregate-then-transform (64ch agg), h2 = aggh @ W2
    k_agg64<<<NN / 4, 256, 0, stream>>>(r12, offs, srcs, dinv, r0);
    k_gemm<64, 128, 8><<<NN / 64, 256, 0, stream>>>(r0, W2, r12);
    k_bn_stats<128><<<NN / 256, 256, 0, stream>>>(r12, sums2, sqs2);
    k_bn_prep<128><<<1, 128, 0, stream>>>(sums2, sqs2, g2, be2, scale, shift);
    k_bn_apply<128><<<NN * 128 / 4 / 256, 256, 0, stream>>>(r12, scale, shift);

    // pooling (batch sorted -> contiguous ranges) + head
    k_gcount<<<NN / 256, 256, 0, stream>>>(batch, gcnt);
    k_scan1<<<NG / 1024, 1024, 0, stream>>>(gcnt, goff, gb, NG);
    k_scan1<<<1, 1024, 0, stream>>>(gb, gb_s, dummy, NG / 1024);
    k_scan_add<<<NG / 1024, 1024, 0, stream>>>(goff, gb_s, NG);
    k_pool<<<NG / 4, 256, 0, stream>>>(r12, goff, gcnt, Wo, bo, out);
}

// Round 5
// 415.523 us; speedup vs baseline: 1.6984x; 1.1962x over previous
//
#include <hip/hip_runtime.h>
#include <hip/hip_fp16.h>

#define NN 131072
#define NE 2097152
#define NT (NE + NN)      // edges + self loops
#define NG 2048
#define NB 1024           // coarse buckets (dst >> 7)
#define CH 256            // chunks
#define ECH (NE / CH)     // 8192 edges per chunk
#define EPSV 1e-5f

// ---------------- generic scan helpers ----------------
__global__ void k_scan1(const int* __restrict__ in, int* __restrict__ out,
                        int* __restrict__ bsums, int n) {
    __shared__ int tmp[1024];
    int t = threadIdx.x;
    int gid = blockIdx.x * 1024 + t;
    int v = (gid < n) ? in[gid] : 0;
    tmp[t] = v;
    __syncthreads();
    for (int off = 1; off < 1024; off <<= 1) {
        int add = (t >= off) ? tmp[t - off] : 0;
        __syncthreads();
        tmp[t] += add;
        __syncthreads();
    }
    if (gid < n) out[gid] = tmp[t] - v;       // exclusive
    if (t == 1023) bsums[blockIdx.x] = tmp[t];
}
__global__ void k_scan_add(int* __restrict__ out, const int* __restrict__ bs, int n) {
    int gid = blockIdx.x * 1024 + threadIdx.x;
    if (gid < n) out[gid] += bs[blockIdx.x];
}
__global__ void k_set_int(int* p, int v) { *p = v; }

// ---------------- CSR build: stable two-level counting sort ----------------
__global__ __launch_bounds__(256) void k_chist(const int* __restrict__ dst, int* __restrict__ ghist) {
    __shared__ int h[NB];
    int c = blockIdx.x, tid = threadIdx.x;
    for (int i = tid; i < NB; i += 256) h[i] = 0;
    __syncthreads();
    const int* d = dst + (long)c * ECH;
    for (int i = tid; i < ECH; i += 256) atomicAdd(&h[d[i] >> 7], 1);
    __syncthreads();
    int* o = ghist + (long)c * NB;
    for (int i = tid; i < NB; i += 256) o[i] = h[i];
}
__global__ void k_transpose(const int* __restrict__ in, int* __restrict__ out) {
    __shared__ int tile[32][33];
    int x = blockIdx.x * 32 + threadIdx.x;
    int y0 = blockIdx.y * 32 + threadIdx.y;
    for (int i = 0; i < 32; i += 8)
        tile[threadIdx.y + i][threadIdx.x] = in[(y0 + i) * NB + x];
    __syncthreads();
    int ox = blockIdx.y * 32 + threadIdx.x;
    int oy0 = blockIdx.x * 32 + threadIdx.y;
    for (int i = 0; i < 32; i += 8)
        out[(oy0 + i) * CH + ox] = tile[threadIdx.x][threadIdx.y + i];
}
__global__ __launch_bounds__(256) void k_cscatter(const int* __restrict__ src, const int* __restrict__ dst,
                                                  const int* __restrict__ scanned, int* __restrict__ packed) {
    __shared__ int cur[NB];
    int c = blockIdx.x, tid = threadIdx.x;
    for (int i = tid; i < NB; i += 256) cur[i] = scanned[i * CH + c];
    __syncthreads();
    const int* s = src + (long)c * ECH;
    const int* d = dst + (long)c * ECH;
    for (int i = tid; i < ECH; i += 256) {
        int dv = d[i], sv = s[i];
        int p = atomicAdd(&cur[dv >> 7], 1);
        packed[p] = sv | ((dv & 127) << 17);
    }
}
__global__ __launch_bounds__(256) void k_fine(const int* __restrict__ packed,
                                              const int* __restrict__ scanned,
                                              int* __restrict__ offs, float* __restrict__ dinv,
                                              int* __restrict__ srcs) {
    __shared__ int hist[128], sc[128], cursor[128];
    int b = blockIdx.x, tid = threadIdx.x;
    int ebeg = scanned[b * CH];
    int eend = (b == NB - 1) ? NE : scanned[(b + 1) * CH];
    if (tid < 128) hist[tid] = 0;
    __syncthreads();
    for (int e = ebeg + tid; e < eend; e += 256)
        atomicAdd(&hist[packed[e] >> 17], 1);
    __syncthreads();
    if (tid < 128) sc[tid] = hist[tid] + 1;
    __syncthreads();
    for (int off = 1; off < 128; off <<= 1) {
        int v = 0;
        if (tid < 128 && tid >= off) v = sc[tid - off];
        __syncthreads();
        if (tid < 128) sc[tid] += v;
        __syncthreads();
    }
    int base = ebeg + b * 128;
    if (tid < 128) {
        int cnt = hist[tid] + 1;
        int ex = sc[tid] - cnt;
        int n = (b << 7) | tid;
        offs[n] = base + ex;
        dinv[n] = rsqrtf((float)cnt);
        srcs[base + ex] = n;
        cursor[tid] = ex + 1;
    }
    __syncthreads();
    for (int e = ebeg + tid; e < eend; e += 256) {
        int p = packed[e];
        int pos = atomicAdd(&cursor[p >> 17], 1);
        srcs[base + pos] = p & 131071;
    }
}
__global__ void k_gcount(const int* __restrict__ batch, int* __restrict__ gcnt) {
    int i = blockIdx.x * 256 + threadIdx.x;
    atomicAdd(&gcnt[batch[i]], 1);
}

// ---------------- gemm1: [64 x 128] @ [128 x 64] -> fp16 ----------------
__global__ __launch_bounds__(256) void k_gemm1(const float* __restrict__ A,
                                               const float* __restrict__ W,
                                               __half* __restrict__ out) {
    __shared__ float as[64 * 128];
    __shared__ float ws[128 * 64];
    int tid = threadIdx.x;
    long row0 = (long)blockIdx.x * 64;
    const float4* Ag = (const float4*)(A + row0 * 128);
    float4* As4 = (float4*)as;
#pragma unroll
    for (int i = 0; i < 8; ++i) As4[tid + i * 256] = Ag[tid + i * 256];
    const float4* Wg = (const float4*)W;
    float4* Ws4 = (float4*)ws;
#pragma unroll
    for (int i = 0; i < 8; ++i) Ws4[tid + i * 256] = Wg[tid + i * 256];
    __syncthreads();
    int ty = tid >> 4, tx = tid & 15;
    float acc[4][4] = {};
    for (int k = 0; k < 128; ++k) {
        float a0 = as[(ty * 4 + 0) * 128 + k];
        float a1 = as[(ty * 4 + 1) * 128 + k];
        float a2 = as[(ty * 4 + 2) * 128 + k];
        float a3 = as[(ty * 4 + 3) * 128 + k];
#pragma unroll
        for (int j = 0; j < 4; ++j) {
            float w = ws[k * 64 + tx * 4 + j];
            acc[0][j] = fmaf(a0, w, acc[0][j]);
            acc[1][j] = fmaf(a1, w, acc[1][j]);
            acc[2][j] = fmaf(a2, w, acc[2][j]);
            acc[3][j] = fmaf(a3, w, acc[3][j]);
        }
    }
#pragma unroll
    for (int i = 0; i < 4; ++i) {
        __half2* op = (__half2*)(out + (row0 + ty * 4 + i) * 64 + tx * 4);
        op[0] = __floats2half2_rn(acc[i][0], acc[i][1]);
        op[1] = __floats2half2_rn(acc[i][2], acc[i][3]);
    }
}

// ---------------- gemm2: fp16 [64 x 64] @ f32 [64 x 128] -> fp16 + fused BN stats partials ----------------
__global__ __launch_bounds__(256) void k_gemm2(const __half* __restrict__ A,
                                               const float* __restrict__ W,
                                               __half* __restrict__ out,
                                               float* __restrict__ pS, float* __restrict__ pQ) {
    __shared__ float as[64 * 64];
    __shared__ float ws[64 * 128];
    __shared__ float red[16][128];
    int tid = threadIdx.x;
    long row0 = (long)blockIdx.x * 64;
    // stage A (half -> float)
#pragma unroll
    for (int i = 0; i < 2; ++i) {
        int idx = tid + i * 256;                      // 8 halves each
        int4 v = ((const int4*)(A + row0 * 64))[idx];
        __half2* hp = (__half2*)&v;
#pragma unroll
        for (int j = 0; j < 4; ++j) {
            float2 f = __half22float2(hp[j]);
            as[idx * 8 + j * 2] = f.x;
            as[idx * 8 + j * 2 + 1] = f.y;
        }
    }
    const float4* Wg = (const float4*)W;
    float4* Ws4 = (float4*)ws;
#pragma unroll
    for (int i = 0; i < 8; ++i) Ws4[tid + i * 256] = Wg[tid + i * 256];
    __syncthreads();
    int ty = tid >> 4, tx = tid & 15;
    float acc[4][8] = {};
    for (int k = 0; k < 64; ++k) {
        float a0 = as[(ty * 4 + 0) * 64 + k];
        float a1 = as[(ty * 4 + 1) * 64 + k];
        float a2 = as[(ty * 4 + 2) * 64 + k];
        float a3 = as[(ty * 4 + 3) * 64 + k];
#pragma unroll
        for (int j = 0; j < 8; ++j) {
            float w = ws[k * 128 + tx * 8 + j];
            acc[0][j] = fmaf(a0, w, acc[0][j]);
            acc[1][j] = fmaf(a1, w, acc[1][j]);
            acc[2][j] = fmaf(a2, w, acc[2][j]);
            acc[3][j] = fmaf(a3, w, acc[3][j]);
        }
    }
#pragma unroll
    for (int i = 0; i < 4; ++i) {
        __half2* op = (__half2*)(out + (row0 + ty * 4 + i) * 128 + tx * 8);
#pragma unroll
        for (int j = 0; j < 4; ++j)
            op[j] = __floats2half2_rn(acc[i][j * 2], acc[i][j * 2 + 1]);
    }
    // fused column stats (sum / sumsq over 64 rows)
    float cs[8], cq[8];
#pragma unroll
    for (int j = 0; j < 8; ++j) {
        cs[j] = acc[0][j] + acc[1][j] + acc[2][j] + acc[3][j];
        cq[j] = acc[0][j] * acc[0][j] + acc[1][j] * acc[1][j] +
                acc[2][j] * acc[2][j] + acc[3][j] * acc[3][j];
    }
#pragma unroll
    for (int j = 0; j < 8; ++j) red[ty][tx * 8 + j] = cs[j];
    __syncthreads();
    if (tid < 128) {
        float s = 0.f;
#pragma unroll
        for (int t = 0; t < 16; ++t) s += red[t][tid];
        pS[blockIdx.x * 128 + tid] = s;
    }
    __syncthreads();
#pragma unroll
    for (int j = 0; j < 8; ++j) red[ty][tx * 8 + j] = cq[j];
    __syncthreads();
    if (tid < 128) {
        float q = 0.f;
#pragma unroll
        for (int t = 0; t < 16; ++t) q += red[t][tid];
        pQ[blockIdx.x * 128 + tid] = q;
    }
}

__global__ void k_redstats(const float* __restrict__ pS, const float* __restrict__ pQ,
                           float* __restrict__ sums, float* __restrict__ sqs) {
    int c = threadIdx.x;
    int rbeg = blockIdx.x * 32;
    float a = 0.f;
    if (c < 128) {
        for (int r = 0; r < 32; ++r) a += pS[(rbeg + r) * 128 + c];
        atomicAdd(&sums[c], a);
    } else {
        int cc = c - 128;
        for (int r = 0; r < 32; ++r) a += pQ[(rbeg + r) * 128 + cc];
        atomicAdd(&sqs[cc], a);
    }
}

// ---------------- 64-channel CSR aggregation over fp16 features ----------------
template <typename OutT>
__global__ __launch_bounds__(256) void k_agg64h(const __half* __restrict__ feat,
                                                const int* __restrict__ offs,
                                                const int* __restrict__ srcs,
                                                const float* __restrict__ dinv,
                                                OutT* __restrict__ out) {
    int wid = (blockIdx.x * 256 + threadIdx.x) >> 6;
    int lane = threadIdx.x & 63;
    int beg = offs[wid], end = offs[wid + 1];
    float dn = dinv[wid];
    float acc = 0.f;
    int e = beg;
    for (; e + 4 <= end; e += 4) {
        int s0 = srcs[e], s1 = srcs[e + 1], s2 = srcs[e + 2], s3 = srcs[e + 3];
        float w0 = dinv[s0], w1 = dinv[s1], w2 = dinv[s2], w3 = dinv[s3];
        float f0 = __half2float(feat[(long)s0 * 64 + lane]);
        float f1 = __half2float(feat[(long)s1 * 64 + lane]);
        float f2 = __half2float(feat[(long)s2 * 64 + lane]);
        float f3 = __half2float(feat[(long)s3 * 64 + lane]);
        acc += f0 * w0 + f1 * w1 + f2 * w2 + f3 * w3;
    }
    for (; e < end; ++e) {
        int s = srcs[e];
        acc += __half2float(feat[(long)s * 64 + lane]) * dinv[s];
    }
    float r = acc * dn;
    if constexpr (sizeof(OutT) == 4)
        out[(long)wid * 64 + lane] = r;
    else
        out[(long)wid * 64 + lane] = __float2half(r);
}

// ---------------- BatchNorm (layer 1 stats over f32) ----------------
template <int C>
__global__ __launch_bounds__(256) void k_bn_stats(const float* __restrict__ h,
                                                  float* __restrict__ sums,
                                                  float* __restrict__ sqs) {
    __shared__ float lsum[256], lsq[256];
    const int RG = 256 / C;
    int tid = threadIdx.x;
    int c = tid % C;
    int rg = tid / C;
    int row0 = blockIdx.x * 256;
    float s = 0.f, q = 0.f;
    for (int i = rg; i < 256; i += RG) {
        float v = h[(long)(row0 + i) * C + c];
        s += v;
        q += v * v;
    }
    lsum[tid] = s; lsq[tid] = q;
    __syncthreads();
    if (tid < C) {
        float ts = 0.f, tq = 0.f;
#pragma unroll
        for (int g = 0; g < RG; ++g) { ts += lsum[g * C + c]; tq += lsq[g * C + c]; }
        atomicAdd(&sums[c], ts);
        atomicAdd(&sqs[c], tq);
    }
}
template <int C>
__global__ void k_bn_prep(const float* __restrict__ sums, const float* __restrict__ sqs,
                          const float* __restrict__ gamma, const float* __restrict__ beta,
                          float* __restrict__ scale, float* __restrict__ shift) {
    int c = threadIdx.x;
    if (c >= C) return;
    const float invN = 1.0f / (float)NN;
    float mean = sums[c] * invN;
    float var = sqs[c] * invN - mean * mean;
    float inv = rsqrtf(var + EPSV);
    float sc = gamma[c] * inv;
    scale[c] = sc;
    shift[c] = beta[c] - mean * sc;
}
// BN1 apply + leaky -> fp16
__global__ __launch_bounds__(256) void k_apply1(const float* __restrict__ h,
                                                const float* __restrict__ scale,
                                                const float* __restrict__ shift,
                                                __half* __restrict__ out) {
    long idx = (long)blockIdx.x * 256 + threadIdx.x;
    float4 v = ((const float4*)h)[idx];
    int cb = (int)((idx * 4) & 63);
    float r[4] = {v.x, v.y, v.z, v.w};
#pragma unroll
    for (int j = 0; j < 4; ++j) {
        float y = fmaf(r[j], scale[cb + j], shift[cb + j]);
        r[j] = y > 0.f ? y : 0.01f * y;
    }
    ((__half2*)out)[idx * 2] = __floats2half2_rn(r[0], r[1]);
    ((__half2*)out)[idx * 2 + 1] = __floats2half2_rn(r[2], r[3]);
}

// ---------------- pooling + BN2 + leaky + head, fused ----------------
__global__ __launch_bounds__(256) void k_pool(const __half* __restrict__ h,
                                              const int* __restrict__ goff,
                                              const int* __restrict__ gcnt,
                                              const float* __restrict__ scale,
                                              const float* __restrict__ shift,
                                              const float* __restrict__ Wo,
                                              const float* __restrict__ bo,
                                              float* __restrict__ out) {
    int g = (blockIdx.x * 256 + threadIdx.x) >> 6;
    int lane = threadIdx.x & 63;
    int beg = goff[g], cnt = gcnt[g];
    float sc0 = scale[2 * lane], sc1 = scale[2 * lane + 1];
    float sh0 = shift[2 * lane], sh1 = shift[2 * lane + 1];
    float a0 = 0.f, a1 = 0.f;
    for (int i = 0; i < cnt; ++i) {
        __half2 v = ((const __half2*)(h + (long)(beg + i) * 128))[lane];
        float2 f = __half22float2(v);
        float y0 = fmaf(f.x, sc0, sh0); y0 = y0 > 0.f ? y0 : 0.01f * y0;
        float y1 = fmaf(f.y, sc1, sh1); y1 = y1 > 0.f ? y1 : 0.01f * y1;
        a0 += y0; a1 += y1;
    }
    float v = a0 * Wo[2 * lane] + a1 * Wo[2 * lane + 1];
    v /= fmaxf((float)cnt, 1.f);
#pragma unroll
    for (int m = 32; m; m >>= 1) v += __shfl_xor(v, m);
    if (lane == 0) out[g] = v + bo[0];
}

extern "C" void kernel_launch(void* const* d_in, const int* in_sizes, int n_in,
                              void* d_out, int out_size, void* d_ws, size_t ws_size,
                              hipStream_t stream) {
    const float* x    = (const float*)d_in[0];
    const int* ei     = (const int*)d_in[1];
    const int* batch  = (const int*)d_in[2];
    const float* W1   = (const float*)d_in[3];
    const float* g1   = (const float*)d_in[5];
    const float* be1  = (const float*)d_in[6];
    const float* W2   = (const float*)d_in[7];
    const float* g2   = (const float*)d_in[9];
    const float* be2  = (const float*)d_in[10];
    const float* Wo   = (const float*)d_in[11];
    const float* bo   = (const float*)d_in[12];
    float* out = (float*)d_out;

    const int* esrc = ei;
    const int* edst = ei + NE;

    // ---- workspace layout ----
    __half* h2h = (__half*)d_ws;                   // [NN,128] half (33.5MB); alias: packed
    float* r12  = (float*)(h2h + (size_t)NN * 128);// [NN,64] f32 (33.5MB); alias: ghist*/pS/pQ
    __half* bufA = (__half*)(r12 + (size_t)NN * 64); // [NN,64] half: xw1h then agghh
    __half* bufB = bufA + (size_t)NN * 64;         // [NN,64] half: h1h
    float* dinv = (float*)(bufB + (size_t)NN * 64);// [NN]
    float* stats = dinv + NN;                      // 1024 floats
    float* sums1 = stats,        *sqs1 = stats + 64;
    float* sums2 = stats + 128,  *sqs2 = stats + 256;
    float* sc1   = stats + 384,  *sh1  = stats + 448;
    float* sc2   = stats + 512,  *sh2  = stats + 640;
    int* offs   = (int*)(stats + 1024);            // [NN+1]
    int* srcs   = offs + NN + 1;                   // [NT]
    int* bsums  = srcs + NT;                       // 256
    int* bsums2 = bsums + 256;                     // 256
    int* dummy  = bsums2 + 256;                    // 8
    int* gcnt   = dummy + 8;                       // [NG]
    int* goff   = gcnt + NG;                       // [NG]
    int* gb     = goff + NG;                       // 8
    int* gb_s   = gb + 8;                          // 8
    // temporal aliases
    int* ghist   = (int*)r12;                      // [CH][NB]   (consumed before agg1 writes r12)
    int* ghist_t = ghist + CH * NB;
    int* scanned = ghist_t + NB * CH;
    int* packed  = (int*)h2h;                      // [NE]       (consumed before gemm2 writes h2h)
    float* pS    = r12;                            // [2048][128] (r12 free after apply1)
    float* pQ    = r12 + 2048 * 128;

    hipMemsetAsync(stats, 0, 1024 * sizeof(float), stream);
    hipMemsetAsync(gcnt, 0, NG * sizeof(int), stream);

    // ---- CSR build ----
    k_chist<<<CH, 256, 0, stream>>>(edst, ghist);
    k_transpose<<<dim3(NB / 32, CH / 32), dim3(32, 8), 0, stream>>>(ghist, ghist_t);
    k_scan1<<<NB * CH / 1024, 1024, 0, stream>>>(ghist_t, scanned, bsums, NB * CH);
    k_scan1<<<1, 1024, 0, stream>>>(bsums, bsums2, dummy, NB * CH / 1024);
    k_scan_add<<<NB * CH / 1024, 1024, 0, stream>>>(scanned, bsums2, NB * CH);
    k_cscatter<<<CH, 256, 0, stream>>>(esrc, edst, scanned, packed);
    k_fine<<<NB, 256, 0, stream>>>(packed, scanned, offs, dinv, srcs);
    k_set_int<<<1, 1, 0, stream>>>(offs + NN, NT);

    // layer 1
    k_gemm1<<<NN / 64, 256, 0, stream>>>(x, W1, bufA);
    k_agg64h<float><<<NN / 4, 256, 0, stream>>>(bufA, offs, srcs, dinv, r12);
    k_bn_stats<64><<<NN / 256, 256, 0, stream>>>(r12, sums1, sqs1);
    k_bn_prep<64><<<1, 64, 0, stream>>>(sums1, sqs1, g1, be1, sc1, sh1);
    k_apply1<<<NN * 64 / 4 / 256, 256, 0, stream>>>(r12, sc1, sh1, bufB);

    // layer 2
    k_agg64h<__half><<<NN / 4, 256, 0, stream>>>(bufB, offs, srcs, dinv, bufA);
    k_gemm2<<<NN / 64, 256, 0, stream>>>(bufA, W2, h2h, pS, pQ);
    k_redstats<<<64, 256, 0, stream>>>(pS, pQ, sums2, sqs2);
    k_bn_prep<128><<<1, 128, 0, stream>>>(sums2, sqs2, g2, be2, sc2, sh2);

    // pooling (+BN2+leaky fused) + head
    k_gcount<<<NN / 256, 256, 0, stream>>>(batch, gcnt);
    k_scan1<<<NG / 1024, 1024, 0, stream>>>(gcnt, goff, gb, NG);
    k_scan1<<<1, 1024, 0, stream>>>(gb, gb_s, dummy, NG / 1024);
    k_scan_add<<<NG / 1024, 1024, 0, stream>>>(goff, gb_s, NG);
    k_pool<<<NG / 4, 256, 0, stream>>>(h2h, goff, gcnt, sc2, sh2, Wo, bo, out);
}

// Round 8
// 412.460 us; speedup vs baseline: 1.7110x; 1.0074x over previous
//
#include <hip/hip_runtime.h>
#include <hip/hip_fp16.h>

#define NN 131072
#define NE 2097152
#define NT (NE + NN)      // edges + self loops
#define NG 2048
#define NB 1024           // coarse buckets (dst >> 7)
#define CH 256            // chunks
#define ECH (NE / CH)     // 8192 edges per chunk
#define EPSV 1e-5f

// ---------------- generic scan helpers ----------------
__global__ void k_scan1(const int* __restrict__ in, int* __restrict__ out,
                        int* __restrict__ bsums, int n) {
    __shared__ int tmp[1024];
    int t = threadIdx.x;
    int gid = blockIdx.x * 1024 + t;
    int v = (gid < n) ? in[gid] : 0;
    tmp[t] = v;
    __syncthreads();
    for (int off = 1; off < 1024; off <<= 1) {
        int add = (t >= off) ? tmp[t - off] : 0;
        __syncthreads();
        tmp[t] += add;
        __syncthreads();
    }
    if (gid < n) out[gid] = tmp[t] - v;       // exclusive
    if (t == 1023) bsums[blockIdx.x] = tmp[t];
}
__global__ void k_scan_add(int* __restrict__ out, const int* __restrict__ bs, int n) {
    int gid = blockIdx.x * 1024 + threadIdx.x;
    if (gid < n) out[gid] += bs[blockIdx.x];
}
__global__ void k_set_int(int* p, int v) { *p = v; }

// ---------------- CSR build: stable two-level counting sort ----------------
__global__ __launch_bounds__(256) void k_chist(const int* __restrict__ dst, int* __restrict__ ghist) {
    __shared__ int h[NB];
    int c = blockIdx.x, tid = threadIdx.x;
    for (int i = tid; i < NB; i += 256) h[i] = 0;
    __syncthreads();
    const int* d = dst + (long)c * ECH;
    for (int i = tid; i < ECH; i += 256) atomicAdd(&h[d[i] >> 7], 1);
    __syncthreads();
    int* o = ghist + (long)c * NB;
    for (int i = tid; i < NB; i += 256) o[i] = h[i];
}
__global__ void k_transpose(const int* __restrict__ in, int* __restrict__ out) {
    __shared__ int tile[32][33];
    int x = blockIdx.x * 32 + threadIdx.x;
    int y0 = blockIdx.y * 32 + threadIdx.y;
    for (int i = 0; i < 32; i += 8)
        tile[threadIdx.y + i][threadIdx.x] = in[(y0 + i) * NB + x];
    __syncthreads();
    int ox = blockIdx.y * 32 + threadIdx.x;
    int oy0 = blockIdx.x * 32 + threadIdx.y;
    for (int i = 0; i < 32; i += 8)
        out[(oy0 + i) * CH + ox] = tile[threadIdx.x][threadIdx.y + i];
}
__global__ __launch_bounds__(256) void k_cscatter(const int* __restrict__ src, const int* __restrict__ dst,
                                                  const int* __restrict__ scanned, int* __restrict__ packed) {
    __shared__ int cur[NB];
    int c = blockIdx.x, tid = threadIdx.x;
    for (int i = tid; i < NB; i += 256) cur[i] = scanned[i * CH + c];
    __syncthreads();
    const int* s = src + (long)c * ECH;
    const int* d = dst + (long)c * ECH;
    for (int i = tid; i < ECH; i += 256) {
        int dv = d[i], sv = s[i];
        int p = atomicAdd(&cur[dv >> 7], 1);
        packed[p] = sv | ((dv & 127) << 17);
    }
}
__global__ __launch_bounds__(256) void k_fine(const int* __restrict__ packed,
                                              const int* __restrict__ scanned,
                                              int* __restrict__ offs, float* __restrict__ dinv,
                                              int* __restrict__ srcs) {
    __shared__ int hist[128], sc[128], cursor[128];
    int b = blockIdx.x, tid = threadIdx.x;
    int ebeg = scanned[b * CH];
    int eend = (b == NB - 1) ? NE : scanned[(b + 1) * CH];
    if (tid < 128) hist[tid] = 0;
    __syncthreads();
    for (int e = ebeg + tid; e < eend; e += 256)
        atomicAdd(&hist[packed[e] >> 17], 1);
    __syncthreads();
    if (tid < 128) sc[tid] = hist[tid] + 1;
    __syncthreads();
    for (int off = 1; off < 128; off <<= 1) {
        int v = 0;
        if (tid < 128 && tid >= off) v = sc[tid - off];
        __syncthreads();
        if (tid < 128) sc[tid] += v;
        __syncthreads();
    }
    int base = ebeg + b * 128;
    if (tid < 128) {
        int cnt = hist[tid] + 1;
        int ex = sc[tid] - cnt;
        int n = (b << 7) | tid;
        offs[n] = base + ex;
        dinv[n] = rsqrtf((float)cnt);
        srcs[base + ex] = n;
        cursor[tid] = ex + 1;
    }
    __syncthreads();
    for (int e = ebeg + tid; e < eend; e += 256) {
        int p = packed[e];
        int pos = atomicAdd(&cursor[p >> 17], 1);
        srcs[base + pos] = p & 131071;
    }
}
__global__ void k_gcount(const int* __restrict__ batch, int* __restrict__ gcnt) {
    int i = blockIdx.x * 256 + threadIdx.x;
    atomicAdd(&gcnt[batch[i]], 1);
}

// ---------------- gemm1: [64 x 128] @ [128 x 64] -> fp16, pre-scaled by dinv[row] ----------------
__global__ __launch_bounds__(256) void k_gemm1(const float* __restrict__ A,
                                               const float* __restrict__ W,
                                               const float* __restrict__ dinv,
                                               __half* __restrict__ out) {
    __shared__ float as[64 * 128];
    __shared__ float ws[128 * 64];
    int tid = threadIdx.x;
    long row0 = (long)blockIdx.x * 64;
    const float4* Ag = (const float4*)(A + row0 * 128);
    float4* As4 = (float4*)as;
#pragma unroll
    for (int i = 0; i < 8; ++i) As4[tid + i * 256] = Ag[tid + i * 256];
    const float4* Wg = (const float4*)W;
    float4* Ws4 = (float4*)ws;
#pragma unroll
    for (int i = 0; i < 8; ++i) Ws4[tid + i * 256] = Wg[tid + i * 256];
    __syncthreads();
    int ty = tid >> 4, tx = tid & 15;
    float acc[4][4] = {};
    for (int k = 0; k < 128; ++k) {
        float a0 = as[(ty * 4 + 0) * 128 + k];
        float a1 = as[(ty * 4 + 1) * 128 + k];
        float a2 = as[(ty * 4 + 2) * 128 + k];
        float a3 = as[(ty * 4 + 3) * 128 + k];
#pragma unroll
        for (int j = 0; j < 4; ++j) {
            float w = ws[k * 64 + tx * 4 + j];
            acc[0][j] = fmaf(a0, w, acc[0][j]);
            acc[1][j] = fmaf(a1, w, acc[1][j]);
            acc[2][j] = fmaf(a2, w, acc[2][j]);
            acc[3][j] = fmaf(a3, w, acc[3][j]);
        }
    }
#pragma unroll
    for (int i = 0; i < 4; ++i) {
        float dv = dinv[row0 + ty * 4 + i];
        __half2* op = (__half2*)(out + (row0 + ty * 4 + i) * 64 + tx * 4);
        op[0] = __floats2half2_rn(acc[i][0] * dv, acc[i][1] * dv);
        op[1] = __floats2half2_rn(acc[i][2] * dv, acc[i][3] * dv);
    }
}

// ---------------- gemm2: fp16 [64 x 64] @ f32 [64 x 128] -> fp16 + fused BN stats partials ----------------
__global__ __launch_bounds__(256) void k_gemm2(const __half* __restrict__ A,
                                               const float* __restrict__ W,
                                               __half* __restrict__ out,
                                               float* __restrict__ pS, float* __restrict__ pQ) {
    __shared__ float as[64 * 64];
    __shared__ float ws[64 * 128];
    __shared__ float red[16][128];
    int tid = threadIdx.x;
    long row0 = (long)blockIdx.x * 64;
#pragma unroll
    for (int i = 0; i < 2; ++i) {
        int idx = tid + i * 256;                      // 8 halves each
        int4 v = ((const int4*)(A + row0 * 64))[idx];
        __half2* hp = (__half2*)&v;
#pragma unroll
        for (int j = 0; j < 4; ++j) {
            float2 f = __half22float2(hp[j]);
            as[idx * 8 + j * 2] = f.x;
            as[idx * 8 + j * 2 + 1] = f.y;
        }
    }
    const float4* Wg = (const float4*)W;
    float4* Ws4 = (float4*)ws;
#pragma unroll
    for (int i = 0; i < 8; ++i) Ws4[tid + i * 256] = Wg[tid + i * 256];
    __syncthreads();
    int ty = tid >> 4, tx = tid & 15;
    float acc[4][8] = {};
    for (int k = 0; k < 64; ++k) {
        float a0 = as[(ty * 4 + 0) * 64 + k];
        float a1 = as[(ty * 4 + 1) * 64 + k];
        float a2 = as[(ty * 4 + 2) * 64 + k];
        float a3 = as[(ty * 4 + 3) * 64 + k];
#pragma unroll
        for (int j = 0; j < 8; ++j) {
            float w = ws[k * 128 + tx * 8 + j];
            acc[0][j] = fmaf(a0, w, acc[0][j]);
            acc[1][j] = fmaf(a1, w, acc[1][j]);
            acc[2][j] = fmaf(a2, w, acc[2][j]);
            acc[3][j] = fmaf(a3, w, acc[3][j]);
        }
    }
#pragma unroll
    for (int i = 0; i < 4; ++i) {
        __half2* op = (__half2*)(out + (row0 + ty * 4 + i) * 128 + tx * 8);
#pragma unroll
        for (int j = 0; j < 4; ++j)
            op[j] = __floats2half2_rn(acc[i][j * 2], acc[i][j * 2 + 1]);
    }
    float cs[8], cq[8];
#pragma unroll
    for (int j = 0; j < 8; ++j) {
        cs[j] = acc[0][j] + acc[1][j] + acc[2][j] + acc[3][j];
        cq[j] = acc[0][j] * acc[0][j] + acc[1][j] * acc[1][j] +
                acc[2][j] * acc[2][j] + acc[3][j] * acc[3][j];
    }
#pragma unroll
    for (int j = 0; j < 8; ++j) red[ty][tx * 8 + j] = cs[j];
    __syncthreads();
    if (tid < 128) {
        float s = 0.f;
#pragma unroll
        for (int t = 0; t < 16; ++t) s += red[t][tid];
        pS[blockIdx.x * 128 + tid] = s;
    }
    __syncthreads();
#pragma unroll
    for (int j = 0; j < 8; ++j) red[ty][tx * 8 + j] = cq[j];
    __syncthreads();
    if (tid < 128) {
        float q = 0.f;
#pragma unroll
        for (int t = 0; t < 16; ++t) q += red[t][tid];
        pQ[blockIdx.x * 128 + tid] = q;
    }
}

__global__ void k_redstats(const float* __restrict__ pS, const float* __restrict__ pQ,
                           float* __restrict__ sums, float* __restrict__ sqs) {
    int c = threadIdx.x;
    int rbeg = blockIdx.x * 32;
    float a = 0.f;
    if (c < 128) {
        for (int r = 0; r < 32; ++r) a += pS[(rbeg + r) * 128 + c];
        atomicAdd(&sums[c], a);
    } else {
        int cc = c - 128;
        for (int r = 0; r < 32; ++r) a += pQ[(rbeg + r) * 128 + cc];
        atomicAdd(&sqs[cc], a);
    }
}

// ---------------- CSR aggregation: feat pre-scaled by dinv[src]; 2 edges/wave-issue ----------------
// lanes 0-31 handle even edges, 32-63 odd edges; each lane reads half2 (2 channels)
__global__ __launch_bounds__(256) void k_agg(const __half2* __restrict__ feat2,
                                             const int* __restrict__ offs,
                                             const int* __restrict__ srcs,
                                             const float* __restrict__ dinv,
                                             __half2* __restrict__ out) {
    int wid = (blockIdx.x * 256 + threadIdx.x) >> 6;   // one wave per dst node
    int lane = threadIdx.x & 63;
    int hi = lane >> 5;
    int c = lane & 31;
    int beg = offs[wid], end = offs[wid + 1];
    float ax = 0.f, ay = 0.f;
    int e = beg + hi;
    for (; e + 2 < end; e += 4) {
        int s0 = srcs[e], s1 = srcs[e + 2];
        float2 f0 = __half22float2(feat2[(long)s0 * 32 + c]);
        float2 f1 = __half22float2(feat2[(long)s1 * 32 + c]);
        ax += f0.x + f1.x;
        ay += f0.y + f1.y;
    }
    if (e < end) {
        int s = srcs[e];
        float2 f = __half22float2(feat2[(long)s * 32 + c]);
        ax += f.x;
        ay += f.y;
    }
    ax += __shfl_xor(ax, 32);
    ay += __shfl_xor(ay, 32);
    if (hi == 0) {
        float dn = dinv[wid];
        out[(long)wid * 32 + c] = __floats2half2_rn(ax * dn, ay * dn);
    }
}

// ---------------- BN1 stats over fp16 h1 ----------------
__global__ __launch_bounds__(256) void k_stats64h(const __half2* __restrict__ h2,
                                                  float* __restrict__ sums, float* __restrict__ sqs) {
    __shared__ float sx[256], sy[256], qx[256], qy[256];
    int tid = threadIdx.x;
    int c = tid & 31, rg = tid >> 5;
    long row0 = (long)blockIdx.x * 1024;
    float ax = 0.f, ay = 0.f, bx = 0.f, by = 0.f;
    for (int i = rg; i < 1024; i += 8) {
        float2 f = __half22float2(h2[(row0 + i) * 32 + c]);
        ax += f.x; ay += f.y; bx += f.x * f.x; by += f.y * f.y;
    }
    sx[tid] = ax; sy[tid] = ay; qx[tid] = bx; qy[tid] = by;
    __syncthreads();
    if (tid < 32) {
        float tax = 0.f, tay = 0.f, tbx = 0.f, tby = 0.f;
#pragma unroll
        for (int g = 0; g < 8; ++g) {
            tax += sx[g * 32 + tid]; tay += sy[g * 32 + tid];
            tbx += qx[g * 32 + tid]; tby += qy[g * 32 + tid];
        }
        atomicAdd(&sums[2 * tid], tax); atomicAdd(&sums[2 * tid + 1], tay);
        atomicAdd(&sqs[2 * tid], tbx);  atomicAdd(&sqs[2 * tid + 1], tby);
    }
}
template <int C>
__global__ void k_bn_prep(const float* __restrict__ sums, const float* __restrict__ sqs,
                          const float* __restrict__ gamma, const float* __restrict__ beta,
                          float* __restrict__ scale, float* __restrict__ shift) {
    int c = threadIdx.x;
    if (c >= C) return;
    const float invN = 1.0f / (float)NN;
    float mean = sums[c] * invN;
    float var = sqs[c] * invN - mean * mean;
    float inv = rsqrtf(var + EPSV);
    float sc = gamma[c] * inv;
    scale[c] = sc;
    shift[c] = beta[c] - mean * sc;
}
// BN1 apply + leaky + dinv[row] pre-scale, fp16 in/out (in-place safe)
__global__ __launch_bounds__(256) void k_apply1h(const __half* __restrict__ h,
                                                 const float* __restrict__ scale,
                                                 const float* __restrict__ shift,
                                                 const float* __restrict__ dinv,
                                                 __half* __restrict__ out) {
    long idx = (long)blockIdx.x * 256 + threadIdx.x;   // unit: 8 halves
    int row = (int)(idx >> 3);
    int cb = (int)(idx & 7) * 8;
    float dv = dinv[row];
    int4 v = ((const int4*)h)[idx];
    __half2* hp = (__half2*)&v;
    int4 o;
    __half2* op = (__half2*)&o;
#pragma unroll
    for (int j = 0; j < 4; ++j) {
        float2 f = __half22float2(hp[j]);
        float y0 = fmaf(f.x, scale[cb + 2 * j], shift[cb + 2 * j]);
        float y1 = fmaf(f.y, scale[cb + 2 * j + 1], shift[cb + 2 * j + 1]);
        y0 = y0 > 0.f ? y0 : 0.01f * y0;
        y1 = y1 > 0.f ? y1 : 0.01f * y1;
        op[j] = __floats2half2_rn(y0 * dv, y1 * dv);
    }
    ((int4*)out)[idx] = o;
}

// ---------------- pooling + BN2 + leaky + head, fused ----------------
__global__ __launch_bounds__(256) void k_pool(const __half* __restrict__ h,
                                              const int* __restrict__ goff,
                                              const int* __restrict__ gcnt,
                                              const float* __restrict__ scale,
                                              const float* __restrict__ shift,
                                              const float* __restrict__ Wo,
                                              const float* __restrict__ bo,
                                              float* __restrict__ out) {
    int g = (blockIdx.x * 256 + threadIdx.x) >> 6;
    int lane = threadIdx.x & 63;
    int beg = goff[g], cnt = gcnt[g];
    float sc0 = scale[2 * lane], sc1 = scale[2 * lane + 1];
    float sh0 = shift[2 * lane], sh1 = shift[2 * lane + 1];
    float a0 = 0.f, a1 = 0.f;
    for (int i = 0; i < cnt; ++i) {
        __half2 v = ((const __half2*)(h + (long)(beg + i) * 128))[lane];
        float2 f = __half22float2(v);
        float y0 = fmaf(f.x, sc0, sh0); y0 = y0 > 0.f ? y0 : 0.01f * y0;
        float y1 = fmaf(f.y, sc1, sh1); y1 = y1 > 0.f ? y1 : 0.01f * y1;
        a0 += y0; a1 += y1;
    }
    float v = a0 * Wo[2 * lane] + a1 * Wo[2 * lane + 1];
    v /= fmaxf((float)cnt, 1.f);
#pragma unroll
    for (int m = 32; m; m >>= 1) v += __shfl_xor(v, m);
    if (lane == 0) out[g] = v + bo[0];
}

extern "C" void kernel_launch(void* const* d_in, const int* in_sizes, int n_in,
                              void* d_out, int out_size, void* d_ws, size_t ws_size,
                              hipStream_t stream) {
    const float* x    = (const float*)d_in[0];
    const int* ei     = (const int*)d_in[1];
    const int* batch  = (const int*)d_in[2];
    const float* W1   = (const float*)d_in[3];
    const float* g1   = (const float*)d_in[5];
    const float* be1  = (const float*)d_in[6];
    const float* W2   = (const float*)d_in[7];
    const float* g2   = (const float*)d_in[9];
    const float* be2  = (const float*)d_in[10];
    const float* Wo   = (const float*)d_in[11];
    const float* bo   = (const float*)d_in[12];
    float* out = (float*)d_out;

    const int* esrc = ei;
    const int* edst = ei + NE;

    // ---- workspace layout ----
    __half* h2h = (__half*)d_ws;                   // [NN,128] half (33.5MB); alias: packed
    __half* bufA = h2h + (size_t)NN * 128;         // [NN,64] half; alias: ghist chain
    __half* bufB = bufA + (size_t)NN * 64;         // [NN,64] half
    float* dinv = (float*)(bufB + (size_t)NN * 64);// [NN]
    float* stats = dinv + NN;                      // 1024 floats
    float* sums1 = stats,        *sqs1 = stats + 64;
    float* sums2 = stats + 128,  *sqs2 = stats + 256;
    float* sc1   = stats + 384,  *sh1  = stats + 448;
    float* sc2   = stats + 512,  *sh2  = stats + 640;
    int* offs   = (int*)(stats + 1024);            // [NN+1]
    int* srcs   = offs + NN + 1;                   // [NT]
    int* bsums  = srcs + NT;                       // 256
    int* bsums2 = bsums + 256;                     // 256
    int* dummy  = bsums2 + 256;                    // 8
    int* gcnt   = dummy + 8;                       // [NG]
    int* goff   = gcnt + NG;                       // [NG]
    int* gb     = goff + NG;                       // 8
    int* gb_s   = gb + 8;                          // 8
    float* pS   = (float*)(gb_s + 8);              // [2048][128]
    float* pQ   = pS + 2048 * 128;                 // [2048][128]
    // temporal aliases
    int* ghist   = (int*)bufA;                     // [CH][NB]  (consumed before gemm1 writes bufA)
    int* ghist_t = ghist + CH * NB;
    int* scanned = ghist_t + NB * CH;
    int* packed  = (int*)h2h;                      // [NE]      (consumed before gemm2 writes h2h)

    hipMemsetAsync(stats, 0, 1024 * sizeof(float), stream);
    hipMemsetAsync(gcnt, 0, NG * sizeof(int), stream);

    // ---- CSR build ----
    k_chist<<<CH, 256, 0, stream>>>(edst, ghist);
    k_transpose<<<dim3(NB / 32, CH / 32), dim3(32, 8), 0, stream>>>(ghist, ghist_t);
    k_scan1<<<NB * CH / 1024, 1024, 0, stream>>>(ghist_t, scanned, bsums, NB * CH);
    k_scan1<<<1, 1024, 0, stream>>>(bsums, bsums2, dummy, NB * CH / 1024);
    k_scan_add<<<NB * CH / 1024, 1024, 0, stream>>>(scanned, bsums2, NB * CH);
    k_cscatter<<<CH, 256, 0, stream>>>(esrc, edst, scanned, packed);
    k_fine<<<NB, 256, 0, stream>>>(packed, scanned, offs, dinv, srcs);
    k_set_int<<<1, 1, 0, stream>>>(offs + NN, NT);

    // layer 1: xw1' = (x @ W1) * dinv[row]  (fp16)
    k_gemm1<<<NN / 64, 256, 0, stream>>>(x, W1, dinv, bufA);
    k_agg<<<NN / 4, 256, 0, stream>>>((const __half2*)bufA, offs, srcs, dinv, (__half2*)bufB);
    k_stats64h<<<NN / 1024, 256, 0, stream>>>((const __half2*)bufB, sums1, sqs1);
    k_bn_prep<64><<<1, 64, 0, stream>>>(sums1, sqs1, g1, be1, sc1, sh1);
    k_apply1h<<<NN * 64 / 8 / 256, 256, 0, stream>>>(bufB, sc1, sh1, dinv, bufB);

    // layer 2: agg in 64ch, then gemm2 (+fused BN2 stats)
    k_agg<<<NN / 4, 256, 0, stream>>>((const __half2*)bufB, offs, srcs, dinv, (__half2*)bufA);
    k_gemm2<<<NN / 64, 256, 0, stream>>>(bufA, W2, h2h, pS, pQ);
    k_redstats<<<64, 256, 0, stream>>>(pS, pQ, sums2, sqs2);
    k_bn_prep<128><<<1, 128, 0, stream>>>(sums2, sqs2, g2, be2, sc2, sh2);

    // pooling (+BN2+leaky fused) + head
    k_gcount<<<NN / 256, 256, 0, stream>>>(batch, gcnt);
    k_scan1<<<NG / 1024, 1024, 0, stream>>>(gcnt, goff, gb, NG);
    k_scan1<<<1, 1024, 0, stream>>>(gb, gb_s, dummy, NG / 1024);
    k_scan_add<<<NG / 1024, 1024, 0, stream>>>(goff, gb_s, NG);
    k_pool<<<NG / 4, 256, 0, stream>>>(h2h, goff, gcnt, sc2, sh2, Wo, bo, out);
}

// Round 9
// 396.567 us; speedup vs baseline: 1.7796x; 1.0401x over previous
//
#include <hip/hip_runtime.h>
#include <hip/hip_fp16.h>

#define NN 131072
#define NE 2097152
#define NT (NE + NN)      // edges + self loops
#define NG 2048
#define NB 1024           // coarse buckets (dst >> 7)
#define CH 256            // chunks
#define ECH (NE / CH)     // 8192 edges per chunk
#define EPSV 1e-5f

// ---------------- generic scan helpers ----------------
__global__ void k_scan1(const int* __restrict__ in, int* __restrict__ out,
                        int* __restrict__ bsums, int n) {
    __shared__ int tmp[1024];
    int t = threadIdx.x;
    int gid = blockIdx.x * 1024 + t;
    int v = (gid < n) ? in[gid] : 0;
    tmp[t] = v;
    __syncthreads();
    for (int off = 1; off < 1024; off <<= 1) {
        int add = (t >= off) ? tmp[t - off] : 0;
        __syncthreads();
        tmp[t] += add;
        __syncthreads();
    }
    if (gid < n) out[gid] = tmp[t] - v;       // exclusive
    if (t == 1023) bsums[blockIdx.x] = tmp[t];
}
__global__ void k_scan_add(int* __restrict__ out, const int* __restrict__ bs, int n) {
    int gid = blockIdx.x * 1024 + threadIdx.x;
    if (gid < n) out[gid] += bs[blockIdx.x];
}
__global__ void k_set_int(int* p, int v) { *p = v; }

// ---------------- CSR build: stable two-level counting sort ----------------
__global__ __launch_bounds__(256) void k_chist(const int* __restrict__ dst, int* __restrict__ ghist) {
    __shared__ int h[NB];
    int c = blockIdx.x, tid = threadIdx.x;
    for (int i = tid; i < NB; i += 256) h[i] = 0;
    __syncthreads();
    const int* d = dst + (long)c * ECH;
    for (int i = tid; i < ECH; i += 256) atomicAdd(&h[d[i] >> 7], 1);
    __syncthreads();
    int* o = ghist + (long)c * NB;
    for (int i = tid; i < NB; i += 256) o[i] = h[i];
}
__global__ void k_transpose(const int* __restrict__ in, int* __restrict__ out) {
    __shared__ int tile[32][33];
    int x = blockIdx.x * 32 + threadIdx.x;
    int y0 = blockIdx.y * 32 + threadIdx.y;
    for (int i = 0; i < 32; i += 8)
        tile[threadIdx.y + i][threadIdx.x] = in[(y0 + i) * NB + x];
    __syncthreads();
    int ox = blockIdx.y * 32 + threadIdx.x;
    int oy0 = blockIdx.x * 32 + threadIdx.y;
    for (int i = 0; i < 32; i += 8)
        out[(oy0 + i) * CH + ox] = tile[threadIdx.x][threadIdx.y + i];
}
__global__ __launch_bounds__(256) void k_cscatter(const int* __restrict__ src, const int* __restrict__ dst,
                                                  const int* __restrict__ scanned, int* __restrict__ packed) {
    __shared__ int cur[NB];
    int c = blockIdx.x, tid = threadIdx.x;
    for (int i = tid; i < NB; i += 256) cur[i] = scanned[i * CH + c];
    __syncthreads();
    const int* s = src + (long)c * ECH;
    const int* d = dst + (long)c * ECH;
    for (int i = tid; i < ECH; i += 256) {
        int dv = d[i], sv = s[i];
        int p = atomicAdd(&cur[dv >> 7], 1);
        packed[p] = sv | ((dv & 127) << 17);
    }
}
__global__ __launch_bounds__(256) void k_fine(const int* __restrict__ packed,
                                              const int* __restrict__ scanned,
                                              int* __restrict__ offs, float* __restrict__ dinv,
                                              int* __restrict__ srcs) {
    __shared__ int hist[128], sc[128], cursor[128];
    int b = blockIdx.x, tid = threadIdx.x;
    int ebeg = scanned[b * CH];
    int eend = (b == NB - 1) ? NE : scanned[(b + 1) * CH];
    if (tid < 128) hist[tid] = 0;
    __syncthreads();
    for (int e = ebeg + tid; e < eend; e += 256)
        atomicAdd(&hist[packed[e] >> 17], 1);
    __syncthreads();
    if (tid < 128) sc[tid] = hist[tid] + 1;
    __syncthreads();
    for (int off = 1; off < 128; off <<= 1) {
        int v = 0;
        if (tid < 128 && tid >= off) v = sc[tid - off];
        __syncthreads();
        if (tid < 128) sc[tid] += v;
        __syncthreads();
    }
    int base = ebeg + b * 128;
    if (tid < 128) {
        int cnt = hist[tid] + 1;
        int ex = sc[tid] - cnt;
        int n = (b << 7) | tid;
        offs[n] = base + ex;
        dinv[n] = rsqrtf((float)cnt);
        srcs[base + ex] = n;
        cursor[tid] = ex + 1;
    }
    __syncthreads();
    for (int e = ebeg + tid; e < eend; e += 256) {
        int p = packed[e];
        int pos = atomicAdd(&cursor[p >> 17], 1);
        srcs[base + pos] = p & 131071;
    }
}
__global__ void k_gcount(const int* __restrict__ batch, int* __restrict__ gcnt) {
    int i = blockIdx.x * 256 + threadIdx.x;
    atomicAdd(&gcnt[batch[i]], 1);
}

// ---------------- gemm1: [64 x 128] @ [128 x 64] -> fp16, pre-scaled by dinv[row] ----------------
__global__ __launch_bounds__(256) void k_gemm1(const float* __restrict__ A,
                                               const float* __restrict__ W,
                                               const float* __restrict__ dinv,
                                               __half* __restrict__ out) {
    __shared__ float as[64 * 128];
    __shared__ float ws[128 * 64];
    int tid = threadIdx.x;
    long row0 = (long)blockIdx.x * 64;
    const float4* Ag = (const float4*)(A + row0 * 128);
    float4* As4 = (float4*)as;
#pragma unroll
    for (int i = 0; i < 8; ++i) As4[tid + i * 256] = Ag[tid + i * 256];
    const float4* Wg = (const float4*)W;
    float4* Ws4 = (float4*)ws;
#pragma unroll
    for (int i = 0; i < 8; ++i) Ws4[tid + i * 256] = Wg[tid + i * 256];
    __syncthreads();
    int ty = tid >> 4, tx = tid & 15;
    float acc[4][4] = {};
    for (int k = 0; k < 128; ++k) {
        float a0 = as[(ty * 4 + 0) * 128 + k];
        float a1 = as[(ty * 4 + 1) * 128 + k];
        float a2 = as[(ty * 4 + 2) * 128 + k];
        float a3 = as[(ty * 4 + 3) * 128 + k];
#pragma unroll
        for (int j = 0; j < 4; ++j) {
            float w = ws[k * 64 + tx * 4 + j];
            acc[0][j] = fmaf(a0, w, acc[0][j]);
            acc[1][j] = fmaf(a1, w, acc[1][j]);
            acc[2][j] = fmaf(a2, w, acc[2][j]);
            acc[3][j] = fmaf(a3, w, acc[3][j]);
        }
    }
#pragma unroll
    for (int i = 0; i < 4; ++i) {
        float dv = dinv[row0 + ty * 4 + i];
        __half2* op = (__half2*)(out + (row0 + ty * 4 + i) * 64 + tx * 4);
        op[0] = __floats2half2_rn(acc[i][0] * dv, acc[i][1] * dv);
        op[1] = __floats2half2_rn(acc[i][2] * dv, acc[i][3] * dv);
    }
}

// ---------------- gemm2: fp16 [64 x 64] @ f32 [64 x 128] -> fp16 + fused BN stats partials ----------------
__global__ __launch_bounds__(256) void k_gemm2(const __half* __restrict__ A,
                                               const float* __restrict__ W,
                                               __half* __restrict__ out,
                                               float* __restrict__ pS, float* __restrict__ pQ) {
    __shared__ float as[64 * 64];
    __shared__ float ws[64 * 128];
    __shared__ float red[16][128];
    int tid = threadIdx.x;
    long row0 = (long)blockIdx.x * 64;
#pragma unroll
    for (int i = 0; i < 2; ++i) {
        int idx = tid + i * 256;                      // 8 halves each
        int4 v = ((const int4*)(A + row0 * 64))[idx];
        __half2* hp = (__half2*)&v;
#pragma unroll
        for (int j = 0; j < 4; ++j) {
            float2 f = __half22float2(hp[j]);
            as[idx * 8 + j * 2] = f.x;
            as[idx * 8 + j * 2 + 1] = f.y;
        }
    }
    const float4* Wg = (const float4*)W;
    float4* Ws4 = (float4*)ws;
#pragma unroll
    for (int i = 0; i < 8; ++i) Ws4[tid + i * 256] = Wg[tid + i * 256];
    __syncthreads();
    int ty = tid >> 4, tx = tid & 15;
    float acc[4][8] = {};
    for (int k = 0; k < 64; ++k) {
        float a0 = as[(ty * 4 + 0) * 64 + k];
        float a1 = as[(ty * 4 + 1) * 64 + k];
        float a2 = as[(ty * 4 + 2) * 64 + k];
        float a3 = as[(ty * 4 + 3) * 64 + k];
#pragma unroll
        for (int j = 0; j < 8; ++j) {
            float w = ws[k * 128 + tx * 8 + j];
            acc[0][j] = fmaf(a0, w, acc[0][j]);
            acc[1][j] = fmaf(a1, w, acc[1][j]);
            acc[2][j] = fmaf(a2, w, acc[2][j]);
            acc[3][j] = fmaf(a3, w, acc[3][j]);
        }
    }
#pragma unroll
    for (int i = 0; i < 4; ++i) {
        __half2* op = (__half2*)(out + (row0 + ty * 4 + i) * 128 + tx * 8);
#pragma unroll
        for (int j = 0; j < 4; ++j)
            op[j] = __floats2half2_rn(acc[i][j * 2], acc[i][j * 2 + 1]);
    }
    float cs[8], cq[8];
#pragma unroll
    for (int j = 0; j < 8; ++j) {
        cs[j] = acc[0][j] + acc[1][j] + acc[2][j] + acc[3][j];
        cq[j] = acc[0][j] * acc[0][j] + acc[1][j] * acc[1][j] +
                acc[2][j] * acc[2][j] + acc[3][j] * acc[3][j];
    }
#pragma unroll
    for (int j = 0; j < 8; ++j) red[ty][tx * 8 + j] = cs[j];
    __syncthreads();
    if (tid < 128) {
        float s = 0.f;
#pragma unroll
        for (int t = 0; t < 16; ++t) s += red[t][tid];
        pS[blockIdx.x * 128 + tid] = s;
    }
    __syncthreads();
#pragma unroll
    for (int j = 0; j < 8; ++j) red[ty][tx * 8 + j] = cq[j];
    __syncthreads();
    if (tid < 128) {
        float q = 0.f;
#pragma unroll
        for (int t = 0; t < 16; ++t) q += red[t][tid];
        pQ[blockIdx.x * 128 + tid] = q;
    }
}

__global__ void k_redstats(const float* __restrict__ pS, const float* __restrict__ pQ,
                           float* __restrict__ sums, float* __restrict__ sqs) {
    int c = threadIdx.x;
    int rbeg = blockIdx.x * 32;
    float a = 0.f;
    if (c < 128) {
        for (int r = 0; r < 32; ++r) a += pS[(rbeg + r) * 128 + c];
        atomicAdd(&sums[c], a);
    } else {
        int cc = c - 128;
        for (int r = 0; r < 32; ++r) a += pQ[(rbeg + r) * 128 + cc];
        atomicAdd(&sqs[cc], a);
    }
}

// ---------------- CSR aggregation: feat pre-scaled by dinv[src]; 8 edges/iteration ----------------
// lanes 0-31 handle even edges, 32-63 odd edges; each lane reads half2 (2 channels);
// 4-deep unroll per half-wave => 8 independent feat loads in flight per wave.
__global__ __launch_bounds__(256) void k_agg(const __half2* __restrict__ feat2,
                                             const int* __restrict__ offs,
                                             const int* __restrict__ srcs,
                                             const float* __restrict__ dinv,
                                             __half2* __restrict__ out) {
    int wid = (blockIdx.x * 256 + threadIdx.x) >> 6;   // one wave per dst node
    int lane = threadIdx.x & 63;
    int hi = lane >> 5;
    int c = lane & 31;
    int beg = offs[wid], end = offs[wid + 1];
    float ax = 0.f, ay = 0.f;
    int e = beg + hi;
    for (; e + 6 < end; e += 8) {
        int s0 = srcs[e], s1 = srcs[e + 2], s2 = srcs[e + 4], s3 = srcs[e + 6];
        float2 f0 = __half22float2(feat2[(long)s0 * 32 + c]);
        float2 f1 = __half22float2(feat2[(long)s1 * 32 + c]);
        float2 f2 = __half22float2(feat2[(long)s2 * 32 + c]);
        float2 f3 = __half22float2(feat2[(long)s3 * 32 + c]);
        ax += (f0.x + f1.x) + (f2.x + f3.x);
        ay += (f0.y + f1.y) + (f2.y + f3.y);
    }
    for (; e + 2 < end; e += 4) {
        int s0 = srcs[e], s1 = srcs[e + 2];
        float2 f0 = __half22float2(feat2[(long)s0 * 32 + c]);
        float2 f1 = __half22float2(feat2[(long)s1 * 32 + c]);
        ax += f0.x + f1.x;
        ay += f0.y + f1.y;
    }
    if (e < end) {
        float2 f = __half22float2(feat2[(long)srcs[e] * 32 + c]);
        ax += f.x;
        ay += f.y;
    }
    ax += __shfl_xor(ax, 32);
    ay += __shfl_xor(ay, 32);
    if (hi == 0) {
        float dn = dinv[wid];
        out[(long)wid * 32 + c] = __floats2half2_rn(ax * dn, ay * dn);
    }
}

// ---------------- BN1 stats over fp16 h1 ----------------
__global__ __launch_bounds__(256) void k_stats64h(const __half2* __restrict__ h2,
                                                  float* __restrict__ sums, float* __restrict__ sqs) {
    __shared__ float sx[256], sy[256], qx[256], qy[256];
    int tid = threadIdx.x;
    int c = tid & 31, rg = tid >> 5;
    long row0 = (long)blockIdx.x * 1024;
    float ax = 0.f, ay = 0.f, bx = 0.f, by = 0.f;
    for (int i = rg; i < 1024; i += 8) {
        float2 f = __half22float2(h2[(row0 + i) * 32 + c]);
        ax += f.x; ay += f.y; bx += f.x * f.x; by += f.y * f.y;
    }
    sx[tid] = ax; sy[tid] = ay; qx[tid] = bx; qy[tid] = by;
    __syncthreads();
    if (tid < 32) {
        float tax = 0.f, tay = 0.f, tbx = 0.f, tby = 0.f;
#pragma unroll
        for (int g = 0; g < 8; ++g) {
            tax += sx[g * 32 + tid]; tay += sy[g * 32 + tid];
            tbx += qx[g * 32 + tid]; tby += qy[g * 32 + tid];
        }
        atomicAdd(&sums[2 * tid], tax); atomicAdd(&sums[2 * tid + 1], tay);
        atomicAdd(&sqs[2 * tid], tbx);  atomicAdd(&sqs[2 * tid + 1], tby);
    }
}
template <int C>
__global__ void k_bn_prep(const float* __restrict__ sums, const float* __restrict__ sqs,
                          const float* __restrict__ gamma, const float* __restrict__ beta,
                          float* __restrict__ scale, float* __restrict__ shift) {
    int c = threadIdx.x;
    if (c >= C) return;
    const float invN = 1.0f / (float)NN;
    float mean = sums[c] * invN;
    float var = sqs[c] * invN - mean * mean;
    float inv = rsqrtf(var + EPSV);
    float sc = gamma[c] * inv;
    scale[c] = sc;
    shift[c] = beta[c] - mean * sc;
}
// BN1 apply + leaky + dinv[row] pre-scale, fp16 in/out (in-place safe)
__global__ __launch_bounds__(256) void k_apply1h(const __half* __restrict__ h,
                                                 const float* __restrict__ scale,
                                                 const float* __restrict__ shift,
                                                 const float* __restrict__ dinv,
                                                 __half* __restrict__ out) {
    long idx = (long)blockIdx.x * 256 + threadIdx.x;   // unit: 8 halves
    int row = (int)(idx >> 3);
    int cb = (int)(idx & 7) * 8;
    float dv = dinv[row];
    int4 v = ((const int4*)h)[idx];
    __half2* hp = (__half2*)&v;
    int4 o;
    __half2* op = (__half2*)&o;
#pragma unroll
    for (int j = 0; j < 4; ++j) {
        float2 f = __half22float2(hp[j]);
        float y0 = fmaf(f.x, scale[cb + 2 * j], shift[cb + 2 * j]);
        float y1 = fmaf(f.y, scale[cb + 2 * j + 1], shift[cb + 2 * j + 1]);
        y0 = y0 > 0.f ? y0 : 0.01f * y0;
        y1 = y1 > 0.f ? y1 : 0.01f * y1;
        op[j] = __floats2half2_rn(y0 * dv, y1 * dv);
    }
    ((int4*)out)[idx] = o;
}

// ---------------- pooling + BN2 + leaky + head, fused ----------------
__global__ __launch_bounds__(256) void k_pool(const __half* __restrict__ h,
                                              const int* __restrict__ goff,
                                              const int* __restrict__ gcnt,
                                              const float* __restrict__ scale,
                                              const float* __restrict__ shift,
                                              const float* __restrict__ Wo,
                                              const float* __restrict__ bo,
                                              float* __restrict__ out) {
    int g = (blockIdx.x * 256 + threadIdx.x) >> 6;
    int lane = threadIdx.x & 63;
    int beg = goff[g], cnt = gcnt[g];
    float sc0 = scale[2 * lane], sc1 = scale[2 * lane + 1];
    float sh0 = shift[2 * lane], sh1 = shift[2 * lane + 1];
    float a0 = 0.f, a1 = 0.f;
    for (int i = 0; i < cnt; ++i) {
        __half2 v = ((const __half2*)(h + (long)(beg + i) * 128))[lane];
        float2 f = __half22float2(v);
        float y0 = fmaf(f.x, sc0, sh0); y0 = y0 > 0.f ? y0 : 0.01f * y0;
        float y1 = fmaf(f.y, sc1, sh1); y1 = y1 > 0.f ? y1 : 0.01f * y1;
        a0 += y0; a1 += y1;
    }
    float v = a0 * Wo[2 * lane] + a1 * Wo[2 * lane + 1];
    v /= fmaxf((float)cnt, 1.f);
#pragma unroll
    for (int m = 32; m; m >>= 1) v += __shfl_xor(v, m);
    if (lane == 0) out[g] = v + bo[0];
}

extern "C" void kernel_launch(void* const* d_in, const int* in_sizes, int n_in,
                              void* d_out, int out_size, void* d_ws, size_t ws_size,
                              hipStream_t stream) {
    const float* x    = (const float*)d_in[0];
    const int* ei     = (const int*)d_in[1];
    const int* batch  = (const int*)d_in[2];
    const float* W1   = (const float*)d_in[3];
    const float* g1   = (const float*)d_in[5];
    const float* be1  = (const float*)d_in[6];
    const float* W2   = (const float*)d_in[7];
    const float* g2   = (const float*)d_in[9];
    const float* be2  = (const float*)d_in[10];
    const float* Wo   = (const float*)d_in[11];
    const float* bo   = (const float*)d_in[12];
    float* out = (float*)d_out;

    const int* esrc = ei;
    const int* edst = ei + NE;

    // ---- workspace layout ----
    __half* h2h = (__half*)d_ws;                   // [NN,128] half (33.5MB); alias: packed
    __half* bufA = h2h + (size_t)NN * 128;         // [NN,64] half; alias: ghist chain
    __half* bufB = bufA + (size_t)NN * 64;         // [NN,64] half
    float* dinv = (float*)(bufB + (size_t)NN * 64);// [NN]
    float* stats = dinv + NN;                      // 1024 floats
    float* sums1 = stats,        *sqs1 = stats + 64;
    float* sums2 = stats + 128,  *sqs2 = stats + 256;
    float* sc1   = stats + 384,  *sh1  = stats + 448;
    float* sc2   = stats + 512,  *sh2  = stats + 640;
    int* offs   = (int*)(stats + 1024);            // [NN+1]
    int* srcs   = offs + NN + 1;                   // [NT]
    int* bsums  = srcs + NT;                       // 256
    int* bsums2 = bsums + 256;                     // 256
    int* dummy  = bsums2 + 256;                    // 8
    int* gcnt   = dummy + 8;                       // [NG]
    int* goff   = gcnt + NG;                       // [NG]
    int* gb     = goff + NG;                       // 8
    int* gb_s   = gb + 8;                          // 8
    float* pS   = (float*)(gb_s + 8);              // [2048][128]
    float* pQ   = pS + 2048 * 128;                 // [2048][128]
    // temporal aliases
    int* ghist   = (int*)bufA;                     // [CH][NB]  (consumed before gemm1 writes bufA)
    int* ghist_t = ghist + CH * NB;
    int* scanned = ghist_t + NB * CH;
    int* packed  = (int*)h2h;                      // [NE]      (consumed before gemm2 writes h2h)

    hipMemsetAsync(stats, 0, 1024 * sizeof(float), stream);
    hipMemsetAsync(gcnt, 0, NG * sizeof(int), stream);

    // ---- CSR build ----
    k_chist<<<CH, 256, 0, stream>>>(edst, ghist);
    k_transpose<<<dim3(NB / 32, CH / 32), dim3(32, 8), 0, stream>>>(ghist, ghist_t);
    k_scan1<<<NB * CH / 1024, 1024, 0, stream>>>(ghist_t, scanned, bsums, NB * CH);
    k_scan1<<<1, 1024, 0, stream>>>(bsums, bsums2, dummy, NB * CH / 1024);
    k_scan_add<<<NB * CH / 1024, 1024, 0, stream>>>(scanned, bsums2, NB * CH);
    k_cscatter<<<CH, 256, 0, stream>>>(esrc, edst, scanned, packed);
    k_fine<<<NB, 256, 0, stream>>>(packed, scanned, offs, dinv, srcs);
    k_set_int<<<1, 1, 0, stream>>>(offs + NN, NT);

    // layer 1: xw1' = (x @ W1) * dinv[row]  (fp16)
    k_gemm1<<<NN / 64, 256, 0, stream>>>(x, W1, dinv, bufA);
    k_agg<<<NN / 4, 256, 0, stream>>>((const __half2*)bufA, offs, srcs, dinv, (__half2*)bufB);
    k_stats64h<<<NN / 1024, 256, 0, stream>>>((const __half2*)bufB, sums1, sqs1);
    k_bn_prep<64><<<1, 64, 0, stream>>>(sums1, sqs1, g1, be1, sc1, sh1);
    k_apply1h<<<NN * 64 / 8 / 256, 256, 0, stream>>>(bufB, sc1, sh1, dinv, bufB);

    // layer 2: agg in 64ch, then gemm2 (+fused BN2 stats)
    k_agg<<<NN / 4, 256, 0, stream>>>((const __half2*)bufB, offs, srcs, dinv, (__half2*)bufA);
    k_gemm2<<<NN / 64, 256, 0, stream>>>(bufA, W2, h2h, pS, pQ);
    k_redstats<<<64, 256, 0, stream>>>(pS, pQ, sums2, sqs2);
    k_bn_prep<128><<<1, 128, 0, stream>>>(sums2, sqs2, g2, be2, sc2, sh2);

    // pooling (+BN2+leaky fused) + head
    k_gcount<<<NN / 256, 256, 0, stream>>>(batch, gcnt);
    k_scan1<<<NG / 1024, 1024, 0, stream>>>(gcnt, goff, gb, NG);
    k_scan1<<<1, 1024, 0, stream>>>(gb, gb_s, dummy, NG / 1024);
    k_scan_add<<<NG / 1024, 1024, 0, stream>>>(goff, gb_s, NG);
    k_pool<<<NG / 4, 256, 0, stream>>>(h2h, goff, gcnt, sc2, sh2, Wo, bo, out);
}

// Round 11
// 335.349 us; speedup vs baseline: 2.1045x; 1.1826x over previous
//
#include <hip/hip_runtime.h>
#include <hip/hip_fp16.h>

#define NN 131072
#define NE 2097152
#define NT (NE + NN)      // edges + self loops
#define NG 2048
#define NB 256            // coarse buckets (dst >> 9)
#define NPB 512           // nodes per bucket
#define CH 256            // chunks
#define ECH (NE / CH)     // 8192 edges per chunk
#define EPSV 1e-5f

// ---------------- generic scan helpers ----------------
__global__ void k_scan1(const int* __restrict__ in, int* __restrict__ out,
                        int* __restrict__ bsums, int n) {
    __shared__ int tmp[1024];
    int t = threadIdx.x;
    int gid = blockIdx.x * 1024 + t;
    int v = (gid < n) ? in[gid] : 0;
    tmp[t] = v;
    __syncthreads();
    for (int off = 1; off < 1024; off <<= 1) {
        int add = (t >= off) ? tmp[t - off] : 0;
        __syncthreads();
        tmp[t] += add;
        __syncthreads();
    }
    if (gid < n) out[gid] = tmp[t] - v;       // exclusive
    if (t == 1023) bsums[blockIdx.x] = tmp[t];
}
__global__ void k_scan_add(int* __restrict__ out, const int* __restrict__ bs, int n) {
    int gid = blockIdx.x * 1024 + threadIdx.x;
    if (gid < n) out[gid] += bs[blockIdx.x];
}

// ---------------- CSR build: stable two-level counting sort ----------------
__global__ __launch_bounds__(256) void k_chist(const int* __restrict__ dst, int* __restrict__ ghist) {
    __shared__ int h[NB];
    int c = blockIdx.x, tid = threadIdx.x;
    if (tid < NB) h[tid] = 0;
    __syncthreads();
    const int* d = dst + (long)c * ECH;
    for (int i = tid; i < ECH; i += 256) atomicAdd(&h[d[i] >> 9], 1);
    __syncthreads();
    if (tid < NB) ghist[(long)c * NB + tid] = h[tid];
}
// transpose [CH][NB] -> [NB][CH]
__global__ void k_transpose(const int* __restrict__ in, int* __restrict__ out) {
    __shared__ int tile[32][33];
    int x = blockIdx.x * 32 + threadIdx.x;
    int y0 = blockIdx.y * 32 + threadIdx.y;
    for (int i = 0; i < 32; i += 8)
        tile[threadIdx.y + i][threadIdx.x] = in[(y0 + i) * NB + x];
    __syncthreads();
    int ox = blockIdx.y * 32 + threadIdx.x;
    int oy0 = blockIdx.x * 32 + threadIdx.y;
    for (int i = 0; i < 32; i += 8)
        out[(oy0 + i) * CH + ox] = tile[threadIdx.x][threadIdx.y + i];
}
// stable scatter: block = chunk; pack src (17b) | (dst & 511) << 17
__global__ __launch_bounds__(256) void k_cscatter(const int* __restrict__ src, const int* __restrict__ dst,
                                                  const int* __restrict__ scanned, int* __restrict__ packed) {
    __shared__ int cur[NB];
    int c = blockIdx.x, tid = threadIdx.x;
    if (tid < NB) cur[tid] = scanned[tid * CH + c];
    __syncthreads();
    const int* s = src + (long)c * ECH;
    const int* d = dst + (long)c * ECH;
    for (int i = tid; i < ECH; i += 256) {
        int dv = d[i], sv = s[i];
        int p = atomicAdd(&cur[dv >> 9], 1);
        packed[p] = sv | ((dv & 511) << 17);
    }
}
// fine pass: block = bucket (512 nodes, 512 threads). Emits dinv, CSR offs, srcs (self loop first).
__global__ __launch_bounds__(512) void k_fine(const int* __restrict__ packed,
                                              const int* __restrict__ scanned,
                                              int* __restrict__ offs, float* __restrict__ dinv,
                                              int* __restrict__ srcs) {
    __shared__ int hist[NPB], sc[NPB], cursor[NPB];
    int b = blockIdx.x, tid = threadIdx.x;
    int ebeg = scanned[b * CH];
    int eend = (b == NB - 1) ? NE : scanned[(b + 1) * CH];
    hist[tid] = 0;
    __syncthreads();
    for (int e = ebeg + tid; e < eend; e += NPB)
        atomicAdd(&hist[packed[e] >> 17], 1);
    __syncthreads();
    sc[tid] = hist[tid] + 1;                      // +1 self loop
    __syncthreads();
    for (int off = 1; off < NPB; off <<= 1) {
        int v = (tid >= off) ? sc[tid - off] : 0;
        __syncthreads();
        sc[tid] += v;
        __syncthreads();
    }
    int base = ebeg + b * NPB;
    {
        int cnt = hist[tid] + 1;
        int ex = sc[tid] - cnt;                   // exclusive scan
        int n = (b << 9) | tid;
        offs[n] = base + ex;
        dinv[n] = rsqrtf((float)cnt);
        srcs[base + ex] = n;                      // self loop first
        cursor[tid] = ex + 1;
    }
    if (b == NB - 1 && tid == 0) offs[NN] = NT;
    __syncthreads();
    for (int e = ebeg + tid; e < eend; e += NPB) {
        int p = packed[e];
        int pos = atomicAdd(&cursor[p >> 17], 1);
        srcs[base + pos] = p & 131071;
    }
}
// per-graph offsets via binary search (batch sorted)
__global__ void k_goff(const int* __restrict__ batch, int* __restrict__ goff) {
    int g = blockIdx.x * 256 + threadIdx.x;
    int lo = 0, hi = NN;
    while (lo < hi) {
        int mid = (lo + hi) >> 1;
        if (batch[mid] < g) lo = mid + 1; else hi = mid;
    }
    goff[g] = lo;
    if (g == 0) goff[NG] = NN;
}

// ---------------- gemm1: [64 x 128] @ [128 x 64] -> fp16, pre-scaled by dinv[row] ----------------
__global__ __launch_bounds__(256) void k_gemm1(const float* __restrict__ A,
                                               const float* __restrict__ W,
                                               const float* __restrict__ dinv,
                                               __half* __restrict__ out) {
    __shared__ float as[64 * 128];
    __shared__ float ws[128 * 64];
    int tid = threadIdx.x;
    long row0 = (long)blockIdx.x * 64;
    const float4* Ag = (const float4*)(A + row0 * 128);
    float4* As4 = (float4*)as;
#pragma unroll
    for (int i = 0; i < 8; ++i) As4[tid + i * 256] = Ag[tid + i * 256];
    const float4* Wg = (const float4*)W;
    float4* Ws4 = (float4*)ws;
#pragma unroll
    for (int i = 0; i < 8; ++i) Ws4[tid + i * 256] = Wg[tid + i * 256];
    __syncthreads();
    int ty = tid >> 4, tx = tid & 15;
    float acc[4][4] = {};
    for (int k = 0; k < 128; ++k) {
        float a0 = as[(ty * 4 + 0) * 128 + k];
        float a1 = as[(ty * 4 + 1) * 128 + k];
        float a2 = as[(ty * 4 + 2) * 128 + k];
        float a3 = as[(ty * 4 + 3) * 128 + k];
#pragma unroll
        for (int j = 0; j < 4; ++j) {
            float w = ws[k * 64 + tx * 4 + j];
            acc[0][j] = fmaf(a0, w, acc[0][j]);
            acc[1][j] = fmaf(a1, w, acc[1][j]);
            acc[2][j] = fmaf(a2, w, acc[2][j]);
            acc[3][j] = fmaf(a3, w, acc[3][j]);
        }
    }
#pragma unroll
    for (int i = 0; i < 4; ++i) {
        float dv = dinv[row0 + ty * 4 + i];
        __half2* op = (__half2*)(out + (row0 + ty * 4 + i) * 64 + tx * 4);
        op[0] = __floats2half2_rn(acc[i][0] * dv, acc[i][1] * dv);
        op[1] = __floats2half2_rn(acc[i][2] * dv, acc[i][3] * dv);
    }
}

// ---------------- gemm2: fp16 [64 x 64] @ f32 [64 x 128] -> fp16 + fused BN stats partials ----------------
__global__ __launch_bounds__(256) void k_gemm2(const __half* __restrict__ A,
                                               const float* __restrict__ W,
                                               __half* __restrict__ out,
                                               float* __restrict__ pS, float* __restrict__ pQ) {
    __shared__ float as[64 * 64];
    __shared__ float ws[64 * 128];
    __shared__ float red[16][128];
    int tid = threadIdx.x;
    long row0 = (long)blockIdx.x * 64;
#pragma unroll
    for (int i = 0; i < 2; ++i) {
        int idx = tid + i * 256;                      // 8 halves each
        int4 v = ((const int4*)(A + row0 * 64))[idx];
        __half2* hp = (__half2*)&v;
#pragma unroll
        for (int j = 0; j < 4; ++j) {
            float2 f = __half22float2(hp[j]);
            as[idx * 8 + j * 2] = f.x;
            as[idx * 8 + j * 2 + 1] = f.y;
        }
    }
    const float4* Wg = (const float4*)W;
    float4* Ws4 = (float4*)ws;
#pragma unroll
    for (int i = 0; i < 8; ++i) Ws4[tid + i * 256] = Wg[tid + i * 256];
    __syncthreads();
    int ty = tid >> 4, tx = tid & 15;
    float acc[4][8] = {};
    for (int k = 0; k < 64; ++k) {
        float a0 = as[(ty * 4 + 0) * 64 + k];
        float a1 = as[(ty * 4 + 1) * 64 + k];
        float a2 = as[(ty * 4 + 2) * 64 + k];
        float a3 = as[(ty * 4 + 3) * 64 + k];
#pragma unroll
        for (int j = 0; j < 8; ++j) {
            float w = ws[k * 128 + tx * 8 + j];
            acc[0][j] = fmaf(a0, w, acc[0][j]);
            acc[1][j] = fmaf(a1, w, acc[1][j]);
            acc[2][j] = fmaf(a2, w, acc[2][j]);
            acc[3][j] = fmaf(a3, w, acc[3][j]);
        }
    }
#pragma unroll
    for (int i = 0; i < 4; ++i) {
        __half2* op = (__half2*)(out + (row0 + ty * 4 + i) * 128 + tx * 8);
#pragma unroll
        for (int j = 0; j < 4; ++j)
            op[j] = __floats2half2_rn(acc[i][j * 2], acc[i][j * 2 + 1]);
    }
    float cs[8], cq[8];
#pragma unroll
    for (int j = 0; j < 8; ++j) {
        cs[j] = acc[0][j] + acc[1][j] + acc[2][j] + acc[3][j];
        cq[j] = acc[0][j] * acc[0][j] + acc[1][j] * acc[1][j] +
                acc[2][j] * acc[2][j] + acc[3][j] * acc[3][j];
    }
#pragma unroll
    for (int j = 0; j < 8; ++j) red[ty][tx * 8 + j] = cs[j];
    __syncthreads();
    if (tid < 128) {
        float s = 0.f;
#pragma unroll
        for (int t = 0; t < 16; ++t) s += red[t][tid];
        pS[blockIdx.x * 128 + tid] = s;
    }
    __syncthreads();
#pragma unroll
    for (int j = 0; j < 8; ++j) red[ty][tx * 8 + j] = cq[j];
    __syncthreads();
    if (tid < 128) {
        float q = 0.f;
#pragma unroll
        for (int t = 0; t < 16; ++t) q += red[t][tid];
        pQ[blockIdx.x * 128 + tid] = q;
    }
}

__global__ void k_redstats(const float* __restrict__ pS, const float* __restrict__ pQ,
                           float* __restrict__ sums, float* __restrict__ sqs) {
    int c = threadIdx.x;
    int rbeg = blockIdx.x * 32;
    float a = 0.f;
    if (c < 128) {
        for (int r = 0; r < 32; ++r) a += pS[(rbeg + r) * 128 + c];
        atomicAdd(&sums[c], a);
    } else {
        int cc = c - 128;
        for (int r = 0; r < 32; ++r) a += pQ[(rbeg + r) * 128 + cc];
        atomicAdd(&sqs[cc], a);
    }
}

// ---------------- CSR aggregation: feat pre-scaled by dinv[src]; srcs software-pipelined ----------------
// lanes 0-31 even edges, 32-63 odd edges; lane reads half2 (2 channels); 8 edges/iter with
// next iteration's srcs prefetched before current feat loads issue.
__global__ __launch_bounds__(256) void k_agg(const __half2* __restrict__ feat2,
                                             const int* __restrict__ offs,
                                             const int* __restrict__ srcs,
                                             const float* __restrict__ dinv,
                                             __half2* __restrict__ out) {
    int wid = (blockIdx.x * 256 + threadIdx.x) >> 6;   // one wave per dst node
    int lane = threadIdx.x & 63;
    int hi = lane >> 5;
    int c = lane & 31;
    int beg = offs[wid], end = offs[wid + 1];
    float ax = 0.f, ay = 0.f;
    int e = beg + hi;
    if (e + 6 < end) {
        int n0 = srcs[e], n1 = srcs[e + 2], n2 = srcs[e + 4], n3 = srcs[e + 6];
        e += 8;
        for (; e + 6 < end; e += 8) {
            int m0 = srcs[e], m1 = srcs[e + 2], m2 = srcs[e + 4], m3 = srcs[e + 6];
            float2 f0 = __half22float2(feat2[(long)n0 * 32 + c]);
            float2 f1 = __half22float2(feat2[(long)n1 * 32 + c]);
            float2 f2 = __half22float2(feat2[(long)n2 * 32 + c]);
            float2 f3 = __half22float2(feat2[(long)n3 * 32 + c]);
            ax += (f0.x + f1.x) + (f2.x + f3.x);
            ay += (f0.y + f1.y) + (f2.y + f3.y);
            n0 = m0; n1 = m1; n2 = m2; n3 = m3;
        }
        float2 f0 = __half22float2(feat2[(long)n0 * 32 + c]);
        float2 f1 = __half22float2(feat2[(long)n1 * 32 + c]);
        float2 f2 = __half22float2(feat2[(long)n2 * 32 + c]);
        float2 f3 = __half22float2(feat2[(long)n3 * 32 + c]);
        ax += (f0.x + f1.x) + (f2.x + f3.x);
        ay += (f0.y + f1.y) + (f2.y + f3.y);
    }
    for (; e + 2 < end; e += 4) {
        int s0 = srcs[e], s1 = srcs[e + 2];
        float2 f0 = __half22float2(feat2[(long)s0 * 32 + c]);
        float2 f1 = __half22float2(feat2[(long)s1 * 32 + c]);
        ax += f0.x + f1.x;
        ay += f0.y + f1.y;
    }
    if (e < end) {
        float2 f = __half22float2(feat2[(long)srcs[e] * 32 + c]);
        ax += f.x;
        ay += f.y;
    }
    ax += __shfl_xor(ax, 32);
    ay += __shfl_xor(ay, 32);
    if (hi == 0) {
        float dn = dinv[wid];
        out[(long)wid * 32 + c] = __floats2half2_rn(ax * dn, ay * dn);
    }
}

// ---------------- BN1 stats over fp16 h1 ----------------
__global__ __launch_bounds__(256) void k_stats64h(const __half2* __restrict__ h2,
                                                  float* __restrict__ sums, float* __restrict__ sqs) {
    __shared__ float sx[256], sy[256], qx[256], qy[256];
    int tid = threadIdx.x;
    int c = tid & 31, rg = tid >> 5;
    long row0 = (long)blockIdx.x * 1024;
    float ax = 0.f, ay = 0.f, bx = 0.f, by = 0.f;
    for (int i = rg; i < 1024; i += 8) {
        float2 f = __half22float2(h2[(row0 + i) * 32 + c]);
        ax += f.x; ay += f.y; bx += f.x * f.x; by += f.y * f.y;
    }
    sx[tid] = ax; sy[tid] = ay; qx[tid] = bx; qy[tid] = by;
    __syncthreads();
    if (tid < 32) {
        float tax = 0.f, tay = 0.f, tbx = 0.f, tby = 0.f;
#pragma unroll
        for (int g = 0; g < 8; ++g) {
            tax += sx[g * 32 + tid]; tay += sy[g * 32 + tid];
            tbx += qx[g * 32 + tid]; tby += qy[g * 32 + tid];
        }
        atomicAdd(&sums[2 * tid], tax); atomicAdd(&sums[2 * tid + 1], tay);
        atomicAdd(&sqs[2 * tid], tbx);  atomicAdd(&sqs[2 * tid + 1], tby);
    }
}
template <int C>
__global__ void k_bn_prep(const float* __restrict__ sums, const float* __restrict__ sqs,
                          const float* __restrict__ gamma, const float* __restrict__ beta,
                          float* __restrict__ scale, float* __restrict__ shift) {
    int c = threadIdx.x;
    if (c >= C) return;
    const float invN = 1.0f / (float)NN;
    float mean = sums[c] * invN;
    float var = sqs[c] * invN - mean * mean;
    float inv = rsqrtf(var + EPSV);
    float sc = gamma[c] * inv;
    scale[c] = sc;
    shift[c] = beta[c] - mean * sc;
}
// BN1 apply + leaky + dinv[row] pre-scale, fp16 in/out (in-place safe)
__global__ __launch_bounds__(256) void k_apply1h(const __half* __restrict__ h,
                                                 const float* __restrict__ scale,
                                                 const float* __restrict__ shift,
                                                 const float* __restrict__ dinv,
                                                 __half* __restrict__ out) {
    long idx = (long)blockIdx.x * 256 + threadIdx.x;   // unit: 8 halves
    int row = (int)(idx >> 3);
    int cb = (int)(idx & 7) * 8;
    float dv = dinv[row];
    int4 v = ((const int4*)h)[idx];
    __half2* hp = (__half2*)&v;
    int4 o;
    __half2* op = (__half2*)&o;
#pragma unroll
    for (int j = 0; j < 4; ++j) {
        float2 f = __half22float2(hp[j]);
        float y0 = fmaf(f.x, scale[cb + 2 * j], shift[cb + 2 * j]);
        float y1 = fmaf(f.y, scale[cb + 2 * j + 1], shift[cb + 2 * j + 1]);
        y0 = y0 > 0.f ? y0 : 0.01f * y0;
        y1 = y1 > 0.f ? y1 : 0.01f * y1;
        op[j] = __floats2half2_rn(y0 * dv, y1 * dv);
    }
    ((int4*)out)[idx] = o;
}

// ---------------- pooling + BN2 + leaky + head, fused ----------------
__global__ __launch_bounds__(256) void k_pool(const __half* __restrict__ h,
                                              const int* __restrict__ goff,
                                              const float* __restrict__ scale,
                                              const float* __restrict__ shift,
                                              const float* __restrict__ Wo,
                                              const float* __restrict__ bo,
                                              float* __restrict__ out) {
    int g = (blockIdx.x * 256 + threadIdx.x) >> 6;
    int lane = threadIdx.x & 63;
    int beg = goff[g], cnt = goff[g + 1] - beg;
    float sc0 = scale[2 * lane], sc1 = scale[2 * lane + 1];
    float sh0 = shift[2 * lane], sh1 = shift[2 * lane + 1];
    float a0 = 0.f, a1 = 0.f;
    for (int i = 0; i < cnt; ++i) {
        __half2 v = ((const __half2*)(h + (long)(beg + i) * 128))[lane];
        float2 f = __half22float2(v);
        float y0 = fmaf(f.x, sc0, sh0); y0 = y0 > 0.f ? y0 : 0.01f * y0;
        float y1 = fmaf(f.y, sc1, sh1); y1 = y1 > 0.f ? y1 : 0.01f * y1;
        a0 += y0; a1 += y1;
    }
    float v = a0 * Wo[2 * lane] + a1 * Wo[2 * lane + 1];
    v /= fmaxf((float)cnt, 1.f);
#pragma unroll
    for (int m = 32; m; m >>= 1) v += __shfl_xor(v, m);
    if (lane == 0) out[g] = v + bo[0];
}

extern "C" void kernel_launch(void* const* d_in, const int* in_sizes, int n_in,
                              void* d_out, int out_size, void* d_ws, size_t ws_size,
                              hipStream_t stream) {
    const float* x    = (const float*)d_in[0];
    const int* ei     = (const int*)d_in[1];
    const int* batch  = (const int*)d_in[2];
    const float* W1   = (const float*)d_in[3];
    const float* g1   = (const float*)d_in[5];
    const float* be1  = (const float*)d_in[6];
    const float* W2   = (const float*)d_in[7];
    const float* g2   = (const float*)d_in[9];
    const float* be2  = (const float*)d_in[10];
    const float* Wo   = (const float*)d_in[11];
    const float* bo   = (const float*)d_in[12];
    float* out = (float*)d_out;

    const int* esrc = ei;
    const int* edst = ei + NE;

    // ---- workspace layout ----
    __half* h2h = (__half*)d_ws;                   // [NN,128] half (33.5MB); alias: packed
    __half* bufA = h2h + (size_t)NN * 128;         // [NN,64] half; alias: ghist chain
    __half* bufB = bufA + (size_t)NN * 64;         // [NN,64] half
    float* dinv = (float*)(bufB + (size_t)NN * 64);// [NN]
    float* stats = dinv + NN;                      // 1024 floats
    float* sums1 = stats,        *sqs1 = stats + 64;
    float* sums2 = stats + 128,  *sqs2 = stats + 256;
    float* sc1   = stats + 384,  *sh1  = stats + 448;
    float* sc2   = stats + 512,  *sh2  = stats + 640;
    int* offs   = (int*)(stats + 1024);            // [NN+1]
    int* srcs   = offs + NN + 1;                   // [NT]
    int* bsums  = srcs + NT;                       // 256
    int* bsums2 = bsums + 256;                     // 256
    int* dummy  = bsums2 + 256;                    // 8
    int* goff   = dummy + 8;                       // [NG+1]
    float* pS   = (float*)(goff + NG + 8);         // [2048][128]
    float* pQ   = pS + 2048 * 128;                 // [2048][128]
    // temporal aliases
    int* ghist   = (int*)bufA;                     // [CH][NB]  (consumed before gemm1 writes bufA)
    int* ghist_t = ghist + CH * NB;
    int* scanned = ghist_t + NB * CH;
    int* packed  = (int*)h2h;                      // [NE]      (consumed before gemm2 writes h2h)

    hipMemsetAsync(stats, 0, 1024 * sizeof(float), stream);

    // ---- CSR build ----
    k_chist<<<CH, 256, 0, stream>>>(edst, ghist);
    k_transpose<<<dim3(NB / 32, CH / 32), dim3(32, 8), 0, stream>>>(ghist, ghist_t);
    k_scan1<<<NB * CH / 1024, 1024, 0, stream>>>(ghist_t, scanned, bsums, NB * CH);
    k_scan1<<<1, 1024, 0, stream>>>(bsums, bsums2, dummy, NB * CH / 1024);
    k_scan_add<<<NB * CH / 1024, 1024, 0, stream>>>(scanned, bsums2, NB * CH);
    k_cscatter<<<CH, 256, 0, stream>>>(esrc, edst, scanned, packed);
    k_fine<<<NB, NPB, 0, stream>>>(packed, scanned, offs, dinv, srcs);

    // layer 1: xw1' = (x @ W1) * dinv[row]  (fp16)
    k_gemm1<<<NN / 64, 256, 0, stream>>>(x, W1, dinv, bufA);
    k_agg<<<NN / 4, 256, 0, stream>>>((const __half2*)bufA, offs, srcs, dinv, (__half2*)bufB);
    k_stats64h<<<NN / 1024, 256, 0, stream>>>((const __half2*)bufB, sums1, sqs1);
    k_bn_prep<64><<<1, 64, 0, stream>>>(sums1, sqs1, g1, be1, sc1, sh1);
    k_apply1h<<<NN * 64 / 8 / 256, 256, 0, stream>>>(bufB, sc1, sh1, dinv, bufB);

    // layer 2: agg in 64ch, then gemm2 (+fused BN2 stats)
    k_agg<<<NN / 4, 256, 0, stream>>>((const __half2*)bufB, offs, srcs, dinv, (__half2*)bufA);
    k_gemm2<<<NN / 64, 256, 0, stream>>>(bufA, W2, h2h, pS, pQ);
    k_redstats<<<64, 256, 0, stream>>>(pS, pQ, sums2, sqs2);
    k_bn_prep<128><<<1, 128, 0, stream>>>(sums2, sqs2, g2, be2, sc2, sh2);

    // pooling (+BN2+leaky fused) + head
    k_goff<<<NG / 256, 256, 0, stream>>>(batch, goff);
    k_pool<<<NG / 4, 256, 0, stream>>>(h2h, goff, sc2, sh2, Wo, bo, out);
}

// Round 12
// 333.190 us; speedup vs baseline: 2.1181x; 1.0065x over previous
//
#include <hip/hip_runtime.h>
#include <hip/hip_fp16.h>

#define NN 131072
#define NE 2097152
#define NT (NE + NN)      // edges + self loops
#define NG 2048
#define NB 256            // coarse buckets (dst >> 9)
#define NPB 512           // nodes per bucket
#define CH 256            // chunks
#define ECH (NE / CH)     // 8192 edges per chunk
#define EPSV 1e-5f

// ---------------- generic scan helpers ----------------
__global__ void k_scan1(const int* __restrict__ in, int* __restrict__ out,
                        int* __restrict__ bsums, int n) {
    __shared__ int tmp[1024];
    int t = threadIdx.x;
    int gid = blockIdx.x * 1024 + t;
    int v = (gid < n) ? in[gid] : 0;
    tmp[t] = v;
    __syncthreads();
    for (int off = 1; off < 1024; off <<= 1) {
        int add = (t >= off) ? tmp[t - off] : 0;
        __syncthreads();
        tmp[t] += add;
        __syncthreads();
    }
    if (gid < n) out[gid] = tmp[t] - v;       // exclusive
    if (t == 1023) bsums[blockIdx.x] = tmp[t];
}
__global__ void k_scan_add(int* __restrict__ out, const int* __restrict__ bs, int n) {
    int gid = blockIdx.x * 1024 + threadIdx.x;
    if (gid < n) out[gid] += bs[blockIdx.x];
}

// ---------------- CSR build: stable two-level counting sort ----------------
__global__ __launch_bounds__(256) void k_chist(const int* __restrict__ dst, int* __restrict__ ghist) {
    __shared__ int h[NB];
    int c = blockIdx.x, tid = threadIdx.x;
    if (tid < NB) h[tid] = 0;
    __syncthreads();
    const int* d = dst + (long)c * ECH;
    for (int i = tid; i < ECH; i += 256) atomicAdd(&h[d[i] >> 9], 1);
    __syncthreads();
    if (tid < NB) ghist[(long)c * NB + tid] = h[tid];
}
// transpose [CH][NB] -> [NB][CH]
__global__ void k_transpose(const int* __restrict__ in, int* __restrict__ out) {
    __shared__ int tile[32][33];
    int x = blockIdx.x * 32 + threadIdx.x;
    int y0 = blockIdx.y * 32 + threadIdx.y;
    for (int i = 0; i < 32; i += 8)
        tile[threadIdx.y + i][threadIdx.x] = in[(y0 + i) * NB + x];
    __syncthreads();
    int ox = blockIdx.y * 32 + threadIdx.x;
    int oy0 = blockIdx.x * 32 + threadIdx.y;
    for (int i = 0; i < 32; i += 8)
        out[(oy0 + i) * CH + ox] = tile[threadIdx.x][threadIdx.y + i];
}
// stable scatter: block = chunk; pack src (17b) | (dst & 511) << 17
__global__ __launch_bounds__(256) void k_cscatter(const int* __restrict__ src, const int* __restrict__ dst,
                                                  const int* __restrict__ scanned, int* __restrict__ packed) {
    __shared__ int cur[NB];
    int c = blockIdx.x, tid = threadIdx.x;
    if (tid < NB) cur[tid] = scanned[tid * CH + c];
    __syncthreads();
    const int* s = src + (long)c * ECH;
    const int* d = dst + (long)c * ECH;
    for (int i = tid; i < ECH; i += 256) {
        int dv = d[i], sv = s[i];
        int p = atomicAdd(&cur[dv >> 9], 1);
        packed[p] = sv | ((dv & 511) << 17);
    }
}
// fine pass: block = bucket (512 nodes, 512 threads). Emits dinv, CSR offs, srcs (self loop first).
__global__ __launch_bounds__(512) void k_fine(const int* __restrict__ packed,
                                              const int* __restrict__ scanned,
                                              int* __restrict__ offs, float* __restrict__ dinv,
                                              int* __restrict__ srcs) {
    __shared__ int hist[NPB], sc[NPB], cursor[NPB];
    int b = blockIdx.x, tid = threadIdx.x;
    int ebeg = scanned[b * CH];
    int eend = (b == NB - 1) ? NE : scanned[(b + 1) * CH];
    hist[tid] = 0;
    __syncthreads();
    for (int e = ebeg + tid; e < eend; e += NPB)
        atomicAdd(&hist[packed[e] >> 17], 1);
    __syncthreads();
    sc[tid] = hist[tid] + 1;                      // +1 self loop
    __syncthreads();
    for (int off = 1; off < NPB; off <<= 1) {
        int v = (tid >= off) ? sc[tid - off] : 0;
        __syncthreads();
        sc[tid] += v;
        __syncthreads();
    }
    int base = ebeg + b * NPB;
    {
        int cnt = hist[tid] + 1;
        int ex = sc[tid] - cnt;                   // exclusive scan
        int n = (b << 9) | tid;
        offs[n] = base + ex;
        dinv[n] = rsqrtf((float)cnt);
        srcs[base + ex] = n;                      // self loop first
        cursor[tid] = ex + 1;
    }
    if (b == NB - 1 && tid == 0) offs[NN] = NT;
    __syncthreads();
    for (int e = ebeg + tid; e < eend; e += NPB) {
        int p = packed[e];
        int pos = atomicAdd(&cursor[p >> 17], 1);
        srcs[base + pos] = p & 131071;
    }
}
// per-graph offsets via binary search (batch sorted)
__global__ void k_goff(const int* __restrict__ batch, int* __restrict__ goff) {
    int g = blockIdx.x * 256 + threadIdx.x;
    int lo = 0, hi = NN;
    while (lo < hi) {
        int mid = (lo + hi) >> 1;
        if (batch[mid] < g) lo = mid + 1; else hi = mid;
    }
    goff[g] = lo;
    if (g == 0) goff[NG] = NN;
}

// ---------------- gemm1: [64 x 128] @ [128 x 64] -> fp16, pre-scaled by dinv[row] ----------------
__global__ __launch_bounds__(256) void k_gemm1(const float* __restrict__ A,
                                               const float* __restrict__ W,
                                               const float* __restrict__ dinv,
                                               __half* __restrict__ out) {
    __shared__ float as[64 * 128];
    __shared__ float ws[128 * 64];
    int tid = threadIdx.x;
    long row0 = (long)blockIdx.x * 64;
    const float4* Ag = (const float4*)(A + row0 * 128);
    float4* As4 = (float4*)as;
#pragma unroll
    for (int i = 0; i < 8; ++i) As4[tid + i * 256] = Ag[tid + i * 256];
    const float4* Wg = (const float4*)W;
    float4* Ws4 = (float4*)ws;
#pragma unroll
    for (int i = 0; i < 8; ++i) Ws4[tid + i * 256] = Wg[tid + i * 256];
    __syncthreads();
    int ty = tid >> 4, tx = tid & 15;
    float acc[4][4] = {};
    for (int k = 0; k < 128; ++k) {
        float a0 = as[(ty * 4 + 0) * 128 + k];
        float a1 = as[(ty * 4 + 1) * 128 + k];
        float a2 = as[(ty * 4 + 2) * 128 + k];
        float a3 = as[(ty * 4 + 3) * 128 + k];
#pragma unroll
        for (int j = 0; j < 4; ++j) {
            float w = ws[k * 64 + tx * 4 + j];
            acc[0][j] = fmaf(a0, w, acc[0][j]);
            acc[1][j] = fmaf(a1, w, acc[1][j]);
            acc[2][j] = fmaf(a2, w, acc[2][j]);
            acc[3][j] = fmaf(a3, w, acc[3][j]);
        }
    }
#pragma unroll
    for (int i = 0; i < 4; ++i) {
        float dv = dinv[row0 + ty * 4 + i];
        __half2* op = (__half2*)(out + (row0 + ty * 4 + i) * 64 + tx * 4);
        op[0] = __floats2half2_rn(acc[i][0] * dv, acc[i][1] * dv);
        op[1] = __floats2half2_rn(acc[i][2] * dv, acc[i][3] * dv);
    }
}

// ---------------- gemm2: fp16 [64 x 64] @ f32 [64 x 128] -> fp16 + fused BN stats partials ----------------
__global__ __launch_bounds__(256) void k_gemm2(const __half* __restrict__ A,
                                               const float* __restrict__ W,
                                               __half* __restrict__ out,
                                               float* __restrict__ pS, float* __restrict__ pQ) {
    __shared__ float as[64 * 64];
    __shared__ float ws[64 * 128];
    __shared__ float red[16][128];
    int tid = threadIdx.x;
    long row0 = (long)blockIdx.x * 64;
#pragma unroll
    for (int i = 0; i < 2; ++i) {
        int idx = tid + i * 256;                      // 8 halves each
        int4 v = ((const int4*)(A + row0 * 64))[idx];
        __half2* hp = (__half2*)&v;
#pragma unroll
        for (int j = 0; j < 4; ++j) {
            float2 f = __half22float2(hp[j]);
            as[idx * 8 + j * 2] = f.x;
            as[idx * 8 + j * 2 + 1] = f.y;
        }
    }
    const float4* Wg = (const float4*)W;
    float4* Ws4 = (float4*)ws;
#pragma unroll
    for (int i = 0; i < 8; ++i) Ws4[tid + i * 256] = Wg[tid + i * 256];
    __syncthreads();
    int ty = tid >> 4, tx = tid & 15;
    float acc[4][8] = {};
    for (int k = 0; k < 64; ++k) {
        float a0 = as[(ty * 4 + 0) * 64 + k];
        float a1 = as[(ty * 4 + 1) * 64 + k];
        float a2 = as[(ty * 4 + 2) * 64 + k];
        float a3 = as[(ty * 4 + 3) * 64 + k];
#pragma unroll
        for (int j = 0; j < 8; ++j) {
            float w = ws[k * 128 + tx * 8 + j];
            acc[0][j] = fmaf(a0, w, acc[0][j]);
            acc[1][j] = fmaf(a1, w, acc[1][j]);
            acc[2][j] = fmaf(a2, w, acc[2][j]);
            acc[3][j] = fmaf(a3, w, acc[3][j]);
        }
    }
#pragma unroll
    for (int i = 0; i < 4; ++i) {
        __half2* op = (__half2*)(out + (row0 + ty * 4 + i) * 128 + tx * 8);
#pragma unroll
        for (int j = 0; j < 4; ++j)
            op[j] = __floats2half2_rn(acc[i][j * 2], acc[i][j * 2 + 1]);
    }
    float cs[8], cq[8];
#pragma unroll
    for (int j = 0; j < 8; ++j) {
        cs[j] = acc[0][j] + acc[1][j] + acc[2][j] + acc[3][j];
        cq[j] = acc[0][j] * acc[0][j] + acc[1][j] * acc[1][j] +
                acc[2][j] * acc[2][j] + acc[3][j] * acc[3][j];
    }
#pragma unroll
    for (int j = 0; j < 8; ++j) red[ty][tx * 8 + j] = cs[j];
    __syncthreads();
    if (tid < 128) {
        float s = 0.f;
#pragma unroll
        for (int t = 0; t < 16; ++t) s += red[t][tid];
        pS[blockIdx.x * 128 + tid] = s;
    }
    __syncthreads();
#pragma unroll
    for (int j = 0; j < 8; ++j) red[ty][tx * 8 + j] = cq[j];
    __syncthreads();
    if (tid < 128) {
        float q = 0.f;
#pragma unroll
        for (int t = 0; t < 16; ++t) q += red[t][tid];
        pQ[blockIdx.x * 128 + tid] = q;
    }
}

__global__ void k_redstats(const float* __restrict__ pS, const float* __restrict__ pQ,
                           float* __restrict__ sums, float* __restrict__ sqs) {
    int c = threadIdx.x;
    int rbeg = blockIdx.x * 32;
    float a = 0.f;
    if (c < 128) {
        for (int r = 0; r < 32; ++r) a += pS[(rbeg + r) * 128 + c];
        atomicAdd(&sums[c], a);
    } else {
        int cc = c - 128;
        for (int r = 0; r < 32; ++r) a += pQ[(rbeg + r) * 128 + cc];
        atomicAdd(&sqs[cc], a);
    }
}

// ---------------- CSR aggregation: feat pre-scaled by dinv[src] ----------------
// 16 edges/iter: half-wave h takes edges [e+8h, e+8h+8); the 16 srcs indices load in ONE
// coalesced lane-parallel instruction, broadcast via shfl; 8 independent feat loads per
// half-wave then issue back-to-back (8 rows in flight per wave instruction stream).
__global__ __launch_bounds__(256) void k_agg(const __half2* __restrict__ feat2,
                                             const int* __restrict__ offs,
                                             const int* __restrict__ srcs,
                                             const float* __restrict__ dinv,
                                             __half2* __restrict__ out) {
    int wid = (blockIdx.x * 256 + threadIdx.x) >> 6;   // one wave per dst node
    int lane = threadIdx.x & 63;
    int hi = lane >> 5;
    int c = lane & 31;
    int beg = offs[wid], end = offs[wid + 1];
    float ax = 0.f, ay = 0.f;
    int e = beg;
    for (; e + 16 <= end; e += 16) {
        int myi = srcs[e + hi * 8 + (c & 7)];          // 16 consecutive ints, one 64B load
#pragma unroll
        for (int j = 0; j < 8; ++j) {
            int s = __shfl(myi, j, 32);                // half-wave-relative broadcast
            float2 f = __half22float2(feat2[(long)s * 32 + c]);
            ax += f.x;
            ay += f.y;
        }
    }
    if (e + 8 <= end) {
        int myi = srcs[e + hi * 4 + (c & 3)];
#pragma unroll
        for (int j = 0; j < 4; ++j) {
            int s = __shfl(myi, j, 32);
            float2 f = __half22float2(feat2[(long)s * 32 + c]);
            ax += f.x;
            ay += f.y;
        }
        e += 8;
    }
    for (int t = e + hi; t < end; t += 2) {            // <=7 edges remain
        float2 f = __half22float2(feat2[(long)srcs[t] * 32 + c]);
        ax += f.x;
        ay += f.y;
    }
    ax += __shfl_xor(ax, 32);
    ay += __shfl_xor(ay, 32);
    if (hi == 0) {
        float dn = dinv[wid];
        out[(long)wid * 32 + c] = __floats2half2_rn(ax * dn, ay * dn);
    }
}

// ---------------- BN1 stats over fp16 h1 ----------------
__global__ __launch_bounds__(256) void k_stats64h(const __half2* __restrict__ h2,
                                                  float* __restrict__ sums, float* __restrict__ sqs) {
    __shared__ float sx[256], sy[256], qx[256], qy[256];
    int tid = threadIdx.x;
    int c = tid & 31, rg = tid >> 5;
    long row0 = (long)blockIdx.x * 1024;
    float ax = 0.f, ay = 0.f, bx = 0.f, by = 0.f;
    for (int i = rg; i < 1024; i += 8) {
        float2 f = __half22float2(h2[(row0 + i) * 32 + c]);
        ax += f.x; ay += f.y; bx += f.x * f.x; by += f.y * f.y;
    }
    sx[tid] = ax; sy[tid] = ay; qx[tid] = bx; qy[tid] = by;
    __syncthreads();
    if (tid < 32) {
        float tax = 0.f, tay = 0.f, tbx = 0.f, tby = 0.f;
#pragma unroll
        for (int g = 0; g < 8; ++g) {
            tax += sx[g * 32 + tid]; tay += sy[g * 32 + tid];
            tbx += qx[g * 32 + tid]; tby += qy[g * 32 + tid];
        }
        atomicAdd(&sums[2 * tid], tax); atomicAdd(&sums[2 * tid + 1], tay);
        atomicAdd(&sqs[2 * tid], tbx);  atomicAdd(&sqs[2 * tid + 1], tby);
    }
}
template <int C>
__global__ void k_bn_prep(const float* __restrict__ sums, const float* __restrict__ sqs,
                          const float* __restrict__ gamma, const float* __restrict__ beta,
                          float* __restrict__ scale, float* __restrict__ shift) {
    int c = threadIdx.x;
    if (c >= C) return;
    const float invN = 1.0f / (float)NN;
    float mean = sums[c] * invN;
    float var = sqs[c] * invN - mean * mean;
    float inv = rsqrtf(var + EPSV);
    float sc = gamma[c] * inv;
    scale[c] = sc;
    shift[c] = beta[c] - mean * sc;
}
// BN1 apply + leaky + dinv[row] pre-scale, fp16 in/out (in-place safe)
__global__ __launch_bounds__(256) void k_apply1h(const __half* __restrict__ h,
                                                 const float* __restrict__ scale,
                                                 const float* __restrict__ shift,
                                                 const float* __restrict__ dinv,
                                                 __half* __restrict__ out) {
    long idx = (long)blockIdx.x * 256 + threadIdx.x;   // unit: 8 halves
    int row = (int)(idx >> 3);
    int cb = (int)(idx & 7) * 8;
    float dv = dinv[row];
    int4 v = ((const int4*)h)[idx];
    __half2* hp = (__half2*)&v;
    int4 o;
    __half2* op = (__half2*)&o;
#pragma unroll
    for (int j = 0; j < 4; ++j) {
        float2 f = __half22float2(hp[j]);
        float y0 = fmaf(f.x, scale[cb + 2 * j], shift[cb + 2 * j]);
        float y1 = fmaf(f.y, scale[cb + 2 * j + 1], shift[cb + 2 * j + 1]);
        y0 = y0 > 0.f ? y0 : 0.01f * y0;
        y1 = y1 > 0.f ? y1 : 0.01f * y1;
        op[j] = __floats2half2_rn(y0 * dv, y1 * dv);
    }
    ((int4*)out)[idx] = o;
}

// ---------------- pooling + BN2 + leaky + head, fused ----------------
__global__ __launch_bounds__(256) void k_pool(const __half* __restrict__ h,
                                              const int* __restrict__ goff,
                                              const float* __restrict__ scale,
                                              const float* __restrict__ shift,
                                              const float* __restrict__ Wo,
                                              const float* __restrict__ bo,
                                              float* __restrict__ out) {
    int g = (blockIdx.x * 256 + threadIdx.x) >> 6;
    int lane = threadIdx.x & 63;
    int beg = goff[g], cnt = goff[g + 1] - beg;
    float sc0 = scale[2 * lane], sc1 = scale[2 * lane + 1];
    float sh0 = shift[2 * lane], sh1 = shift[2 * lane + 1];
    float a0 = 0.f, a1 = 0.f;
    for (int i = 0; i < cnt; ++i) {
        __half2 v = ((const __half2*)(h + (long)(beg + i) * 128))[lane];
        float2 f = __half22float2(v);
        float y0 = fmaf(f.x, sc0, sh0); y0 = y0 > 0.f ? y0 : 0.01f * y0;
        float y1 = fmaf(f.y, sc1, sh1); y1 = y1 > 0.f ? y1 : 0.01f * y1;
        a0 += y0; a1 += y1;
    }
    float v = a0 * Wo[2 * lane] + a1 * Wo[2 * lane + 1];
    v /= fmaxf((float)cnt, 1.f);
#pragma unroll
    for (int m = 32; m; m >>= 1) v += __shfl_xor(v, m);
    if (lane == 0) out[g] = v + bo[0];
}

extern "C" void kernel_launch(void* const* d_in, const int* in_sizes, int n_in,
                              void* d_out, int out_size, void* d_ws, size_t ws_size,
                              hipStream_t stream) {
    const float* x    = (const float*)d_in[0];
    const int* ei     = (const int*)d_in[1];
    const int* batch  = (const int*)d_in[2];
    const float* W1   = (const float*)d_in[3];
    const float* g1   = (const float*)d_in[5];
    const float* be1  = (const float*)d_in[6];
    const float* W2   = (const float*)d_in[7];
    const float* g2   = (const float*)d_in[9];
    const float* be2  = (const float*)d_in[10];
    const float* Wo   = (const float*)d_in[11];
    const float* bo   = (const float*)d_in[12];
    float* out = (float*)d_out;

    const int* esrc = ei;
    const int* edst = ei + NE;

    // ---- workspace layout ----
    __half* h2h = (__half*)d_ws;                   // [NN,128] half (33.5MB); alias: packed
    __half* bufA = h2h + (size_t)NN * 128;         // [NN,64] half; alias: ghist chain
    __half* bufB = bufA + (size_t)NN * 64;         // [NN,64] half
    float* dinv = (float*)(bufB + (size_t)NN * 64);// [NN]
    float* stats = dinv + NN;                      // 1024 floats
    float* sums1 = stats,        *sqs1 = stats + 64;
    float* sums2 = stats + 128,  *sqs2 = stats + 256;
    float* sc1   = stats + 384,  *sh1  = stats + 448;
    float* sc2   = stats + 512,  *sh2  = stats + 640;
    int* offs   = (int*)(stats + 1024);            // [NN+1]
    int* srcs   = offs + NN + 1;                   // [NT]
    int* bsums  = srcs + NT;                       // 256
    int* bsums2 = bsums + 256;                     // 256
    int* dummy  = bsums2 + 256;                    // 8
    int* goff   = dummy + 8;                       // [NG+1]
    float* pS   = (float*)(goff + NG + 8);         // [2048][128]
    float* pQ   = pS + 2048 * 128;                 // [2048][128]
    // temporal aliases
    int* ghist   = (int*)bufA;                     // [CH][NB]  (consumed before gemm1 writes bufA)
    int* ghist_t = ghist + CH * NB;
    int* scanned = ghist_t + NB * CH;
    int* packed  = (int*)h2h;                      // [NE]      (consumed before gemm2 writes h2h)

    hipMemsetAsync(stats, 0, 1024 * sizeof(float), stream);

    // ---- CSR build ----
    k_chist<<<CH, 256, 0, stream>>>(edst, ghist);
    k_transpose<<<dim3(NB / 32, CH / 32), dim3(32, 8), 0, stream>>>(ghist, ghist_t);
    k_scan1<<<NB * CH / 1024, 1024, 0, stream>>>(ghist_t, scanned, bsums, NB * CH);
    k_scan1<<<1, 1024, 0, stream>>>(bsums, bsums2, dummy, NB * CH / 1024);
    k_scan_add<<<NB * CH / 1024, 1024, 0, stream>>>(scanned, bsums2, NB * CH);
    k_cscatter<<<CH, 256, 0, stream>>>(esrc, edst, scanned, packed);
    k_fine<<<NB, NPB, 0, stream>>>(packed, scanned, offs, dinv, srcs);

    // layer 1: xw1' = (x @ W1) * dinv[row]  (fp16)
    k_gemm1<<<NN / 64, 256, 0, stream>>>(x, W1, dinv, bufA);
    k_agg<<<NN / 4, 256, 0, stream>>>((const __half2*)bufA, offs, srcs, dinv, (__half2*)bufB);
    k_stats64h<<<NN / 1024, 256, 0, stream>>>((const __half2*)bufB, sums1, sqs1);
    k_bn_prep<64><<<1, 64, 0, stream>>>(sums1, sqs1, g1, be1, sc1, sh1);
    k_apply1h<<<NN * 64 / 8 / 256, 256, 0, stream>>>(bufB, sc1, sh1, dinv, bufB);

    // layer 2: agg in 64ch, then gemm2 (+fused BN2 stats)
    k_agg<<<NN / 4, 256, 0, stream>>>((const __half2*)bufB, offs, srcs, dinv, (__half2*)bufA);
    k_gemm2<<<NN / 64, 256, 0, stream>>>(bufA, W2, h2h, pS, pQ);
    k_redstats<<<64, 256, 0, stream>>>(pS, pQ, sums2, sqs2);
    k_bn_prep<128><<<1, 128, 0, stream>>>(sums2, sqs2, g2, be2, sc2, sh2);

    // pooling (+BN2+leaky fused) + head
    k_goff<<<NG / 256, 256, 0, stream>>>(batch, goff);
    k_pool<<<NG / 4, 256, 0, stream>>>(h2h, goff, sc2, sh2, Wo, bo, out);
}

// Round 14
// 319.197 us; speedup vs baseline: 2.2109x; 1.0438x over previous
//
#include <hip/hip_runtime.h>
#include <hip/hip_fp16.h>

#define NN 131072
#define NE 2097152
#define NT (NE + NN)        // edges + self loops
#define NTP (NE + 16 * NN)  // padded CSR capacity
#define NG 2048
#define NB 256              // coarse buckets (dst >> 9)
#define NPB 512             // nodes per bucket
#define CH 256              // chunks
#define ECH (NE / CH)       // 8192 edges per chunk
#define EPSV 1e-5f

// ---------------- generic scan helpers ----------------
__global__ void k_scan1(const int* __restrict__ in, int* __restrict__ out,
                        int* __restrict__ bsums, int n) {
    __shared__ int tmp[1024];
    int t = threadIdx.x;
    int gid = blockIdx.x * 1024 + t;
    int v = (gid < n) ? in[gid] : 0;
    tmp[t] = v;
    __syncthreads();
    for (int off = 1; off < 1024; off <<= 1) {
        int add = (t >= off) ? tmp[t - off] : 0;
        __syncthreads();
        tmp[t] += add;
        __syncthreads();
    }
    if (gid < n) out[gid] = tmp[t] - v;       // exclusive
    if (t == 1023) bsums[blockIdx.x] = tmp[t];
}
__global__ void k_scan_add(int* __restrict__ out, const int* __restrict__ bs, int n) {
    int gid = blockIdx.x * 1024 + threadIdx.x;
    if (gid < n) out[gid] += bs[blockIdx.x];
}

// ---------------- CSR build: stable two-level counting sort ----------------
__global__ __launch_bounds__(256) void k_chist(const int* __restrict__ dst, int* __restrict__ ghist) {
    __shared__ int h[NB];
    int c = blockIdx.x, tid = threadIdx.x;
    if (tid < NB) h[tid] = 0;
    __syncthreads();
    const int* d = dst + (long)c * ECH;
    for (int i = tid; i < ECH; i += 256) atomicAdd(&h[d[i] >> 9], 1);
    __syncthreads();
    if (tid < NB) ghist[(long)c * NB + tid] = h[tid];
}
// transpose [CH][NB] -> [NB][CH]
__global__ void k_transpose(const int* __restrict__ in, int* __restrict__ out) {
    __shared__ int tile[32][33];
    int x = blockIdx.x * 32 + threadIdx.x;
    int y0 = blockIdx.y * 32 + threadIdx.y;
    for (int i = 0; i < 32; i += 8)
        tile[threadIdx.y + i][threadIdx.x] = in[(y0 + i) * NB + x];
    __syncthreads();
    int ox = blockIdx.y * 32 + threadIdx.x;
    int oy0 = blockIdx.x * 32 + threadIdx.y;
    for (int i = 0; i < 32; i += 8)
        out[(oy0 + i) * CH + ox] = tile[threadIdx.x][threadIdx.y + i];
}
// stable scatter: block = chunk; pack src (17b) | (dst & 511) << 17
__global__ __launch_bounds__(256) void k_cscatter(const int* __restrict__ src, const int* __restrict__ dst,
                                                  const int* __restrict__ scanned, int* __restrict__ packed) {
    __shared__ int cur[NB];
    int c = blockIdx.x, tid = threadIdx.x;
    if (tid < NB) cur[tid] = scanned[tid * CH + c];
    __syncthreads();
    const int* s = src + (long)c * ECH;
    const int* d = dst + (long)c * ECH;
    for (int i = tid; i < ECH; i += 256) {
        int dv = d[i], sv = s[i];
        int p = atomicAdd(&cur[dv >> 9], 1);
        packed[p] = sv | ((dv & 511) << 17);
    }
}
// fine pass: block = bucket (512 nodes, 512 threads). Emits dinv, ninfo(start,paddedDeg),
// srcs with self loop first and sentinel (NN) padding to a multiple of 16.
// Bucket b's padded region starts at scanned[b*CH] + b*8192 (<= +16 pad per node * 512).
__global__ __launch_bounds__(512) void k_fine(const int* __restrict__ packed,
                                              const int* __restrict__ scanned,
                                              int2* __restrict__ ninfo, float* __restrict__ dinv,
                                              int* __restrict__ srcs) {
    __shared__ int hist[NPB], sc[NPB], cursor[NPB];
    int b = blockIdx.x, tid = threadIdx.x;
    int ebeg = scanned[b * CH];
    int eend = (b == NB - 1) ? NE : scanned[(b + 1) * CH];
    hist[tid] = 0;
    __syncthreads();
    for (int e = ebeg + tid; e < eend; e += NPB)
        atomicAdd(&hist[packed[e] >> 17], 1);
    __syncthreads();
    int cnt = hist[tid] + 1;                      // +1 self loop
    int pc = (cnt + 15) & ~15;                    // pad to multiple of 16
    sc[tid] = pc;
    __syncthreads();
    for (int off = 1; off < NPB; off <<= 1) {
        int v = (tid >= off) ? sc[tid - off] : 0;
        __syncthreads();
        sc[tid] += v;
        __syncthreads();
    }
    int rbase = ebeg + b * 8192;                  // bucket's padded region base
    int base = rbase + sc[tid] - pc;              // exclusive scan
    int n = (b << 9) | tid;
    ninfo[n] = make_int2(base, pc);
    dinv[n] = rsqrtf((float)cnt);
    srcs[base] = n;                               // self loop first
    cursor[tid] = base + 1;
    __syncthreads();
    for (int e = ebeg + tid; e < eend; e += NPB) {
        int p = packed[e];
        int pos = atomicAdd(&cursor[p >> 17], 1);
        srcs[pos] = p & 131071;
    }
    __syncthreads();
    for (int q = base + cnt; q < base + pc; ++q) srcs[q] = NN;  // sentinel padding
}
// per-graph offsets via binary search (batch sorted)
__global__ void k_goff(const int* __restrict__ batch, int* __restrict__ goff) {
    int g = blockIdx.x * 256 + threadIdx.x;
    int lo = 0, hi = NN;
    while (lo < hi) {
        int mid = (lo + hi) >> 1;
        if (batch[mid] < g) lo = mid + 1; else hi = mid;
    }
    goff[g] = lo;
    if (g == 0) goff[NG] = NN;
}

// ---------------- gemm1: [64 x 128] @ [128 x 64] -> fp16, pre-scaled by dinv[row] ----------------
__global__ __launch_bounds__(256) void k_gemm1(const float* __restrict__ A,
                                               const float* __restrict__ W,
                                               const float* __restrict__ dinv,
                                               __half* __restrict__ out) {
    __shared__ float as[64 * 128];
    __shared__ float ws[128 * 64];
    int tid = threadIdx.x;
    long row0 = (long)blockIdx.x * 64;
    const float4* Ag = (const float4*)(A + row0 * 128);
    float4* As4 = (float4*)as;
#pragma unroll
    for (int i = 0; i < 8; ++i) As4[tid + i * 256] = Ag[tid + i * 256];
    const float4* Wg = (const float4*)W;
    float4* Ws4 = (float4*)ws;
#pragma unroll
    for (int i = 0; i < 8; ++i) Ws4[tid + i * 256] = Wg[tid + i * 256];
    __syncthreads();
    int ty = tid >> 4, tx = tid & 15;
    float acc[4][4] = {};
    for (int k = 0; k < 128; ++k) {
        float a0 = as[(ty * 4 + 0) * 128 + k];
        float a1 = as[(ty * 4 + 1) * 128 + k];
        float a2 = as[(ty * 4 + 2) * 128 + k];
        float a3 = as[(ty * 4 + 3) * 128 + k];
#pragma unroll
        for (int j = 0; j < 4; ++j) {
            float w = ws[k * 64 + tx * 4 + j];
            acc[0][j] = fmaf(a0, w, acc[0][j]);
            acc[1][j] = fmaf(a1, w, acc[1][j]);
            acc[2][j] = fmaf(a2, w, acc[2][j]);
            acc[3][j] = fmaf(a3, w, acc[3][j]);
        }
    }
#pragma unroll
    for (int i = 0; i < 4; ++i) {
        float dv = dinv[row0 + ty * 4 + i];
        __half2* op = (__half2*)(out + (row0 + ty * 4 + i) * 64 + tx * 4);
        op[0] = __floats2half2_rn(acc[i][0] * dv, acc[i][1] * dv);
        op[1] = __floats2half2_rn(acc[i][2] * dv, acc[i][3] * dv);
    }
}

// ---------------- gemm2: fp16 [64 x 64] @ f32 [64 x 128] -> fp16 + fused BN stats partials ----------------
__global__ __launch_bounds__(256) void k_gemm2(const __half* __restrict__ A,
                                               const float* __restrict__ W,
                                               __half* __restrict__ out,
                                               float* __restrict__ pS, float* __restrict__ pQ) {
    __shared__ float as[64 * 64];
    __shared__ float ws[64 * 128];
    __shared__ float red[16][128];
    int tid = threadIdx.x;
    long row0 = (long)blockIdx.x * 64;
#pragma unroll
    for (int i = 0; i < 2; ++i) {
        int idx = tid + i * 256;                      // 8 halves each
        int4 v = ((const int4*)(A + row0 * 64))[idx];
        __half2* hp = (__half2*)&v;
#pragma unroll
        for (int j = 0; j < 4; ++j) {
            float2 f = __half22float2(hp[j]);
            as[idx * 8 + j * 2] = f.x;
            as[idx * 8 + j * 2 + 1] = f.y;
        }
    }
    const float4* Wg = (const float4*)W;
    float4* Ws4 = (float4*)ws;
#pragma unroll
    for (int i = 0; i < 8; ++i) Ws4[tid + i * 256] = Wg[tid + i * 256];
    __syncthreads();
    int ty = tid >> 4, tx = tid & 15;
    float acc[4][8] = {};
    for (int k = 0; k < 64; ++k) {
        float a0 = as[(ty * 4 + 0) * 64 + k];
        float a1 = as[(ty * 4 + 1) * 64 + k];
        float a2 = as[(ty * 4 + 2) * 64 + k];
        float a3 = as[(ty * 4 + 3) * 64 + k];
#pragma unroll
        for (int j = 0; j < 8; ++j) {
            float w = ws[k * 128 + tx * 8 + j];
            acc[0][j] = fmaf(a0, w, acc[0][j]);
            acc[1][j] = fmaf(a1, w, acc[1][j]);
            acc[2][j] = fmaf(a2, w, acc[2][j]);
            acc[3][j] = fmaf(a3, w, acc[3][j]);
        }
    }
#pragma unroll
    for (int i = 0; i < 4; ++i) {
        __half2* op = (__half2*)(out + (row0 + ty * 4 + i) * 128 + tx * 8);
#pragma unroll
        for (int j = 0; j < 4; ++j)
            op[j] = __floats2half2_rn(acc[i][j * 2], acc[i][j * 2 + 1]);
    }
    float cs[8], cq[8];
#pragma unroll
    for (int j = 0; j < 8; ++j) {
        cs[j] = acc[0][j] + acc[1][j] + acc[2][j] + acc[3][j];
        cq[j] = acc[0][j] * acc[0][j] + acc[1][j] * acc[1][j] +
                acc[2][j] * acc[2][j] + acc[3][j] * acc[3][j];
    }
#pragma unroll
    for (int j = 0; j < 8; ++j) red[ty][tx * 8 + j] = cs[j];
    __syncthreads();
    if (tid < 128) {
        float s = 0.f;
#pragma unroll
        for (int t = 0; t < 16; ++t) s += red[t][tid];
        pS[blockIdx.x * 128 + tid] = s;
    }
    __syncthreads();
#pragma unroll
    for (int j = 0; j < 8; ++j) red[ty][tx * 8 + j] = cq[j];
    __syncthreads();
    if (tid < 128) {
        float q = 0.f;
#pragma unroll
        for (int t = 0; t < 16; ++t) q += red[t][tid];
        pQ[blockIdx.x * 128 + tid] = q;
    }
}

__global__ void k_redstats(const float* __restrict__ pS, const float* __restrict__ pQ,
                           float* __restrict__ sums, float* __restrict__ sqs) {
    int c = threadIdx.x;
    int rbeg = blockIdx.x * 32;
    float a = 0.f;
    if (c < 128) {
        for (int r = 0; r < 32; ++r) a += pS[(rbeg + r) * 128 + c];
        atomicAdd(&sums[c], a);
    } else {
        int cc = c - 128;
        for (int r = 0; r < 32; ++r) a += pQ[(rbeg + r) * 128 + cc];
        atomicAdd(&sqs[cc], a);
    }
}

// ---------------- CSR aggregation: feat pre-scaled by dinv[src]; padded edge lists ----------------
// Edge lists are padded to multiples of 16 with sentinel NN (zero feature row, L1-hot).
// Single branch-free loop: one coalesced srcs load + 8 feat loads (8 rows in flight) per 16 edges.
__global__ __launch_bounds__(256) void k_agg(const __half2* __restrict__ feat2,
                                             const int2* __restrict__ ninfo,
                                             const int* __restrict__ srcs,
                                             const float* __restrict__ dinv,
                                             __half2* __restrict__ out) {
    int wid = (blockIdx.x * 256 + threadIdx.x) >> 6;   // one wave per dst node
    int lane = threadIdx.x & 63;
    int hi = lane >> 5;
    int c = lane & 31;
    int2 ni = ninfo[wid];                              // broadcast 8B load
    int e0 = ni.x, pd = ni.y;
    float ax = 0.f, ay = 0.f;
    for (int e = e0; e < e0 + pd; e += 16) {
        int myi = srcs[e + hi * 8 + (c & 7)];          // 16 consecutive ints, one 64B load
#pragma unroll
        for (int j = 0; j < 8; ++j) {
            int s = __shfl(myi, j, 32);                // half-wave-relative broadcast
            float2 f = __half22float2(feat2[(long)s * 32 + c]);
            ax += f.x;
            ay += f.y;
        }
    }
    ax += __shfl_xor(ax, 32);
    ay += __shfl_xor(ay, 32);
    if (hi == 0) {
        float dn = dinv[wid];
        out[(long)wid * 32 + c] = __floats2half2_rn(ax * dn, ay * dn);
    }
}

// ---------------- BN1 stats over fp16 h1 ----------------
__global__ __launch_bounds__(256) void k_stats64h(const __half2* __restrict__ h2,
                                                  float* __restrict__ sums, float* __restrict__ sqs) {
    __shared__ float sx[256], sy[256], qx[256], qy[256];
    int tid = threadIdx.x;
    int c = tid & 31, rg = tid >> 5;
    long row0 = (long)blockIdx.x * 1024;
    float ax = 0.f, ay = 0.f, bx = 0.f, by = 0.f;
    for (int i = rg; i < 1024; i += 8) {
        float2 f = __half22float2(h2[(row0 + i) * 32 + c]);
        ax += f.x; ay += f.y; bx += f.x * f.x; by += f.y * f.y;
    }
    sx[tid] = ax; sy[tid] = ay; qx[tid] = bx; qy[tid] = by;
    __syncthreads();
    if (tid < 32) {
        float tax = 0.f, tay = 0.f, tbx = 0.f, tby = 0.f;
#pragma unroll
        for (int g = 0; g < 8; ++g) {
            tax += sx[g * 32 + tid]; tay += sy[g * 32 + tid];
            tbx += qx[g * 32 + tid]; tby += qy[g * 32 + tid];
        }
        atomicAdd(&sums[2 * tid], tax); atomicAdd(&sums[2 * tid + 1], tay);
        atomicAdd(&sqs[2 * tid], tbx);  atomicAdd(&sqs[2 * tid + 1], tby);
    }
}
template <int C>
__global__ void k_bn_prep(const float* __restrict__ sums, const float* __restrict__ sqs,
                          const float* __restrict__ gamma, const float* __restrict__ beta,
                          float* __restrict__ scale, float* __restrict__ shift) {
    int c = threadIdx.x;
    if (c >= C) return;
    const float invN = 1.0f / (float)NN;
    float mean = sums[c] * invN;
    float var = sqs[c] * invN - mean * mean;
    float inv = rsqrtf(var + EPSV);
    float sc = gamma[c] * inv;
    scale[c] = sc;
    shift[c] = beta[c] - mean * sc;
}
// BN1 apply + leaky + dinv[row] pre-scale, fp16 in/out (in-place safe)
__global__ __launch_bounds__(256) void k_apply1h(const __half* __restrict__ h,
                                                 const float* __restrict__ scale,
                                                 const float* __restrict__ shift,
                                                 const float* __restrict__ dinv,
                                                 __half* __restrict__ out) {
    long idx = (long)blockIdx.x * 256 + threadIdx.x;   // unit: 8 halves
    int row = (int)(idx >> 3);
    int cb = (int)(idx & 7) * 8;
    float dv = dinv[row];
    int4 v = ((const int4*)h)[idx];
    __half2* hp = (__half2*)&v;
    int4 o;
    __half2* op = (__half2*)&o;
#pragma unroll
    for (int j = 0; j < 4; ++j) {
        float2 f = __half22float2(hp[j]);
        float y0 = fmaf(f.x, scale[cb + 2 * j], shift[cb + 2 * j]);
        float y1 = fmaf(f.y, scale[cb + 2 * j + 1], shift[cb + 2 * j + 1]);
        y0 = y0 > 0.f ? y0 : 0.01f * y0;
        y1 = y1 > 0.f ? y1 : 0.01f * y1;
        op[j] = __floats2half2_rn(y0 * dv, y1 * dv);
    }
    ((int4*)out)[idx] = o;
}

// ---------------- pooling + BN2 + leaky + head, fused ----------------
__global__ __launch_bounds__(256) void k_pool(const __half* __restrict__ h,
                                              const int* __restrict__ goff,
                                              const float* __restrict__ scale,
                                              const float* __restrict__ shift,
                                              const float* __restrict__ Wo,
                                              const float* __restrict__ bo,
                                              float* __restrict__ out) {
    int g = (blockIdx.x * 256 + threadIdx.x) >> 6;
    int lane = threadIdx.x & 63;
    int beg = goff[g], cnt = goff[g + 1] - beg;
    float sc0 = scale[2 * lane], sc1 = scale[2 * lane + 1];
    float sh0 = shift[2 * lane], sh1 = shift[2 * lane + 1];
    float a0 = 0.f, a1 = 0.f;
    for (int i = 0; i < cnt; ++i) {
        __half2 v = ((const __half2*)(h + (long)(beg + i) * 128))[lane];
        float2 f = __half22float2(v);
        float y0 = fmaf(f.x, sc0, sh0); y0 = y0 > 0.f ? y0 : 0.01f * y0;
        float y1 = fmaf(f.y, sc1, sh1); y1 = y1 > 0.f ? y1 : 0.01f * y1;
        a0 += y0; a1 += y1;
    }
    float v = a0 * Wo[2 * lane] + a1 * Wo[2 * lane + 1];
    v /= fmaxf((float)cnt, 1.f);
#pragma unroll
    for (int m = 32; m; m >>= 1) v += __shfl_xor(v, m);
    if (lane == 0) out[g] = v + bo[0];
}

extern "C" void kernel_launch(void* const* d_in, const int* in_sizes, int n_in,
                              void* d_out, int out_size, void* d_ws, size_t ws_size,
                              hipStream_t stream) {
    const float* x    = (const float*)d_in[0];
    const int* ei     = (const int*)d_in[1];
    const int* batch  = (const int*)d_in[2];
    const float* W1   = (const float*)d_in[3];
    const float* g1   = (const float*)d_in[5];
    const float* be1  = (const float*)d_in[6];
    const float* W2   = (const float*)d_in[7];
    const float* g2   = (const float*)d_in[9];
    const float* be2  = (const float*)d_in[10];
    const float* Wo   = (const float*)d_in[11];
    const float* bo   = (const float*)d_in[12];
    float* out = (float*)d_out;

    const int* esrc = ei;
    const int* edst = ei + NE;

    // ---- workspace layout ----
    __half* h2h = (__half*)d_ws;                   // [NN,128] half (33.5MB); alias: packed
    __half* bufA = h2h + (size_t)NN * 128;         // [NN+1,64] half; alias: ghist chain
    __half* bufB = bufA + (size_t)(NN + 1) * 64;   // [NN+1,64] half
    float* dinv = (float*)(bufB + (size_t)(NN + 1) * 64); // [NN]
    float* stats = dinv + NN;                      // 1024 floats
    float* sums1 = stats,        *sqs1 = stats + 64;
    float* sums2 = stats + 128,  *sqs2 = stats + 256;
    float* sc1   = stats + 384,  *sh1  = stats + 448;
    float* sc2   = stats + 512,  *sh2  = stats + 640;
    int2* ninfo = (int2*)(stats + 1024);           // [NN]
    int* srcs   = (int*)(ninfo + NN);              // [NTP]
    int* bsums  = srcs + NTP;                      // 256
    int* bsums2 = bsums + 256;                     // 256
    int* dummy  = bsums2 + 256;                    // 8
    int* goff   = dummy + 8;                       // [NG+1]
    float* pS   = (float*)(goff + NG + 8);         // [2048][128]
    float* pQ   = pS + 2048 * 128;                 // [2048][128]
    // temporal aliases
    int* ghist   = (int*)bufA;                     // [CH][NB]  (consumed before gemm1 writes bufA)
    int* ghist_t = ghist + CH * NB;
    int* scanned = ghist_t + NB * CH;
    int* packed  = (int*)h2h;                      // [NE]      (consumed before gemm2 writes h2h)

    hipMemsetAsync(stats, 0, 1024 * sizeof(float), stream);
    hipMemsetAsync(bufA + (size_t)NN * 64, 0, 128, stream);  // zero sentinel row
    hipMemsetAsync(bufB + (size_t)NN * 64, 0, 128, stream);  // zero sentinel row

    // ---- CSR build ----
    k_chist<<<CH, 256, 0, stream>>>(edst, ghist);
    k_transpose<<<dim3(NB / 32, CH / 32), dim3(32, 8), 0, stream>>>(ghist, ghist_t);
    k_scan1<<<NB * CH / 1024, 1024, 0, stream>>>(ghist_t, scanned, bsums, NB * CH);
    k_scan1<<<1, 1024, 0, stream>>>(bsums, bsums2, dummy, NB * CH / 1024);
    k_scan_add<<<NB * CH / 1024, 1024, 0, stream>>>(scanned, bsums2, NB * CH);
    k_cscatter<<<CH, 256, 0, stream>>>(esrc, edst, scanned, packed);
    k_fine<<<NB, NPB, 0, stream>>>(packed, scanned, ninfo, dinv, srcs);

    // layer 1: xw1' = (x @ W1) * dinv[row]  (fp16)
    k_gemm1<<<NN / 64, 256, 0, stream>>>(x, W1, dinv, bufA);
    k_agg<<<NN / 4, 256, 0, stream>>>((const __half2*)bufA, ninfo, srcs, dinv, (__half2*)bufB);
    k_stats64h<<<NN / 1024, 256, 0, stream>>>((const __half2*)bufB, sums1, sqs1);
    k_bn_prep<64><<<1, 64, 0, stream>>>(sums1, sqs1, g1, be1, sc1, sh1);
    k_apply1h<<<NN * 64 / 8 / 256, 256, 0, stream>>>(bufB, sc1, sh1, dinv, bufB);

    // layer 2: agg in 64ch, then gemm2 (+fused BN2 stats)
    k_agg<<<NN / 4, 256, 0, stream>>>((const __half2*)bufB, ninfo, srcs, dinv, (__half2*)bufA);
    k_gemm2<<<NN / 64, 256, 0, stream>>>(bufA, W2, h2h, pS, pQ);
    k_redstats<<<64, 256, 0, stream>>>(pS, pQ, sums2, sqs2);
    k_bn_prep<128><<<1, 128, 0, stream>>>(sums2, sqs2, g2, be2, sc2, sh2);

    // pooling (+BN2+leaky fused) + head
    k_goff<<<NG / 256, 256, 0, stream>>>(batch, goff);
    k_pool<<<NG / 4, 256, 0, stream>>>(h2h, goff, sc2, sh2, Wo, bo, out);
}

// Round 15
// 318.613 us; speedup vs baseline: 2.2150x; 1.0018x over previous
//
#include <hip/hip_runtime.h>
#include <hip/hip_fp16.h>

#define NN 131072
#define NE 2097152
#define NT (NE + NN)        // edges + self loops
#define NTP (NE + 16 * NN)  // padded CSR capacity
#define NG 2048
#define NB 256              // coarse buckets (dst >> 9)
#define NPB 512             // nodes per bucket
#define CH 256              // chunks
#define ECH (NE / CH)       // 8192 edges per chunk
#define EPSV 1e-5f

typedef __fp16 half4v __attribute__((ext_vector_type(4)));
typedef float float4v __attribute__((ext_vector_type(4)));

// ---------------- generic scan helpers ----------------
__global__ void k_scan1(const int* __restrict__ in, int* __restrict__ out,
                        int* __restrict__ bsums, int n) {
    __shared__ int tmp[1024];
    int t = threadIdx.x;
    int gid = blockIdx.x * 1024 + t;
    int v = (gid < n) ? in[gid] : 0;
    tmp[t] = v;
    __syncthreads();
    for (int off = 1; off < 1024; off <<= 1) {
        int add = (t >= off) ? tmp[t - off] : 0;
        __syncthreads();
        tmp[t] += add;
        __syncthreads();
    }
    if (gid < n) out[gid] = tmp[t] - v;       // exclusive
    if (t == 1023) bsums[blockIdx.x] = tmp[t];
}
__global__ void k_scan_add(int* __restrict__ out, const int* __restrict__ bs, int n) {
    int gid = blockIdx.x * 1024 + threadIdx.x;
    if (gid < n) out[gid] += bs[blockIdx.x];
}

// ---------------- CSR build: stable two-level counting sort ----------------
__global__ __launch_bounds__(256) void k_chist(const int* __restrict__ dst, int* __restrict__ ghist) {
    __shared__ int h[NB];
    int c = blockIdx.x, tid = threadIdx.x;
    if (tid < NB) h[tid] = 0;
    __syncthreads();
    const int* d = dst + (long)c * ECH;
    for (int i = tid; i < ECH; i += 256) atomicAdd(&h[d[i] >> 9], 1);
    __syncthreads();
    if (tid < NB) ghist[(long)c * NB + tid] = h[tid];
}
// transpose [CH][NB] -> [NB][CH]
__global__ void k_transpose(const int* __restrict__ in, int* __restrict__ out) {
    __shared__ int tile[32][33];
    int x = blockIdx.x * 32 + threadIdx.x;
    int y0 = blockIdx.y * 32 + threadIdx.y;
    for (int i = 0; i < 32; i += 8)
        tile[threadIdx.y + i][threadIdx.x] = in[(y0 + i) * NB + x];
    __syncthreads();
    int ox = blockIdx.y * 32 + threadIdx.x;
    int oy0 = blockIdx.x * 32 + threadIdx.y;
    for (int i = 0; i < 32; i += 8)
        out[(oy0 + i) * CH + ox] = tile[threadIdx.x][threadIdx.y + i];
}
// stable scatter: block = chunk; pack src (17b) | (dst & 511) << 17
__global__ __launch_bounds__(256) void k_cscatter(const int* __restrict__ src, const int* __restrict__ dst,
                                                  const int* __restrict__ scanned, int* __restrict__ packed) {
    __shared__ int cur[NB];
    int c = blockIdx.x, tid = threadIdx.x;
    if (tid < NB) cur[tid] = scanned[tid * CH + c];
    __syncthreads();
    const int* s = src + (long)c * ECH;
    const int* d = dst + (long)c * ECH;
    for (int i = tid; i < ECH; i += 256) {
        int dv = d[i], sv = s[i];
        int p = atomicAdd(&cur[dv >> 9], 1);
        packed[p] = sv | ((dv & 511) << 17);
    }
}
// fine pass: block = bucket (512 nodes, 512 threads). Emits dinv, ninfo(start,paddedDeg),
// srcs with self loop first and sentinel (NN) padding to a multiple of 16.
__global__ __launch_bounds__(512) void k_fine(const int* __restrict__ packed,
                                              const int* __restrict__ scanned,
                                              int2* __restrict__ ninfo, float* __restrict__ dinv,
                                              int* __restrict__ srcs) {
    __shared__ int hist[NPB], sc[NPB], cursor[NPB];
    int b = blockIdx.x, tid = threadIdx.x;
    int ebeg = scanned[b * CH];
    int eend = (b == NB - 1) ? NE : scanned[(b + 1) * CH];
    hist[tid] = 0;
    __syncthreads();
    for (int e = ebeg + tid; e < eend; e += NPB)
        atomicAdd(&hist[packed[e] >> 17], 1);
    __syncthreads();
    int cnt = hist[tid] + 1;                      // +1 self loop
    int pc = (cnt + 15) & ~15;                    // pad to multiple of 16
    sc[tid] = pc;
    __syncthreads();
    for (int off = 1; off < NPB; off <<= 1) {
        int v = (tid >= off) ? sc[tid - off] : 0;
        __syncthreads();
        sc[tid] += v;
        __syncthreads();
    }
    int rbase = ebeg + b * 8192;                  // bucket's padded region base
    int base = rbase + sc[tid] - pc;              // exclusive scan
    int n = (b << 9) | tid;
    ninfo[n] = make_int2(base, pc);
    dinv[n] = rsqrtf((float)cnt);
    srcs[base] = n;                               // self loop first
    cursor[tid] = base + 1;
    __syncthreads();
    for (int e = ebeg + tid; e < eend; e += NPB) {
        int p = packed[e];
        int pos = atomicAdd(&cursor[p >> 17], 1);
        srcs[pos] = p & 131071;
    }
    __syncthreads();
    for (int q = base + cnt; q < base + pc; ++q) srcs[q] = NN;  // sentinel padding
}
// per-graph offsets via binary search (batch sorted)
__global__ void k_goff(const int* __restrict__ batch, int* __restrict__ goff) {
    int g = blockIdx.x * 256 + threadIdx.x;
    int lo = 0, hi = NN;
    while (lo < hi) {
        int mid = (lo + hi) >> 1;
        if (batch[mid] < g) lo = mid + 1; else hi = mid;
    }
    goff[g] = lo;
    if (g == 0) goff[NG] = NN;
}

// ---------------- gemm1 (MFMA 16x16x16 f16): [64 x 128] @ [128 x 64] -> fp16 * dinv[row] ----------------
// A staged fp16 [64][132pad]; W1 staged transposed fp16 wst[64 cols][132pad].
__global__ __launch_bounds__(256) void k_gemm1(const float* __restrict__ A,
                                               const float* __restrict__ W,
                                               const float* __restrict__ dinv,
                                               __half* __restrict__ out) {
    __shared__ __fp16 as_[64 * 132];
    __shared__ __fp16 ws_[64 * 132];
    int tid = threadIdx.x;
    long row0 = (long)blockIdx.x * 64;
    // stage A: 64x128 f32 -> fp16, row-major stride 132
    const float4v* Ag = (const float4v*)(A + row0 * 128);
#pragma unroll
    for (int i = 0; i < 8; ++i) {
        int flat = tid + i * 256;          // unit: 4 floats
        int row = flat >> 5, k4 = flat & 31;
        float4v v = Ag[flat];
        half4v h = {(__fp16)v.x, (__fp16)v.y, (__fp16)v.z, (__fp16)v.w};
        *(half4v*)&as_[row * 132 + k4 * 4] = h;
    }
    // stage W transposed: W [128][64] f32 -> ws_[n][k] fp16
#pragma unroll
    for (int i = 0; i < 32; ++i) {
        int flat = tid + i * 256;
        int k = flat >> 6, n = flat & 63;
        ws_[n * 132 + k] = (__fp16)W[flat];
    }
    __syncthreads();
    int w = tid >> 6, l = tid & 63;
    int lr = l & 15, lg = l >> 4;
    float4v acc[4] = {};
    for (int k0 = 0; k0 < 128; k0 += 16) {
        half4v a = *(const half4v*)&as_[(w * 16 + lr) * 132 + k0 + lg * 4];
#pragma unroll
        for (int t4 = 0; t4 < 4; ++t4) {
            half4v b = *(const half4v*)&ws_[(t4 * 16 + lr) * 132 + k0 + lg * 4];
            acc[t4] = __builtin_amdgcn_mfma_f32_16x16x16f16(a, b, acc[t4], 0, 0, 0);
        }
    }
    // epilogue: D row = 4*lg + r (within 16-band), col = 16*t4 + lr
    float dv[4];
#pragma unroll
    for (int r = 0; r < 4; ++r) dv[r] = dinv[row0 + w * 16 + lg * 4 + r];
#pragma unroll
    for (int t4 = 0; t4 < 4; ++t4)
#pragma unroll
        for (int r = 0; r < 4; ++r) {
            long row = row0 + w * 16 + lg * 4 + r;
            out[row * 64 + t4 * 16 + lr] = __float2half(acc[t4][r] * dv[r]);
        }
}

// ---------------- gemm2 (MFMA 16x16x16 f16): fp16 [64 x 64] @ [64 x 128] -> fp16 + BN stats ----------------
__global__ __launch_bounds__(256) void k_gemm2(const __half* __restrict__ A,
                                               const float* __restrict__ W,
                                               __half* __restrict__ out,
                                               float* __restrict__ pS, float* __restrict__ pQ) {
    __shared__ __fp16 as_[64 * 68];
    __shared__ __fp16 ws_[128 * 68];
    __shared__ float redS[128], redQ[128];
    int tid = threadIdx.x;
    long row0 = (long)blockIdx.x * 64;
    if (tid < 128) { redS[tid] = 0.f; redQ[tid] = 0.f; }
    // stage A: 64x64 fp16, stride 68
    const int4* Ag = (const int4*)(A + row0 * 64);
#pragma unroll
    for (int i = 0; i < 2; ++i) {
        int flat8 = tid + i * 256;         // unit: 8 halves
        int row = flat8 >> 3, h8 = flat8 & 7;
        int4 v = Ag[flat8];
        *(half4v*)&as_[row * 68 + h8 * 8]     = *(half4v*)&v;
        *(half4v*)&as_[row * 68 + h8 * 8 + 4] = *((half4v*)&v + 1);
    }
    // stage W transposed: W [64][128] f32 -> ws_[n][k] fp16
#pragma unroll
    for (int i = 0; i < 32; ++i) {
        int flat = tid + i * 256;
        int k = flat >> 7, n = flat & 127;
        ws_[n * 68 + k] = (__fp16)W[flat];
    }
    __syncthreads();
    int w = tid >> 6, l = tid & 63;
    int lr = l & 15, lg = l >> 4;
    float4v acc[8] = {};
    for (int k0 = 0; k0 < 64; k0 += 16) {
        half4v a = *(const half4v*)&as_[(w * 16 + lr) * 68 + k0 + lg * 4];
#pragma unroll
        for (int t4 = 0; t4 < 8; ++t4) {
            half4v b = *(const half4v*)&ws_[(t4 * 16 + lr) * 68 + k0 + lg * 4];
            acc[t4] = __builtin_amdgcn_mfma_f32_16x16x16f16(a, b, acc[t4], 0, 0, 0);
        }
    }
#pragma unroll
    for (int t4 = 0; t4 < 8; ++t4) {
        float cs = 0.f, cq = 0.f;
#pragma unroll
        for (int r = 0; r < 4; ++r) {
            long row = row0 + w * 16 + lg * 4 + r;
            float v = acc[t4][r];
            out[row * 128 + t4 * 16 + lr] = __float2half(v);
            cs += v;
            cq += v * v;
        }
        atomicAdd(&redS[t4 * 16 + lr], cs);
        atomicAdd(&redQ[t4 * 16 + lr], cq);
    }
    __syncthreads();
    if (tid < 128) {
        pS[blockIdx.x * 128 + tid] = redS[tid];
        pQ[blockIdx.x * 128 + tid] = redQ[tid];
    }
}

__global__ void k_redstats(const float* __restrict__ pS, const float* __restrict__ pQ,
                           float* __restrict__ sums, float* __restrict__ sqs) {
    int c = threadIdx.x;
    int rbeg = blockIdx.x * 32;
    float a = 0.f;
    if (c < 128) {
        for (int r = 0; r < 32; ++r) a += pS[(rbeg + r) * 128 + c];
        atomicAdd(&sums[c], a);
    } else {
        int cc = c - 128;
        for (int r = 0; r < 32; ++r) a += pQ[(rbeg + r) * 128 + cc];
        atomicAdd(&sqs[cc], a);
    }
}

// ---------------- CSR aggregation: feat pre-scaled by dinv[src]; padded edge lists ----------------
__global__ __launch_bounds__(256) void k_agg(const __half2* __restrict__ feat2,
                                             const int2* __restrict__ ninfo,
                                             const int* __restrict__ srcs,
                                             const float* __restrict__ dinv,
                                             __half2* __restrict__ out) {
    int wid = (blockIdx.x * 256 + threadIdx.x) >> 6;   // one wave per dst node
    int lane = threadIdx.x & 63;
    int hi = lane >> 5;
    int c = lane & 31;
    int2 ni = ninfo[wid];                              // broadcast 8B load
    int e0 = ni.x, pd = ni.y;
    float ax = 0.f, ay = 0.f;
    for (int e = e0; e < e0 + pd; e += 16) {
        int myi = srcs[e + hi * 8 + (c & 7)];          // 16 consecutive ints, one 64B load
#pragma unroll
        for (int j = 0; j < 8; ++j) {
            int s = __shfl(myi, j, 32);                // half-wave-relative broadcast
            float2 f = __half22float2(feat2[(long)s * 32 + c]);
            ax += f.x;
            ay += f.y;
        }
    }
    ax += __shfl_xor(ax, 32);
    ay += __shfl_xor(ay, 32);
    if (hi == 0) {
        float dn = dinv[wid];
        out[(long)wid * 32 + c] = __floats2half2_rn(ax * dn, ay * dn);
    }
}

// ---------------- BN1 stats over fp16 h1 ----------------
__global__ __launch_bounds__(256) void k_stats64h(const __half2* __restrict__ h2,
                                                  float* __restrict__ sums, float* __restrict__ sqs) {
    __shared__ float sx[256], sy[256], qx[256], qy[256];
    int tid = threadIdx.x;
    int c = tid & 31, rg = tid >> 5;
    long row0 = (long)blockIdx.x * 1024;
    float ax = 0.f, ay = 0.f, bx = 0.f, by = 0.f;
    for (int i = rg; i < 1024; i += 8) {
        float2 f = __half22float2(h2[(row0 + i) * 32 + c]);
        ax += f.x; ay += f.y; bx += f.x * f.x; by += f.y * f.y;
    }
    sx[tid] = ax; sy[tid] = ay; qx[tid] = bx; qy[tid] = by;
    __syncthreads();
    if (tid < 32) {
        float tax = 0.f, tay = 0.f, tbx = 0.f, tby = 0.f;
#pragma unroll
        for (int g = 0; g < 8; ++g) {
            tax += sx[g * 32 + tid]; tay += sy[g * 32 + tid];
            tbx += qx[g * 32 + tid]; tby += qy[g * 32 + tid];
        }
        atomicAdd(&sums[2 * tid], tax); atomicAdd(&sums[2 * tid + 1], tay);
        atomicAdd(&sqs[2 * tid], tbx);  atomicAdd(&sqs[2 * tid + 1], tby);
    }
}
template <int C>
__global__ void k_bn_prep(const float* __restrict__ sums, const float* __restrict__ sqs,
                          const float* __restrict__ gamma, const float* __restrict__ beta,
                          float* __restrict__ scale, float* __restrict__ shift) {
    int c = threadIdx.x;
    if (c >= C) return;
    const float invN = 1.0f / (float)NN;
    float mean = sums[c] * invN;
    float var = sqs[c] * invN - mean * mean;
    float inv = rsqrtf(var + EPSV);
    float sc = gamma[c] * inv;
    scale[c] = sc;
    shift[c] = beta[c] - mean * sc;
}
// BN1 apply + leaky + dinv[row] pre-scale, fp16 in/out (in-place safe)
__global__ __launch_bounds__(256) void k_apply1h(const __half* __restrict__ h,
                                                 const float* __restrict__ scale,
                                                 const float* __restrict__ shift,
                                                 const float* __restrict__ dinv,
                                                 __half* __restrict__ out) {
    long idx = (long)blockIdx.x * 256 + threadIdx.x;   // unit: 8 halves
    int row = (int)(idx >> 3);
    int cb = (int)(idx & 7) * 8;
    float dv = dinv[row];
    int4 v = ((const int4*)h)[idx];
    __half2* hp = (__half2*)&v;
    int4 o;
    __half2* op = (__half2*)&o;
#pragma unroll
    for (int j = 0; j < 4; ++j) {
        float2 f = __half22float2(hp[j]);
        float y0 = fmaf(f.x, scale[cb + 2 * j], shift[cb + 2 * j]);
        float y1 = fmaf(f.y, scale[cb + 2 * j + 1], shift[cb + 2 * j + 1]);
        y0 = y0 > 0.f ? y0 : 0.01f * y0;
        y1 = y1 > 0.f ? y1 : 0.01f * y1;
        op[j] = __floats2half2_rn(y0 * dv, y1 * dv);
    }
    ((int4*)out)[idx] = o;
}

// ---------------- pooling + BN2 + leaky + head, fused ----------------
__global__ __launch_bounds__(256) void k_pool(const __half* __restrict__ h,
                                              const int* __restrict__ goff,
                                              const float* __restrict__ scale,
                                              const float* __restrict__ shift,
                                              const float* __restrict__ Wo,
                                              const float* __restrict__ bo,
                                              float* __restrict__ out) {
    int g = (blockIdx.x * 256 + threadIdx.x) >> 6;
    int lane = threadIdx.x & 63;
    int beg = goff[g], cnt = goff[g + 1] - beg;
    float sc0 = scale[2 * lane], sc1 = scale[2 * lane + 1];
    float sh0 = shift[2 * lane], sh1 = shift[2 * lane + 1];
    float a0 = 0.f, a1 = 0.f;
    for (int i = 0; i < cnt; ++i) {
        __half2 v = ((const __half2*)(h + (long)(beg + i) * 128))[lane];
        float2 f = __half22float2(v);
        float y0 = fmaf(f.x, sc0, sh0); y0 = y0 > 0.f ? y0 : 0.01f * y0;
        float y1 = fmaf(f.y, sc1, sh1); y1 = y1 > 0.f ? y1 : 0.01f * y1;
        a0 += y0; a1 += y1;
    }
    float v = a0 * Wo[2 * lane] + a1 * Wo[2 * lane + 1];
    v /= fmaxf((float)cnt, 1.f);
#pragma unroll
    for (int m = 32; m; m >>= 1) v += __shfl_xor(v, m);
    if (lane == 0) out[g] = v + bo[0];
}

extern "C" void kernel_launch(void* const* d_in, const int* in_sizes, int n_in,
                              void* d_out, int out_size, void* d_ws, size_t ws_size,
                              hipStream_t stream) {
    const float* x    = (const float*)d_in[0];
    const int* ei     = (const int*)d_in[1];
    const int* batch  = (const int*)d_in[2];
    const float* W1   = (const float*)d_in[3];
    const float* g1   = (const float*)d_in[5];
    const float* be1  = (const float*)d_in[6];
    const float* W2   = (const float*)d_in[7];
    const float* g2   = (const float*)d_in[9];
    const float* be2  = (const float*)d_in[10];
    const float* Wo   = (const float*)d_in[11];
    const float* bo   = (const float*)d_in[12];
    float* out = (float*)d_out;

    const int* esrc = ei;
    const int* edst = ei + NE;

    // ---- workspace layout ----
    __half* h2h = (__half*)d_ws;                   // [NN,128] half (33.5MB); alias: packed
    __half* bufA = h2h + (size_t)NN * 128;         // [NN+1,64] half; alias: ghist chain
    __half* bufB = bufA + (size_t)(NN + 1) * 64;   // [NN+1,64] half
    float* dinv = (float*)(bufB + (size_t)(NN + 1) * 64); // [NN]
    float* stats = dinv + NN;                      // 1024 floats
    float* sums1 = stats,        *sqs1 = stats + 64;
    float* sums2 = stats + 128,  *sqs2 = stats + 256;
    float* sc1   = stats + 384,  *sh1  = stats + 448;
    float* sc2   = stats + 512,  *sh2  = stats + 640;
    int2* ninfo = (int2*)(stats + 1024);           // [NN]
    int* srcs   = (int*)(ninfo + NN);              // [NTP]
    int* bsums  = srcs + NTP;                      // 256
    int* bsums2 = bsums + 256;                     // 256
    int* dummy  = bsums2 + 256;                    // 8
    int* goff   = dummy + 8;                       // [NG+1]
    float* pS   = (float*)(goff + NG + 8);         // [2048][128]
    float* pQ   = pS + 2048 * 128;                 // [2048][128]
    // temporal aliases
    int* ghist   = (int*)bufA;                     // [CH][NB]  (consumed before gemm1 writes bufA)
    int* ghist_t = ghist + CH * NB;
    int* scanned = ghist_t + NB * CH;
    int* packed  = (int*)h2h;                      // [NE]      (consumed before gemm2 writes h2h)

    hipMemsetAsync(stats, 0, 1024 * sizeof(float), stream);
    hipMemsetAsync(bufA + (size_t)NN * 64, 0, 128, stream);  // zero sentinel row
    hipMemsetAsync(bufB + (size_t)NN * 64, 0, 128, stream);  // zero sentinel row

    // ---- CSR build ----
    k_chist<<<CH, 256, 0, stream>>>(edst, ghist);
    k_transpose<<<dim3(NB / 32, CH / 32), dim3(32, 8), 0, stream>>>(ghist, ghist_t);
    k_scan1<<<NB * CH / 1024, 1024, 0, stream>>>(ghist_t, scanned, bsums, NB * CH);
    k_scan1<<<1, 1024, 0, stream>>>(bsums, bsums2, dummy, NB * CH / 1024);
    k_scan_add<<<NB * CH / 1024, 1024, 0, stream>>>(scanned, bsums2, NB * CH);
    k_cscatter<<<CH, 256, 0, stream>>>(esrc, edst, scanned, packed);
    k_fine<<<NB, NPB, 0, stream>>>(packed, scanned, ninfo, dinv, srcs);

    // layer 1: xw1' = (x @ W1) * dinv[row]  (fp16, MFMA)
    k_gemm1<<<NN / 64, 256, 0, stream>>>(x, W1, dinv, bufA);
    k_agg<<<NN / 4, 256, 0, stream>>>((const __half2*)bufA, ninfo, srcs, dinv, (__half2*)bufB);
    k_stats64h<<<NN / 1024, 256, 0, stream>>>((const __half2*)bufB, sums1, sqs1);
    k_bn_prep<64><<<1, 64, 0, stream>>>(sums1, sqs1, g1, be1, sc1, sh1);
    k_apply1h<<<NN * 64 / 8 / 256, 256, 0, stream>>>(bufB, sc1, sh1, dinv, bufB);

    // layer 2: agg in 64ch, then gemm2 (MFMA, +fused BN2 stats)
    k_agg<<<NN / 4, 256, 0, stream>>>((const __half2*)bufB, ninfo, srcs, dinv, (__half2*)bufA);
    k_gemm2<<<NN / 64, 256, 0, stream>>>(bufA, W2, h2h, pS, pQ);
    k_redstats<<<64, 256, 0, stream>>>(pS, pQ, sums2, sqs2);
    k_bn_prep<128><<<1, 128, 0, stream>>>(sums2, sqs2, g2, be2, sc2, sh2);

    // pooling (+BN2+leaky fused) + head
    k_goff<<<NG / 256, 256, 0, stream>>>(batch, goff);
    k_pool<<<NG / 4, 256, 0, stream>>>(h2h, goff, sc2, sh2, Wo, bo, out);
}

// Round 16
// 301.341 us; speedup vs baseline: 2.3420x; 1.0573x over previous
//
#include <hip/hip_runtime.h>
#include <hip/hip_fp16.h>

#define NN 131072
#define NE 2097152
#define NT (NE + NN)        // edges + self loops
#define NTP (NE + 16 * NN)  // padded CSR capacity
#define NG 2048
#define NB 256              // coarse buckets (dst >> 9)
#define NPB 512             // nodes per bucket
#define CH 256              // chunks
#define ECH (NE / CH)       // 8192 edges per chunk
#define EPSV 1e-5f

typedef __fp16 half4v __attribute__((ext_vector_type(4)));
typedef float float4v __attribute__((ext_vector_type(4)));

// ---------------- generic scan helpers ----------------
__global__ void k_scan1(const int* __restrict__ in, int* __restrict__ out,
                        int* __restrict__ bsums, int n) {
    __shared__ int tmp[1024];
    int t = threadIdx.x;
    int gid = blockIdx.x * 1024 + t;
    int v = (gid < n) ? in[gid] : 0;
    tmp[t] = v;
    __syncthreads();
    for (int off = 1; off < 1024; off <<= 1) {
        int add = (t >= off) ? tmp[t - off] : 0;
        __syncthreads();
        tmp[t] += add;
        __syncthreads();
    }
    if (gid < n) out[gid] = tmp[t] - v;       // exclusive
    if (t == 1023) bsums[blockIdx.x] = tmp[t];
}
__global__ void k_scan_add(int* __restrict__ out, const int* __restrict__ bs, int n) {
    int gid = blockIdx.x * 1024 + threadIdx.x;
    if (gid < n) out[gid] += bs[blockIdx.x];
}

// ---------------- CSR build: stable two-level counting sort ----------------
__global__ __launch_bounds__(256) void k_chist(const int* __restrict__ dst, int* __restrict__ ghist) {
    __shared__ int h[NB];
    int c = blockIdx.x, tid = threadIdx.x;
    if (tid < NB) h[tid] = 0;
    __syncthreads();
    const int* d = dst + (long)c * ECH;
    for (int i = tid; i < ECH; i += 256) atomicAdd(&h[d[i] >> 9], 1);
    __syncthreads();
    if (tid < NB) ghist[(long)c * NB + tid] = h[tid];
}
// transpose [CH][NB] -> [NB][CH]
__global__ void k_transpose(const int* __restrict__ in, int* __restrict__ out) {
    __shared__ int tile[32][33];
    int x = blockIdx.x * 32 + threadIdx.x;
    int y0 = blockIdx.y * 32 + threadIdx.y;
    for (int i = 0; i < 32; i += 8)
        tile[threadIdx.y + i][threadIdx.x] = in[(y0 + i) * NB + x];
    __syncthreads();
    int ox = blockIdx.y * 32 + threadIdx.x;
    int oy0 = blockIdx.x * 32 + threadIdx.y;
    for (int i = 0; i < 32; i += 8)
        out[(oy0 + i) * CH + ox] = tile[threadIdx.x][threadIdx.y + i];
}
// stable scatter: block = chunk; pack src (17b) | (dst & 511) << 17
__global__ __launch_bounds__(256) void k_cscatter(const int* __restrict__ src, const int* __restrict__ dst,
                                                  const int* __restrict__ scanned, int* __restrict__ packed) {
    __shared__ int cur[NB];
    int c = blockIdx.x, tid = threadIdx.x;
    if (tid < NB) cur[tid] = scanned[tid * CH + c];
    __syncthreads();
    const int* s = src + (long)c * ECH;
    const int* d = dst + (long)c * ECH;
    for (int i = tid; i < ECH; i += 256) {
        int dv = d[i], sv = s[i];
        int p = atomicAdd(&cur[dv >> 9], 1);
        packed[p] = sv | ((dv & 511) << 17);
    }
}
// fine pass: block = bucket (512 nodes, 512 threads). Emits dinv, ninfo(start,paddedDeg),
// srcs with self loop first and sentinel (NN) padding to a multiple of 16.
__global__ __launch_bounds__(512) void k_fine(const int* __restrict__ packed,
                                              const int* __restrict__ scanned,
                                              int2* __restrict__ ninfo, float* __restrict__ dinv,
                                              int* __restrict__ srcs) {
    __shared__ int hist[NPB], sc[NPB], cursor[NPB];
    int b = blockIdx.x, tid = threadIdx.x;
    int ebeg = scanned[b * CH];
    int eend = (b == NB - 1) ? NE : scanned[(b + 1) * CH];
    hist[tid] = 0;
    __syncthreads();
    for (int e = ebeg + tid; e < eend; e += NPB)
        atomicAdd(&hist[packed[e] >> 17], 1);
    __syncthreads();
    int cnt = hist[tid] + 1;                      // +1 self loop
    int pc = (cnt + 15) & ~15;                    // pad to multiple of 16
    sc[tid] = pc;
    __syncthreads();
    for (int off = 1; off < NPB; off <<= 1) {
        int v = (tid >= off) ? sc[tid - off] : 0;
        __syncthreads();
        sc[tid] += v;
        __syncthreads();
    }
    int rbase = ebeg + b * 8192;                  // bucket's padded region base
    int base = rbase + sc[tid] - pc;              // exclusive scan
    int n = (b << 9) | tid;
    ninfo[n] = make_int2(base, pc);
    dinv[n] = rsqrtf((float)cnt);
    srcs[base] = n;                               // self loop first
    cursor[tid] = base + 1;
    __syncthreads();
    for (int e = ebeg + tid; e < eend; e += NPB) {
        int p = packed[e];
        int pos = atomicAdd(&cursor[p >> 17], 1);
        srcs[pos] = p & 131071;
    }
    __syncthreads();
    for (int q = base + cnt; q < base + pc; ++q) srcs[q] = NN;  // sentinel padding
}
// per-graph offsets via binary search (batch sorted)
__global__ void k_goff(const int* __restrict__ batch, int* __restrict__ goff) {
    int g = blockIdx.x * 256 + threadIdx.x;
    int lo = 0, hi = NN;
    while (lo < hi) {
        int mid = (lo + hi) >> 1;
        if (batch[mid] < g) lo = mid + 1; else hi = mid;
    }
    goff[g] = lo;
    if (g == 0) goff[NG] = NN;
}

// ---------------- gemm1 (MFMA 16x16x16 f16): [64 x 128] @ [128 x 64] -> fp16 * dinv[row] ----------------
// A staged fp16 [64][132pad]; W1 staged transposed fp16 wst[64 cols][132pad].
__global__ __launch_bounds__(256) void k_gemm1(const float* __restrict__ A,
                                               const float* __restrict__ W,
                                               const float* __restrict__ dinv,
                                               __half* __restrict__ out) {
    __shared__ __fp16 as_[64 * 132];
    __shared__ __fp16 ws_[64 * 132];
    int tid = threadIdx.x;
    long row0 = (long)blockIdx.x * 64;
    // stage A: 64x128 f32 -> fp16, row-major stride 132
    const float4v* Ag = (const float4v*)(A + row0 * 128);
#pragma unroll
    for (int i = 0; i < 8; ++i) {
        int flat = tid + i * 256;          // unit: 4 floats
        int row = flat >> 5, k4 = flat & 31;
        float4v v = Ag[flat];
        half4v h = {(__fp16)v.x, (__fp16)v.y, (__fp16)v.z, (__fp16)v.w};
        *(half4v*)&as_[row * 132 + k4 * 4] = h;
    }
    // stage W transposed: W [128][64] f32 -> ws_[n][k] fp16
#pragma unroll
    for (int i = 0; i < 32; ++i) {
        int flat = tid + i * 256;
        int k = flat >> 6, n = flat & 63;
        ws_[n * 132 + k] = (__fp16)W[flat];
    }
    __syncthreads();
    int w = tid >> 6, l = tid & 63;
    int lr = l & 15, lg = l >> 4;
    float4v acc[4] = {};
    for (int k0 = 0; k0 < 128; k0 += 16) {
        half4v a = *(const half4v*)&as_[(w * 16 + lr) * 132 + k0 + lg * 4];
#pragma unroll
        for (int t4 = 0; t4 < 4; ++t4) {
            half4v b = *(const half4v*)&ws_[(t4 * 16 + lr) * 132 + k0 + lg * 4];
            acc[t4] = __builtin_amdgcn_mfma_f32_16x16x16f16(a, b, acc[t4], 0, 0, 0);
        }
    }
    // epilogue: D row = 4*lg + r (within 16-band), col = 16*t4 + lr
    float dv[4];
#pragma unroll
    for (int r = 0; r < 4; ++r) dv[r] = dinv[row0 + w * 16 + lg * 4 + r];
#pragma unroll
    for (int t4 = 0; t4 < 4; ++t4)
#pragma unroll
        for (int r = 0; r < 4; ++r) {
            long row = row0 + w * 16 + lg * 4 + r;
            out[row * 64 + t4 * 16 + lr] = __float2half(acc[t4][r] * dv[r]);
        }
}

// ---------------- gemm2 (VALU): fp16 [64 x 64] @ f32 [64 x 128] -> fp16 + fused BN stats partials ----------------
__global__ __launch_bounds__(256) void k_gemm2(const __half* __restrict__ A,
                                               const float* __restrict__ W,
                                               __half* __restrict__ out,
                                               float* __restrict__ pS, float* __restrict__ pQ) {
    __shared__ float as[64 * 64];
    __shared__ float ws[64 * 128];
    __shared__ float red[16][128];
    int tid = threadIdx.x;
    long row0 = (long)blockIdx.x * 64;
#pragma unroll
    for (int i = 0; i < 2; ++i) {
        int idx = tid + i * 256;                      // 8 halves each
        int4 v = ((const int4*)(A + row0 * 64))[idx];
        __half2* hp = (__half2*)&v;
#pragma unroll
        for (int j = 0; j < 4; ++j) {
            float2 f = __half22float2(hp[j]);
            as[idx * 8 + j * 2] = f.x;
            as[idx * 8 + j * 2 + 1] = f.y;
        }
    }
    const float4* Wg = (const float4*)W;
    float4* Ws4 = (float4*)ws;
#pragma unroll
    for (int i = 0; i < 8; ++i) Ws4[tid + i * 256] = Wg[tid + i * 256];
    __syncthreads();
    int ty = tid >> 4, tx = tid & 15;
    float acc[4][8] = {};
    for (int k = 0; k < 64; ++k) {
        float a0 = as[(ty * 4 + 0) * 64 + k];
        float a1 = as[(ty * 4 + 1) * 64 + k];
        float a2 = as[(ty * 4 + 2) * 64 + k];
        float a3 = as[(ty * 4 + 3) * 64 + k];
#pragma unroll
        for (int j = 0; j < 8; ++j) {
            float w = ws[k * 128 + tx * 8 + j];
            acc[0][j] = fmaf(a0, w, acc[0][j]);
            acc[1][j] = fmaf(a1, w, acc[1][j]);
            acc[2][j] = fmaf(a2, w, acc[2][j]);
            acc[3][j] = fmaf(a3, w, acc[3][j]);
        }
    }
#pragma unroll
    for (int i = 0; i < 4; ++i) {
        __half2* op = (__half2*)(out + (row0 + ty * 4 + i) * 128 + tx * 8);
#pragma unroll
        for (int j = 0; j < 4; ++j)
            op[j] = __floats2half2_rn(acc[i][j * 2], acc[i][j * 2 + 1]);
    }
    float cs[8], cq[8];
#pragma unroll
    for (int j = 0; j < 8; ++j) {
        cs[j] = acc[0][j] + acc[1][j] + acc[2][j] + acc[3][j];
        cq[j] = acc[0][j] * acc[0][j] + acc[1][j] * acc[1][j] +
                acc[2][j] * acc[2][j] + acc[3][j] * acc[3][j];
    }
#pragma unroll
    for (int j = 0; j < 8; ++j) red[ty][tx * 8 + j] = cs[j];
    __syncthreads();
    if (tid < 128) {
        float s = 0.f;
#pragma unroll
        for (int t = 0; t < 16; ++t) s += red[t][tid];
        pS[blockIdx.x * 128 + tid] = s;
    }
    __syncthreads();
#pragma unroll
    for (int j = 0; j < 8; ++j) red[ty][tx * 8 + j] = cq[j];
    __syncthreads();
    if (tid < 128) {
        float q = 0.f;
#pragma unroll
        for (int t = 0; t < 16; ++t) q += red[t][tid];
        pQ[blockIdx.x * 128 + tid] = q;
    }
}

__global__ void k_redstats(const float* __restrict__ pS, const float* __restrict__ pQ,
                           float* __restrict__ sums, float* __restrict__ sqs) {
    int c = threadIdx.x;
    int rbeg = blockIdx.x * 32;
    float a = 0.f;
    if (c < 128) {
        for (int r = 0; r < 32; ++r) a += pS[(rbeg + r) * 128 + c];
        atomicAdd(&sums[c], a);
    } else {
        int cc = c - 128;
        for (int r = 0; r < 32; ++r) a += pQ[(rbeg + r) * 128 + cc];
        atomicAdd(&sqs[cc], a);
    }
}

// ---------------- CSR aggregation: feat pre-scaled by dinv[src]; padded edge lists ----------------
__global__ __launch_bounds__(256) void k_agg(const __half2* __restrict__ feat2,
                                             const int2* __restrict__ ninfo,
                                             const int* __restrict__ srcs,
                                             const float* __restrict__ dinv,
                                             __half2* __restrict__ out) {
    int wid = (blockIdx.x * 256 + threadIdx.x) >> 6;   // one wave per dst node
    int lane = threadIdx.x & 63;
    int hi = lane >> 5;
    int c = lane & 31;
    int2 ni = ninfo[wid];                              // broadcast 8B load
    int e0 = ni.x, pd = ni.y;
    float ax = 0.f, ay = 0.f;
    for (int e = e0; e < e0 + pd; e += 16) {
        int myi = srcs[e + hi * 8 + (c & 7)];          // 16 consecutive ints, one 64B load
#pragma unroll
        for (int j = 0; j < 8; ++j) {
            int s = __shfl(myi, j, 32);                // half-wave-relative broadcast
            float2 f = __half22float2(feat2[(long)s * 32 + c]);
            ax += f.x;
            ay += f.y;
        }
    }
    ax += __shfl_xor(ax, 32);
    ay += __shfl_xor(ay, 32);
    if (hi == 0) {
        float dn = dinv[wid];
        out[(long)wid * 32 + c] = __floats2half2_rn(ax * dn, ay * dn);
    }
}

// ---------------- BN1 stats over fp16 h1 ----------------
__global__ __launch_bounds__(256) void k_stats64h(const __half2* __restrict__ h2,
                                                  float* __restrict__ sums, float* __restrict__ sqs) {
    __shared__ float sx[256], sy[256], qx[256], qy[256];
    int tid = threadIdx.x;
    int c = tid & 31, rg = tid >> 5;
    long row0 = (long)blockIdx.x * 1024;
    float ax = 0.f, ay = 0.f, bx = 0.f, by = 0.f;
    for (int i = rg; i < 1024; i += 8) {
        float2 f = __half22float2(h2[(row0 + i) * 32 + c]);
        ax += f.x; ay += f.y; bx += f.x * f.x; by += f.y * f.y;
    }
    sx[tid] = ax; sy[tid] = ay; qx[tid] = bx; qy[tid] = by;
    __syncthreads();
    if (tid < 32) {
        float tax = 0.f, tay = 0.f, tbx = 0.f, tby = 0.f;
#pragma unroll
        for (int g = 0; g < 8; ++g) {
            tax += sx[g * 32 + tid]; tay += sy[g * 32 + tid];
            tbx += qx[g * 32 + tid]; tby += qy[g * 32 + tid];
        }
        atomicAdd(&sums[2 * tid], tax); atomicAdd(&sums[2 * tid + 1], tay);
        atomicAdd(&sqs[2 * tid], tbx);  atomicAdd(&sqs[2 * tid + 1], tby);
    }
}
template <int C>
__global__ void k_bn_prep(const float* __restrict__ sums, const float* __restrict__ sqs,
                          const float* __restrict__ gamma, const float* __restrict__ beta,
                          float* __restrict__ scale, float* __restrict__ shift) {
    int c = threadIdx.x;
    if (c >= C) return;
    const float invN = 1.0f / (float)NN;
    float mean = sums[c] * invN;
    float var = sqs[c] * invN - mean * mean;
    float inv = rsqrtf(var + EPSV);
    float sc = gamma[c] * inv;
    scale[c] = sc;
    shift[c] = beta[c] - mean * sc;
}
// BN1 apply + leaky + dinv[row] pre-scale, fp16 in/out (in-place safe)
__global__ __launch_bounds__(256) void k_apply1h(const __half* __restrict__ h,
                                                 const float* __restrict__ scale,
                                                 const float* __restrict__ shift,
                                                 const float* __restrict__ dinv,
                                                 __half* __restrict__ out) {
    long idx = (long)blockIdx.x * 256 + threadIdx.x;   // unit: 8 halves
    int row = (int)(idx >> 3);
    int cb = (int)(idx & 7) * 8;
    float dv = dinv[row];
    int4 v = ((const int4*)h)[idx];
    __half2* hp = (__half2*)&v;
    int4 o;
    __half2* op = (__half2*)&o;
#pragma unroll
    for (int j = 0; j < 4; ++j) {
        float2 f = __half22float2(hp[j]);
        float y0 = fmaf(f.x, scale[cb + 2 * j], shift[cb + 2 * j]);
        float y1 = fmaf(f.y, scale[cb + 2 * j + 1], shift[cb + 2 * j + 1]);
        y0 = y0 > 0.f ? y0 : 0.01f * y0;
        y1 = y1 > 0.f ? y1 : 0.01f * y1;
        op[j] = __floats2half2_rn(y0 * dv, y1 * dv);
    }
    ((int4*)out)[idx] = o;
}

// ---------------- pooling + BN2 + leaky + head, fused ----------------
__global__ __launch_bounds__(256) void k_pool(const __half* __restrict__ h,
                                              const int* __restrict__ goff,
                                              const float* __restrict__ scale,
                                              const float* __restrict__ shift,
                                              const float* __restrict__ Wo,
                                              const float* __restrict__ bo,
                                              float* __restrict__ out) {
    int g = (blockIdx.x * 256 + threadIdx.x) >> 6;
    int lane = threadIdx.x & 63;
    int beg = goff[g], cnt = goff[g + 1] - beg;
    float sc0 = scale[2 * lane], sc1 = scale[2 * lane + 1];
    float sh0 = shift[2 * lane], sh1 = shift[2 * lane + 1];
    float a0 = 0.f, a1 = 0.f;
    for (int i = 0; i < cnt; ++i) {
        __half2 v = ((const __half2*)(h + (long)(beg + i) * 128))[lane];
        float2 f = __half22float2(v);
        float y0 = fmaf(f.x, sc0, sh0); y0 = y0 > 0.f ? y0 : 0.01f * y0;
        float y1 = fmaf(f.y, sc1, sh1); y1 = y1 > 0.f ? y1 : 0.01f * y1;
        a0 += y0; a1 += y1;
    }
    float v = a0 * Wo[2 * lane] + a1 * Wo[2 * lane + 1];
    v /= fmaxf((float)cnt, 1.f);
#pragma unroll
    for (int m = 32; m; m >>= 1) v += __shfl_xor(v, m);
    if (lane == 0) out[g] = v + bo[0];
}

extern "C" void kernel_launch(void* const* d_in, const int* in_sizes, int n_in,
                              void* d_out, int out_size, void* d_ws, size_t ws_size,
                              hipStream_t stream) {
    const float* x    = (const float*)d_in[0];
    const int* ei     = (const int*)d_in[1];
    const int* batch  = (const int*)d_in[2];
    const float* W1   = (const float*)d_in[3];
    const float* g1   = (const float*)d_in[5];
    const float* be1  = (const float*)d_in[6];
    const float* W2   = (const float*)d_in[7];
    const float* g2   = (const float*)d_in[9];
    const float* be2  = (const float*)d_in[10];
    const float* Wo   = (const float*)d_in[11];
    const float* bo   = (const float*)d_in[12];
    float* out = (float*)d_out;

    const int* esrc = ei;
    const int* edst = ei + NE;

    // ---- workspace layout ----
    __half* h2h = (__half*)d_ws;                   // [NN,128] half (33.5MB); alias: packed
    __half* bufA = h2h + (size_t)NN * 128;         // [NN+1,64] half; alias: ghist chain
    __half* bufB = bufA + (size_t)(NN + 1) * 64;   // [NN+1,64] half
    float* dinv = (float*)(bufB + (size_t)(NN + 1) * 64); // [NN]
    float* stats = dinv + NN;                      // 1024 floats
    float* sums1 = stats,        *sqs1 = stats + 64;
    float* sums2 = stats + 128,  *sqs2 = stats + 256;
    float* sc1   = stats + 384,  *sh1  = stats + 448;
    float* sc2   = stats + 512,  *sh2  = stats + 640;
    int2* ninfo = (int2*)(stats + 1024);           // [NN]
    int* srcs   = (int*)(ninfo + NN);              // [NTP]
    int* bsums  = srcs + NTP;                      // 256
    int* bsums2 = bsums + 256;                     // 256
    int* dummy  = bsums2 + 256;                    // 8
    int* goff   = dummy + 8;                       // [NG+1]
    float* pS   = (float*)(goff + NG + 8);         // [2048][128]
    float* pQ   = pS + 2048 * 128;                 // [2048][128]
    // temporal aliases
    int* ghist   = (int*)bufA;                     // [CH][NB]  (consumed before gemm1 writes bufA)
    int* ghist_t = ghist + CH * NB;
    int* scanned = ghist_t + NB * CH;
    int* packed  = (int*)h2h;                      // [NE]      (consumed before gemm2 writes h2h)

    hipMemsetAsync(stats, 0, 1024 * sizeof(float), stream);
    hipMemsetAsync(bufA + (size_t)NN * 64, 0, 128, stream);  // zero sentinel row
    hipMemsetAsync(bufB + (size_t)NN * 64, 0, 128, stream);  // zero sentinel row

    // ---- CSR build ----
    k_chist<<<CH, 256, 0, stream>>>(edst, ghist);
    k_transpose<<<dim3(NB / 32, CH / 32), dim3(32, 8), 0, stream>>>(ghist, ghist_t);
    k_scan1<<<NB * CH / 1024, 1024, 0, stream>>>(ghist_t, scanned, bsums, NB * CH);
    k_scan1<<<1, 1024, 0, stream>>>(bsums, bsums2, dummy, NB * CH / 1024);
    k_scan_add<<<NB * CH / 1024, 1024, 0, stream>>>(scanned, bsums2, NB * CH);
    k_cscatter<<<CH, 256, 0, stream>>>(esrc, edst, scanned, packed);
    k_fine<<<NB, NPB, 0, stream>>>(packed, scanned, ninfo, dinv, srcs);

    // layer 1: xw1' = (x @ W1) * dinv[row]  (fp16, MFMA)
    k_gemm1<<<NN / 64, 256, 0, stream>>>(x, W1, dinv, bufA);
    k_agg<<<NN / 4, 256, 0, stream>>>((const __half2*)bufA, ninfo, srcs, dinv, (__half2*)bufB);
    k_stats64h<<<NN / 1024, 256, 0, stream>>>((const __half2*)bufB, sums1, sqs1);
    k_bn_prep<64><<<1, 64, 0, stream>>>(sums1, sqs1, g1, be1, sc1, sh1);
    k_apply1h<<<NN * 64 / 8 / 256, 256, 0, stream>>>(bufB, sc1, sh1, dinv, bufB);

    // layer 2: agg in 64ch, then gemm2 (VALU, +fused BN2 stats)
    k_agg<<<NN / 4, 256, 0, stream>>>((const __half2*)bufB, ninfo, srcs, dinv, (__half2*)bufA);
    k_gemm2<<<NN / 64, 256, 0, stream>>>(bufA, W2, h2h, pS, pQ);
    k_redstats<<<64, 256, 0, stream>>>(pS, pQ, sums2, sqs2);
    k_bn_prep<128><<<1, 128, 0, stream>>>(sums2, sqs2, g2, be2, sc2, sh2);

    // pooling (+BN2+leaky fused) + head
    k_goff<<<NG / 256, 256, 0, stream>>>(batch, goff);
    k_pool<<<NG / 4, 256, 0, stream>>>(h2h, goff, sc2, sh2, Wo, bo, out);
}